// Round 1
// baseline (361.953 us; speedup 1.0000x reference)
//
#include <hip/hip_runtime.h>
#include <math.h>

#define BD 8      // B
#define LD 256    // L
#define DM 256    // D_MODEL
#define DS 16     // D_STATE
#define DI 512    // D_INNER
#define RK 16     // DT_RANK

#define NROWS (2*BD*LD)   // 4096 rows (both branches concatenated)

__device__ __forceinline__ float wred(float v){
  v += __shfl_xor(v, 32, 64);
  v += __shfl_xor(v, 16, 64);
  v += __shfl_xor(v,  8, 64);
  v += __shfl_xor(v,  4, 64);
  v += __shfl_xor(v,  2, 64);
  v += __shfl_xor(v,  1, 64);
  return v;
}
__device__ __forceinline__ float siluf(float x){ return x / (1.f + __expf(-x)); }
__device__ __forceinline__ float softplusf(float x){
  return fmaxf(x, 0.f) + log1pf(__expf(-fabsf(x)));
}

// ---------- shortcut: ident = LN(x @ sc_W + sc_b), eps=1e-5 ----------
__global__ __launch_bounds__(256) void k_shortcut(
    const float* __restrict__ x_spa, const float* __restrict__ x_spe,
    const float* __restrict__ sc_W, const float* __restrict__ sc_b,
    const float* __restrict__ ln_g, const float* __restrict__ ln_b,
    float* __restrict__ ident)
{
  __shared__ float rows[8][DM];
  __shared__ float mu_s[8], rs_s[8];
  int tid = threadIdx.x;
  int r0 = blockIdx.x * 8;
  int branch = (r0 >= BD*LD);
  const float* xb = branch ? x_spe : x_spa;
  int rr0 = branch ? r0 - BD*LD : r0;
  for (int r=0;r<8;r++) rows[r][tid] = xb[(rr0+r)*DM + tid];
  __syncthreads();
  float acc[8];
  #pragma unroll
  for (int r=0;r<8;r++) acc[r]=0.f;
  for (int k=0;k<DM;k++){
    float w = sc_W[k*DM + tid];
    #pragma unroll
    for (int r=0;r<8;r++) acc[r] = fmaf(rows[r][k], w, acc[r]);
  }
  float bias = sc_b[tid];
  __syncthreads();
  #pragma unroll
  for (int r=0;r<8;r++) rows[r][tid] = acc[r] + bias;
  __syncthreads();
  int wave = tid>>6, lane = tid&63;
  for (int r=wave*2; r<wave*2+2; r++){
    float s=0;
    #pragma unroll
    for (int i=0;i<4;i++) s += rows[r][lane+64*i];
    s = wred(s);
    float mu = s * (1.f/DM);
    float v=0;
    #pragma unroll
    for (int i=0;i<4;i++){ float d = rows[r][lane+64*i]-mu; v = fmaf(d,d,v); }
    v = wred(v);
    if (lane==0){ mu_s[r]=mu; rs_s[r]=rsqrtf(v*(1.f/DM)+1e-5f); }
  }
  __syncthreads();
  float g = ln_g[tid], be = ln_b[tid];
  for (int r=0;r<8;r++)
    ident[(r0+r)*DM + tid] = (rows[r][tid]-mu_s[r])*rs_s[r]*g + be;
}

// ---------- LN(x) @ W_in -> xc_raw (cols 0..511), silu(z) (cols 512..1023) ----------
__global__ __launch_bounds__(256) void k_lnwin(
    const float* __restrict__ x_spa, const float* __restrict__ x_spe,
    const float* __restrict__ g_spa, const float* __restrict__ b_spa,
    const float* __restrict__ g_spe, const float* __restrict__ b_spe,
    const float* __restrict__ Win_spa, const float* __restrict__ Win_spe,
    float* __restrict__ xc_raw, float* __restrict__ sz)
{
  __shared__ float xn[8][DM];
  __shared__ float mu_s[8], rs_s[8];
  int tid=threadIdx.x;
  int r0 = blockIdx.x*8;
  int branch = (r0 >= BD*LD);
  const float* xb  = branch ? x_spe  : x_spa;
  const float* g   = branch ? g_spe  : g_spa;
  const float* bb  = branch ? b_spe  : b_spa;
  const float* Win = branch ? Win_spe: Win_spa;
  int rr0 = branch ? r0-BD*LD : r0;
  for (int r=0;r<8;r++) xn[r][tid] = xb[(rr0+r)*DM+tid];
  __syncthreads();
  int wave=tid>>6, lane=tid&63;
  for (int r=wave*2;r<wave*2+2;r++){
    float s=0;
    #pragma unroll
    for(int i=0;i<4;i++) s+=xn[r][lane+64*i];
    s=wred(s); float mu=s*(1.f/DM);
    float v=0;
    #pragma unroll
    for(int i=0;i<4;i++){ float d=xn[r][lane+64*i]-mu; v=fmaf(d,d,v); }
    v=wred(v);
    if(lane==0){ mu_s[r]=mu; rs_s[r]=rsqrtf(v*(1.f/DM)+1e-6f); }
  }
  __syncthreads();
  float gg=g[tid], bbv=bb[tid];
  float tmp[8];
  #pragma unroll
  for(int r=0;r<8;r++) tmp[r]=(xn[r][tid]-mu_s[r])*rs_s[r]*gg+bbv;
  __syncthreads();
  #pragma unroll
  for(int r=0;r<8;r++) xn[r][tid]=tmp[r];
  __syncthreads();
  float acc[8][4];
  #pragma unroll
  for(int r=0;r<8;r++)
    #pragma unroll
    for(int j=0;j<4;j++) acc[r][j]=0.f;
  for(int k=0;k<DM;k++){
    float w0=Win[k*1024+tid], w1=Win[k*1024+tid+256];
    float w2=Win[k*1024+tid+512], w3=Win[k*1024+tid+768];
    #pragma unroll
    for(int r=0;r<8;r++){
      float xv=xn[r][k];
      acc[r][0]=fmaf(xv,w0,acc[r][0]);
      acc[r][1]=fmaf(xv,w1,acc[r][1]);
      acc[r][2]=fmaf(xv,w2,acc[r][2]);
      acc[r][3]=fmaf(xv,w3,acc[r][3]);
    }
  }
  for(int r=0;r<8;r++){
    int row=r0+r;
    xc_raw[row*DI + tid]       = acc[r][0];
    xc_raw[row*DI + tid + 256] = acc[r][1];
    sz[row*DI + tid]           = siluf(acc[r][2]);
    sz[row*DI + tid + 256]     = siluf(acc[r][3]);
  }
}

// ---------- causal conv + silu -> xc ; x_dbl = xc@W_x ; dt = softplus(dt_raw@W_dt+b_dt) ----------
__global__ __launch_bounds__(256) void k_convdt(
    const float* __restrict__ cw_spa, const float* __restrict__ cb_spa,
    const float* __restrict__ Wx_spa, const float* __restrict__ Wdt_spa, const float* __restrict__ bdt_spa,
    const float* __restrict__ cw_spe, const float* __restrict__ cb_spe,
    const float* __restrict__ Wx_spe, const float* __restrict__ Wdt_spe, const float* __restrict__ bdt_spe,
    const float* __restrict__ xc_raw,
    float* __restrict__ xc, float* __restrict__ dt,
    float* __restrict__ Bm, float* __restrict__ Cm)
{
  __shared__ float xcs[DI];
  __shared__ float xdbl[48];
  int tid=threadIdx.x;
  int row = blockIdx.x;            // 0..4095
  int branch = row >= BD*LD;
  int l = row & (LD-1);
  const float* cw  = branch ? cw_spe : cw_spa;
  const float* cb  = branch ? cb_spe : cb_spa;
  const float* Wx  = branch ? Wx_spe : Wx_spa;
  const float* Wdt = branch ? Wdt_spe: Wdt_spa;
  const float* bdt = branch ? bdt_spe: bdt_spa;
  #pragma unroll
  for(int i=0;i<2;i++){
    int d = tid + 256*i;
    float a = cb[d];
    #pragma unroll
    for(int k=0;k<4;k++){
      int li = l + k - 3;
      if (li >= 0) a = fmaf(xc_raw[(row + k - 3)*DI + d], cw[d*4+k], a);
    }
    float v = siluf(a);
    xcs[d] = v;
    xc[row*DI+d] = v;
  }
  __syncthreads();
  if (tid < 48){
    float a=0.f;
    for(int k=0;k<DI;k++) a = fmaf(xcs[k], Wx[k*48+tid], a);
    xdbl[tid]=a;
    if (tid>=16 && tid<32) Bm[row*DS + tid-16] = a;
    else if (tid>=32)      Cm[row*DS + tid-32] = a;
  }
  __syncthreads();
  #pragma unroll
  for(int i=0;i<2;i++){
    int d = tid + 256*i;
    float a = bdt[d];
    #pragma unroll
    for(int r=0;r<RK;r++) a = fmaf(xdbl[r], Wdt[r*DI+d], a);
    dt[row*DI+d] = softplusf(a);
  }
}

// ---------- selective scan: y = (scan + xc*D) * silu(z) ----------
__global__ __launch_bounds__(256) void k_scan(
    const float* __restrict__ Alog_spa, const float* __restrict__ Dp_spa,
    const float* __restrict__ Alog_spe, const float* __restrict__ Dp_spe,
    const float* __restrict__ dt, const float* __restrict__ xc,
    const float* __restrict__ sz, const float* __restrict__ Bm,
    const float* __restrict__ Cm, float* __restrict__ y)
{
  __shared__ float dt_c[16][16], xc_c[16][16], sz_c[16][16], b_c[16][16], c_c[16][16];
  int tid=threadIdx.x;
  int bi=blockIdx.x;               // 0..511
  int branch = bi >> 8;
  int rem = bi & 255;
  int b = rem >> 5;
  int d0 = (rem & 31) * 16;
  const float* Alog = branch ? Alog_spe : Alog_spa;
  const float* Dp   = branch ? Dp_spe   : Dp_spa;
  int dg = tid >> 4, s = tid & 15;
  int d = d0 + dg;
  float A_ds = -expf(Alog[d*DS + s]);
  float Dv = Dp[d];
  int row0 = branch*BD*LD + b*LD;
  float h = 0.f;
  for (int l0=0;l0<LD;l0+=16){
    int srow = row0 + l0 + dg;     // staging: li=tid/16, j=tid%16
    dt_c[dg][s] = dt[srow*DI + d0 + s];
    xc_c[dg][s] = xc[srow*DI + d0 + s];
    sz_c[dg][s] = sz[srow*DI + d0 + s];
    b_c[dg][s]  = Bm[srow*DS + s];
    c_c[dg][s]  = Cm[srow*DS + s];
    __syncthreads();
    #pragma unroll
    for(int li=0;li<16;li++){
      float dtv = dt_c[li][dg];
      float xcv = xc_c[li][dg];
      float dA = __expf(dtv * A_ds);
      h = fmaf(dA, h, dtv * b_c[li][s] * xcv);
      float yp = h * c_c[li][s];
      yp += __shfl_xor(yp, 1, 64);
      yp += __shfl_xor(yp, 2, 64);
      yp += __shfl_xor(yp, 4, 64);
      yp += __shfl_xor(yp, 8, 64);
      if (s==0) y[(row0+l0+li)*DI + d] = (yp + xcv*Dv) * sz_c[li][dg];
    }
    __syncthreads();
  }
}

// ---------- out GEMM + relu + residual ----------
__global__ __launch_bounds__(256) void k_wout(
    const float* __restrict__ Wout_spa, const float* __restrict__ Wout_spe,
    const float* __restrict__ x_spa, const float* __restrict__ x_spe,
    const float* __restrict__ y, float* __restrict__ ae)
{
  __shared__ float yr[8][DI];      // 16 KB
  int tid=threadIdx.x;
  int r0=blockIdx.x*8;
  int branch = r0 >= BD*LD;
  const float* Wout = branch ? Wout_spe : Wout_spa;
  const float* xb   = branch ? x_spe    : x_spa;
  int rr0 = branch ? r0 - BD*LD : r0;
  for(int r=0;r<8;r++){
    yr[r][tid]       = y[(r0+r)*DI + tid];
    yr[r][tid+256]   = y[(r0+r)*DI + tid + 256];
  }
  __syncthreads();
  float acc[8];
  #pragma unroll
  for(int r=0;r<8;r++) acc[r]=0.f;
  for(int k=0;k<DI;k++){
    float w = Wout[k*DM + tid];
    #pragma unroll
    for(int r=0;r<8;r++) acc[r]=fmaf(yr[r][k], w, acc[r]);
  }
  for(int r=0;r<8;r++)
    ae[(r0+r)*DM + tid] = fmaxf(acc[r],0.f) + xb[(rr0+r)*DM + tid];
}

// ---------- mean-pool both branches ----------
__global__ __launch_bounds__(256) void k_pool(const float* __restrict__ ae, float* __restrict__ pooled)
{
  int b=blockIdx.x, c=threadIdx.x;
  const float* a0 = ae + (b*LD)*DM + c;
  const float* a1 = ae + ((BD + b)*LD)*DM + c;
  float s=0.f;
  #pragma unroll 4
  for(int l=0;l<LD;l++) s += a0[l*DM] + a1[l*DM];
  pooled[b*DM+c] = s * (0.5f/LD);
}

// ---------- gate: fw = sigmoid(pooled @ fusion_W) ----------
__global__ __launch_bounds__(256) void k_gate(const float* __restrict__ pooled,
    const float* __restrict__ fW, float* __restrict__ fw)
{
  __shared__ float p[DM];
  int b=blockIdx.x, tid=threadIdx.x;
  p[tid]=pooled[b*DM+tid];
  __syncthreads();
  float a=0.f;
  for(int k=0;k<DM;k++) a=fmaf(p[k], fW[k*DM+tid], a);
  fw[b*DM+tid]=1.f/(1.f+__expf(-a));
}

// ---------- final: out = ae*fw + ident ----------
__global__ __launch_bounds__(256) void k_final(const float* __restrict__ ae,
    const float* __restrict__ ident, const float* __restrict__ fw, float* __restrict__ out)
{
  int idx = blockIdx.x*256 + threadIdx.x;
  int c = idx & (DM-1);
  int bb = (idx>>16) & 7;
  out[idx] = ae[idx]*fw[bb*DM+c] + ident[idx];
}

extern "C" void kernel_launch(void* const* d_in, const int* in_sizes, int n_in,
                              void* d_out, int out_size, void* d_ws, size_t ws_size,
                              hipStream_t stream) {
  const float* x_spa     = (const float*)d_in[0];
  const float* x_spe     = (const float*)d_in[1];
  const float* spa_ln_g  = (const float*)d_in[2];
  const float* spa_ln_b  = (const float*)d_in[3];
  const float* spa_W_in  = (const float*)d_in[4];
  const float* spa_cw    = (const float*)d_in[5];
  const float* spa_cb    = (const float*)d_in[6];
  const float* spa_W_x   = (const float*)d_in[7];
  const float* spa_W_dt  = (const float*)d_in[8];
  const float* spa_b_dt  = (const float*)d_in[9];
  const float* spa_A_log = (const float*)d_in[10];
  const float* spa_D     = (const float*)d_in[11];
  const float* spa_W_out = (const float*)d_in[12];
  const float* spe_ln_g  = (const float*)d_in[13];
  const float* spe_ln_b  = (const float*)d_in[14];
  const float* spe_W_in  = (const float*)d_in[15];
  const float* spe_cw    = (const float*)d_in[16];
  const float* spe_cb    = (const float*)d_in[17];
  const float* spe_W_x   = (const float*)d_in[18];
  const float* spe_W_dt  = (const float*)d_in[19];
  const float* spe_b_dt  = (const float*)d_in[20];
  const float* spe_A_log = (const float*)d_in[21];
  const float* spe_D     = (const float*)d_in[22];
  const float* spe_W_out = (const float*)d_in[23];
  const float* sc_W      = (const float*)d_in[24];
  const float* sc_b      = (const float*)d_in[25];
  const float* sc_ln_g   = (const float*)d_in[26];
  const float* sc_ln_b   = (const float*)d_in[27];
  const float* fusion_W  = (const float*)d_in[28];

  float* ws = (float*)d_ws;
  float* ident  = ws;                       // 4096*256
  float* xc_raw = ident  + NROWS*DM;        // 4096*512 (reused as y)
  float* sz     = xc_raw + NROWS*DI;        // 4096*512
  float* xc     = sz     + NROWS*DI;        // 4096*512
  float* dt     = xc     + NROWS*DI;        // 4096*512 (reused as ae)
  float* Bm     = dt     + NROWS*DI;        // 4096*16
  float* Cm     = Bm     + NROWS*DS;        // 4096*16
  float* pooled = Cm     + NROWS*DS;        // 8*256
  float* fw     = pooled + BD*DM;           // 8*256

  float* out = (float*)d_out;

  k_shortcut<<<NROWS/8, 256, 0, stream>>>(x_spa, x_spe, sc_W, sc_b, sc_ln_g, sc_ln_b, ident);
  k_lnwin<<<NROWS/8, 256, 0, stream>>>(x_spa, x_spe, spa_ln_g, spa_ln_b, spe_ln_g, spe_ln_b,
                                       spa_W_in, spe_W_in, xc_raw, sz);
  k_convdt<<<NROWS, 256, 0, stream>>>(spa_cw, spa_cb, spa_W_x, spa_W_dt, spa_b_dt,
                                      spe_cw, spe_cb, spe_W_x, spe_W_dt, spe_b_dt,
                                      xc_raw, xc, dt, Bm, Cm);
  float* y = xc_raw;   // xc_raw dead after k_convdt
  k_scan<<<512, 256, 0, stream>>>(spa_A_log, spa_D, spe_A_log, spe_D, dt, xc, sz, Bm, Cm, y);
  float* ae = dt;      // dt dead after k_scan
  k_wout<<<NROWS/8, 256, 0, stream>>>(spa_W_out, spe_W_out, x_spa, x_spe, y, ae);
  k_pool<<<BD, 256, 0, stream>>>(ae, pooled);
  k_gate<<<BD, 256, 0, stream>>>(pooled, fusion_W, fw);
  k_final<<<NROWS*DM/256, 256, 0, stream>>>(ae, ident, fw, out);
}

// Round 3
// 353.294 us; speedup vs baseline: 1.0245x; 1.0245x over previous
//
#include <hip/hip_runtime.h>
#include <math.h>

#define BD 8      // B
#define LD 256    // L
#define DM 256    // D_MODEL
#define DS 16     // D_STATE
#define DI 512    // D_INNER
#define RK 16     // DT_RANK

#define NROWS (2*BD*LD)   // 4096 rows (both branches concatenated)

__device__ __forceinline__ float wred(float v){
  v += __shfl_xor(v, 32, 64);
  v += __shfl_xor(v, 16, 64);
  v += __shfl_xor(v,  8, 64);
  v += __shfl_xor(v,  4, 64);
  v += __shfl_xor(v,  2, 64);
  v += __shfl_xor(v,  1, 64);
  return v;
}
__device__ __forceinline__ float siluf(float x){ return x / (1.f + __expf(-x)); }
__device__ __forceinline__ float softplusf(float x){
  return fmaxf(x, 0.f) + log1pf(__expf(-fabsf(x)));
}
__device__ __forceinline__ void fma4(float4& a, float s, const float4& w){
  a.x = fmaf(s, w.x, a.x);
  a.y = fmaf(s, w.y, a.y);
  a.z = fmaf(s, w.z, a.z);
  a.w = fmaf(s, w.w, a.w);
}

// ---------- shortcut: ident = LN(x @ sc_W + sc_b), eps=1e-5 ; 16 rows/block ----------
__global__ __launch_bounds__(256) void k_shortcut(
    const float* __restrict__ x_spa, const float* __restrict__ x_spe,
    const float* __restrict__ sc_W, const float* __restrict__ sc_b,
    const float* __restrict__ ln_g, const float* __restrict__ ln_b,
    float* __restrict__ ident)
{
  __shared__ float rows[16][DM];   // 16 KB
  __shared__ float mu_s[16], rs_s[16];
  int tid = threadIdx.x;
  int r0 = blockIdx.x * 16;
  int branch = (r0 >= BD*LD);
  const float* xb = branch ? x_spe : x_spa;
  int rr0 = branch ? r0 - BD*LD : r0;
  // stage 16x256 via float4: 1024 float4 / 256 threads = 4 each
  for (int p=0;p<4;p++){
    int idx = tid + 256*p;          // 0..1023
    int r = idx >> 6, c4 = (idx & 63) * 4;
    *(float4*)&rows[r][c4] = *(const float4*)(xb + (rr0+r)*DM + c4);
  }
  __syncthreads();
  // GEMM: thread owns col tid; k unrolled by 4 with b128 LDS reads
  float acc[16];
  #pragma unroll
  for (int r=0;r<16;r++) acc[r]=0.f;
  for (int k=0;k<DM;k+=4){
    float w0 = sc_W[(k+0)*DM + tid];
    float w1 = sc_W[(k+1)*DM + tid];
    float w2 = sc_W[(k+2)*DM + tid];
    float w3 = sc_W[(k+3)*DM + tid];
    #pragma unroll
    for (int r=0;r<16;r++){
      float4 xv = *(float4*)&rows[r][k];
      acc[r] = fmaf(xv.x, w0, acc[r]);
      acc[r] = fmaf(xv.y, w1, acc[r]);
      acc[r] = fmaf(xv.z, w2, acc[r]);
      acc[r] = fmaf(xv.w, w3, acc[r]);
    }
  }
  float bias = sc_b[tid];
  __syncthreads();
  #pragma unroll
  for (int r=0;r<16;r++) rows[r][tid] = acc[r] + bias;
  __syncthreads();
  int wave = tid>>6, lane = tid&63;
  for (int r=wave*4; r<wave*4+4; r++){
    float s=0;
    #pragma unroll
    for (int i=0;i<4;i++) s += rows[r][lane+64*i];
    s = wred(s);
    float mu = s * (1.f/DM);
    float v=0;
    #pragma unroll
    for (int i=0;i<4;i++){ float d = rows[r][lane+64*i]-mu; v = fmaf(d,d,v); }
    v = wred(v);
    if (lane==0){ mu_s[r]=mu; rs_s[r]=rsqrtf(v*(1.f/DM)+1e-5f); }
  }
  __syncthreads();
  float g = ln_g[tid], be = ln_b[tid];
  #pragma unroll
  for (int r=0;r<16;r++)
    ident[(r0+r)*DM + tid] = (rows[r][tid]-mu_s[r])*rs_s[r]*g + be;
}

// ---------- LN(x) @ W_in -> xc_raw (cols 0..511), silu(z) (cols 512..1023); 16 rows/block ----------
__global__ __launch_bounds__(256) void k_lnwin(
    const float* __restrict__ x_spa, const float* __restrict__ x_spe,
    const float* __restrict__ g_spa, const float* __restrict__ b_spa,
    const float* __restrict__ g_spe, const float* __restrict__ b_spe,
    const float* __restrict__ Win_spa, const float* __restrict__ Win_spe,
    float* __restrict__ xc_raw, float* __restrict__ sz)
{
  __shared__ float xn[16][DM];     // 16 KB
  __shared__ float mu_s[16], rs_s[16];
  int tid=threadIdx.x;
  int r0 = blockIdx.x*16;
  int branch = (r0 >= BD*LD);
  const float* xb  = branch ? x_spe  : x_spa;
  const float* g   = branch ? g_spe  : g_spa;
  const float* bb  = branch ? b_spe  : b_spa;
  const float* Win = branch ? Win_spe: Win_spa;
  int rr0 = branch ? r0-BD*LD : r0;
  for (int p=0;p<4;p++){
    int idx = tid + 256*p;
    int r = idx >> 6, c4 = (idx & 63) * 4;
    *(float4*)&xn[r][c4] = *(const float4*)(xb + (rr0+r)*DM + c4);
  }
  __syncthreads();
  int wave=tid>>6, lane=tid&63;
  for (int r=wave*4;r<wave*4+4;r++){
    float s=0;
    #pragma unroll
    for(int i=0;i<4;i++) s+=xn[r][lane+64*i];
    s=wred(s); float mu=s*(1.f/DM);
    float v=0;
    #pragma unroll
    for(int i=0;i<4;i++){ float d=xn[r][lane+64*i]-mu; v=fmaf(d,d,v); }
    v=wred(v);
    if(lane==0){ mu_s[r]=mu; rs_s[r]=rsqrtf(v*(1.f/DM)+1e-6f); }
  }
  __syncthreads();
  float gg=g[tid], bbv=bb[tid];
  #pragma unroll
  for(int r=0;r<16;r++) xn[r][tid]=(xn[r][tid]-mu_s[r])*rs_s[r]*gg+bbv;  // own column only
  __syncthreads();
  // GEMM: thread owns output cols 4*tid .. 4*tid+3 (of 1024)
  float4 acc[16];
  #pragma unroll
  for(int r=0;r<16;r++) acc[r]=make_float4(0.f,0.f,0.f,0.f);
  const float* Wp = Win + 4*tid;
  for(int k=0;k<DM;k+=4){
    float4 w0 = *(const float4*)(Wp + (k+0)*1024);
    float4 w1 = *(const float4*)(Wp + (k+1)*1024);
    float4 w2 = *(const float4*)(Wp + (k+2)*1024);
    float4 w3 = *(const float4*)(Wp + (k+3)*1024);
    #pragma unroll
    for(int r=0;r<16;r++){
      float4 xv = *(float4*)&xn[r][k];
      fma4(acc[r], xv.x, w0);
      fma4(acc[r], xv.y, w1);
      fma4(acc[r], xv.z, w2);
      fma4(acc[r], xv.w, w3);
    }
  }
  if (tid < 128){
    int c = 4*tid;
    #pragma unroll
    for(int r=0;r<16;r++)
      *(float4*)(xc_raw + (r0+r)*DI + c) = acc[r];
  } else {
    int c = 4*tid - DI;
    #pragma unroll
    for(int r=0;r<16;r++){
      float4 v;
      v.x = siluf(acc[r].x); v.y = siluf(acc[r].y);
      v.z = siluf(acc[r].z); v.w = siluf(acc[r].w);
      *(float4*)(sz + (r0+r)*DI + c) = v;
    }
  }
}

// ---------- causal conv + silu -> xc ; x_dbl = xc@W_x ; dt = softplus(dt_raw@W_dt+b_dt) ----------
// 8 rows per block
__global__ __launch_bounds__(256) void k_convdt(
    const float* __restrict__ cw_spa, const float* __restrict__ cb_spa,
    const float* __restrict__ Wx_spa, const float* __restrict__ Wdt_spa, const float* __restrict__ bdt_spa,
    const float* __restrict__ cw_spe, const float* __restrict__ cb_spe,
    const float* __restrict__ Wx_spe, const float* __restrict__ Wdt_spe, const float* __restrict__ bdt_spe,
    const float* __restrict__ xc_raw,
    float* __restrict__ xc, float* __restrict__ dt,
    float* __restrict__ Bm, float* __restrict__ Cm)
{
  __shared__ float raw[11][DI];    // 22 KB
  __shared__ float xcs[8][DI];     // 16 KB
  __shared__ float xpart[384][2];  // 3 KB
  __shared__ float xdbl[8][48];    // 1.5 KB
  int tid=threadIdx.x;
  int r0 = blockIdx.x*8;           // 512 blocks
  int branch = r0 >= BD*LD;
  int l0 = r0 & (LD-1);
  const float* cw  = branch ? cw_spe : cw_spa;
  const float* cb  = branch ? cb_spe : cb_spa;
  const float* Wx  = branch ? Wx_spe : Wx_spa;
  const float* Wdt = branch ? Wdt_spe: Wdt_spa;
  const float* bdt = branch ? bdt_spe: bdt_spa;
  // stage rows r0-3 .. r0+7 (zero-padded at batch start)
  for (int idx=tid; idx<1408; idx+=256){
    int j = idx >> 7, c4 = (idx & 127) * 4;
    int lrow = l0 - 3 + j;
    float4 v = make_float4(0.f,0.f,0.f,0.f);
    if (lrow >= 0) v = *(const float4*)(xc_raw + (r0-3+j)*DI + c4);
    *(float4*)&raw[j][c4] = v;
  }
  __syncthreads();
  // conv + silu
  {
    float4 cw4a = *(const float4*)(cw + 4*tid);
    float4 cw4b = *(const float4*)(cw + 4*(tid+256));
    float cba = cb[tid], cbb = cb[tid+256];
    #pragma unroll
    for (int r=0;r<8;r++){
      float a = cba;
      a = fmaf(raw[r+0][tid], cw4a.x, a);
      a = fmaf(raw[r+1][tid], cw4a.y, a);
      a = fmaf(raw[r+2][tid], cw4a.z, a);
      a = fmaf(raw[r+3][tid], cw4a.w, a);
      xcs[r][tid] = siluf(a);
      float b = cbb;
      b = fmaf(raw[r+0][tid+256], cw4b.x, b);
      b = fmaf(raw[r+1][tid+256], cw4b.y, b);
      b = fmaf(raw[r+2][tid+256], cw4b.z, b);
      b = fmaf(raw[r+3][tid+256], cw4b.w, b);
      xcs[r][tid+256] = siluf(b);
    }
  }
  __syncthreads();
  // store xc (float4)
  for (int idx=tid; idx<1024; idx+=256){
    int r = idx >> 7, c4 = (idx & 127) * 4;
    *(float4*)(xc + (r0+r)*DI + c4) = *(float4*)&xcs[r][c4];
  }
  // x_dbl: 384 dots of 512, split into 768 half-dots of 256
  for (int p=0;p<3;p++){
    int id = tid + 256*p;          // 0..767
    int half = id & 1, o = id >> 1;  // o in 0..383
    int r = o / 48, c = o - r*48;
    const float* wp = Wx + c + half*256*48;
    const float* xp = &xcs[r][half*256];
    float a=0.f;
    for (int k=0;k<256;k+=4){
      float4 xv = *(const float4*)(xp + k);
      a = fmaf(xv.x, wp[(k+0)*48], a);
      a = fmaf(xv.y, wp[(k+1)*48], a);
      a = fmaf(xv.z, wp[(k+2)*48], a);
      a = fmaf(xv.w, wp[(k+3)*48], a);
    }
    xpart[o][half] = a;
  }
  __syncthreads();
  for (int o=tid;o<384;o+=256){
    int r = o / 48, c = o - r*48;
    float a = xpart[o][0] + xpart[o][1];
    xdbl[r][c] = a;
    int gr = r0 + r;
    if (c>=16 && c<32)      Bm[gr*DS + c-16] = a;
    else if (c>=32)         Cm[gr*DS + c-32] = a;
  }
  __syncthreads();
  // dt
  {
    float wdt0[16], wdt1[16];
    #pragma unroll
    for (int j=0;j<16;j++){ wdt0[j]=Wdt[j*DI+tid]; wdt1[j]=Wdt[j*DI+tid+256]; }
    float b0 = bdt[tid], b1 = bdt[tid+256];
    #pragma unroll
    for (int r=0;r<8;r++){
      float a0=b0, a1=b1;
      #pragma unroll
      for (int j=0;j<16;j++){
        float xv = xdbl[r][j];
        a0 = fmaf(xv, wdt0[j], a0);
        a1 = fmaf(xv, wdt1[j], a1);
      }
      dt[(r0+r)*DI + tid]       = softplusf(a0);
      dt[(r0+r)*DI + tid + 256] = softplusf(a1);
    }
  }
}

// ---------- selective scan: y = (scan + xc*D) * silu(z) ----------
// 64-row chunks, float4 staging, register double-buffer
__global__ __launch_bounds__(256) void k_scan(
    const float* __restrict__ Alog_spa, const float* __restrict__ Dp_spa,
    const float* __restrict__ Alog_spe, const float* __restrict__ Dp_spe,
    const float* __restrict__ dt, const float* __restrict__ xc,
    const float* __restrict__ sz, const float* __restrict__ Bm,
    const float* __restrict__ Cm, float* __restrict__ y)
{
  __shared__ float dtc[2][64][16], xcc[2][64][16], szc[2][64][16], bc[2][64][16], cc[2][64][16]; // 40 KB
  __shared__ float yc[64][16];     // 4 KB
  int tid=threadIdx.x;
  int bi=blockIdx.x;               // 0..511
  int branch = bi >> 8;
  int rem = bi & 255;
  int b = rem >> 5;
  int d0 = (rem & 31) * 16;
  const float* Alog = branch ? Alog_spe : Alog_spa;
  const float* Dp   = branch ? Dp_spe   : Dp_spa;
  int dg = tid >> 4, s = tid & 15;
  int d = d0 + dg;
  float A_ds = -__expf(Alog[d*DS + s]);
  float Dv = Dp[d];
  int row0 = branch*BD*LD + b*LD;
  int lrow = tid >> 2, c4 = (tid & 3) * 4;  // staging coords
  // prologue: chunk 0
  {
    int row = row0 + lrow;
    float4 a0 = *(const float4*)(dt + row*DI + d0 + c4);
    float4 a1 = *(const float4*)(xc + row*DI + d0 + c4);
    float4 a2 = *(const float4*)(sz + row*DI + d0 + c4);
    float4 a3 = *(const float4*)(Bm + row*DS + c4);
    float4 a4 = *(const float4*)(Cm + row*DS + c4);
    *(float4*)&dtc[0][lrow][c4] = a0;
    *(float4*)&xcc[0][lrow][c4] = a1;
    *(float4*)&szc[0][lrow][c4] = a2;
    *(float4*)&bc[0][lrow][c4]  = a3;
    *(float4*)&cc[0][lrow][c4]  = a4;
  }
  __syncthreads();
  float h = 0.f;
  for (int c=0;c<4;c++){
    int cur = c & 1, nxt = cur ^ 1;
    float4 n0,n1,n2,n3,n4;
    if (c < 3){
      int row = row0 + (c+1)*64 + lrow;
      n0 = *(const float4*)(dt + row*DI + d0 + c4);
      n1 = *(const float4*)(xc + row*DI + d0 + c4);
      n2 = *(const float4*)(sz + row*DI + d0 + c4);
      n3 = *(const float4*)(Bm + row*DS + c4);
      n4 = *(const float4*)(Cm + row*DS + c4);
    }
    #pragma unroll 8
    for (int li=0; li<64; li++){
      float dtv = dtc[cur][li][dg];
      float xcv = xcc[cur][li][dg];
      float dA = __expf(dtv * A_ds);
      h = fmaf(dA, h, dtv * bc[cur][li][s] * xcv);
      float yp = h * cc[cur][li][s];
      yp += __shfl_xor(yp, 1, 64);
      yp += __shfl_xor(yp, 2, 64);
      yp += __shfl_xor(yp, 4, 64);
      yp += __shfl_xor(yp, 8, 64);
      if (s==0) yc[li][dg] = fmaf(xcv, Dv, yp) * szc[cur][li][dg];
    }
    __syncthreads();
    // coalesced y store
    {
      int row = row0 + c*64 + lrow;
      *(float4*)(y + row*DI + d0 + c4) = *(float4*)&yc[lrow][c4];
    }
    if (c < 3){
      *(float4*)&dtc[nxt][lrow][c4] = n0;
      *(float4*)&xcc[nxt][lrow][c4] = n1;
      *(float4*)&szc[nxt][lrow][c4] = n2;
      *(float4*)&bc[nxt][lrow][c4]  = n3;
      *(float4*)&cc[nxt][lrow][c4]  = n4;
    }
    __syncthreads();
  }
}

// ---------- out GEMM + relu + residual; 16 rows/block ----------
__global__ __launch_bounds__(256) void k_wout(
    const float* __restrict__ Wout_spa, const float* __restrict__ Wout_spe,
    const float* __restrict__ x_spa, const float* __restrict__ x_spe,
    const float* __restrict__ y, float* __restrict__ ae)
{
  __shared__ float yr[16][DI];     // 32 KB
  int tid=threadIdx.x;
  int r0=blockIdx.x*16;
  int branch = r0 >= BD*LD;
  const float* Wout = branch ? Wout_spe : Wout_spa;
  const float* xb   = branch ? x_spe    : x_spa;
  int rr0 = branch ? r0 - BD*LD : r0;
  for (int p=0;p<8;p++){
    int idx = tid + 256*p;         // 0..2047
    int r = idx >> 7, c4 = (idx & 127) * 4;
    *(float4*)&yr[r][c4] = *(const float4*)(y + (r0+r)*DI + c4);
  }
  __syncthreads();
  float acc[16];
  #pragma unroll
  for(int r=0;r<16;r++) acc[r]=0.f;
  for(int k=0;k<DI;k+=4){
    float w0 = Wout[(k+0)*DM + tid];
    float w1 = Wout[(k+1)*DM + tid];
    float w2 = Wout[(k+2)*DM + tid];
    float w3 = Wout[(k+3)*DM + tid];
    #pragma unroll
    for(int r=0;r<16;r++){
      float4 yv = *(float4*)&yr[r][k];
      acc[r] = fmaf(yv.x, w0, acc[r]);
      acc[r] = fmaf(yv.y, w1, acc[r]);
      acc[r] = fmaf(yv.z, w2, acc[r]);
      acc[r] = fmaf(yv.w, w3, acc[r]);
    }
  }
  #pragma unroll
  for(int r=0;r<16;r++)
    ae[(r0+r)*DM + tid] = fmaxf(acc[r],0.f) + xb[(rr0+r)*DM + tid];
}

// ---------- pool + gate fused ----------
__global__ __launch_bounds__(256) void k_poolgate(const float* __restrict__ ae,
    const float* __restrict__ fW, float* __restrict__ fw)
{
  __shared__ float p[DM];
  int b=blockIdx.x, c=threadIdx.x;
  const float* a0 = ae + (b*LD)*DM + c;
  const float* a1 = ae + ((BD + b)*LD)*DM + c;
  float s=0.f;
  #pragma unroll 8
  for(int l=0;l<LD;l++) s += a0[l*DM] + a1[l*DM];
  p[c] = s * (0.5f/LD);
  __syncthreads();
  float a=0.f;
  for(int k=0;k<DM;k+=4){
    a = fmaf(p[k+0], fW[(k+0)*DM+c], a);
    a = fmaf(p[k+1], fW[(k+1)*DM+c], a);
    a = fmaf(p[k+2], fW[(k+2)*DM+c], a);
    a = fmaf(p[k+3], fW[(k+3)*DM+c], a);
  }
  fw[b*DM+c]=1.f/(1.f+__expf(-a));
}

// ---------- final: out = ae*fw + ident (float4) ----------
__global__ __launch_bounds__(256) void k_final(const float* __restrict__ ae,
    const float* __restrict__ ident, const float* __restrict__ fw, float* __restrict__ out)
{
  int idx4 = blockIdx.x*256 + threadIdx.x;   // float4 index, 262144 total
  int row = idx4 >> 6;                        // global row 0..4095
  int b = (row >> 8) & 7;
  int c4 = (idx4 & 63) * 4;
  float4 av = *(const float4*)(ae + idx4*4);
  float4 iv = *(const float4*)(ident + idx4*4);
  float4 fv = *(const float4*)(fw + b*DM + c4);
  float4 o;
  o.x = fmaf(av.x, fv.x, iv.x);
  o.y = fmaf(av.y, fv.y, iv.y);
  o.z = fmaf(av.z, fv.z, iv.z);
  o.w = fmaf(av.w, fv.w, iv.w);
  *(float4*)(out + idx4*4) = o;
}

extern "C" void kernel_launch(void* const* d_in, const int* in_sizes, int n_in,
                              void* d_out, int out_size, void* d_ws, size_t ws_size,
                              hipStream_t stream) {
  const float* x_spa     = (const float*)d_in[0];
  const float* x_spe     = (const float*)d_in[1];
  const float* spa_ln_g  = (const float*)d_in[2];
  const float* spa_ln_b  = (const float*)d_in[3];
  const float* spa_W_in  = (const float*)d_in[4];
  const float* spa_cw    = (const float*)d_in[5];
  const float* spa_cb    = (const float*)d_in[6];
  const float* spa_W_x   = (const float*)d_in[7];
  const float* spa_W_dt  = (const float*)d_in[8];
  const float* spa_b_dt  = (const float*)d_in[9];
  const float* spa_A_log = (const float*)d_in[10];
  const float* spa_D     = (const float*)d_in[11];
  const float* spa_W_out = (const float*)d_in[12];
  const float* spe_ln_g  = (const float*)d_in[13];
  const float* spe_ln_b  = (const float*)d_in[14];
  const float* spe_W_in  = (const float*)d_in[15];
  const float* spe_cw    = (const float*)d_in[16];
  const float* spe_cb    = (const float*)d_in[17];
  const float* spe_W_x   = (const float*)d_in[18];
  const float* spe_W_dt  = (const float*)d_in[19];
  const float* spe_b_dt  = (const float*)d_in[20];
  const float* spe_A_log = (const float*)d_in[21];
  const float* spe_D     = (const float*)d_in[22];
  const float* spe_W_out = (const float*)d_in[23];
  const float* sc_W      = (const float*)d_in[24];
  const float* sc_b      = (const float*)d_in[25];
  const float* sc_ln_g   = (const float*)d_in[26];
  const float* sc_ln_b   = (const float*)d_in[27];
  const float* fusion_W  = (const float*)d_in[28];

  float* ws = (float*)d_ws;
  float* ident  = ws;                       // 4096*256
  float* xc_raw = ident  + NROWS*DM;        // 4096*512 (reused as y)
  float* sz     = xc_raw + NROWS*DI;        // 4096*512
  float* xc     = sz     + NROWS*DI;        // 4096*512
  float* dt     = xc     + NROWS*DI;        // 4096*512 (reused as ae)
  float* Bm     = dt     + NROWS*DI;        // 4096*16
  float* Cm     = Bm     + NROWS*DS;        // 4096*16
  float* pooled = Cm     + NROWS*DS;        // 8*256 (unused now)
  float* fw     = pooled + BD*DM;           // 8*256

  float* out = (float*)d_out;

  k_lnwin<<<NROWS/16, 256, 0, stream>>>(x_spa, x_spe, spa_ln_g, spa_ln_b, spe_ln_g, spe_ln_b,
                                        spa_W_in, spe_W_in, xc_raw, sz);
  k_convdt<<<NROWS/8, 256, 0, stream>>>(spa_cw, spa_cb, spa_W_x, spa_W_dt, spa_b_dt,
                                        spe_cw, spe_cb, spe_W_x, spe_W_dt, spe_b_dt,
                                        xc_raw, xc, dt, Bm, Cm);
  float* y = xc_raw;   // xc_raw dead after k_convdt
  k_scan<<<512, 256, 0, stream>>>(spa_A_log, spa_D, spe_A_log, spe_D, dt, xc, sz, Bm, Cm, y);
  k_shortcut<<<NROWS/16, 256, 0, stream>>>(x_spa, x_spe, sc_W, sc_b, sc_ln_g, sc_ln_b, ident);
  float* ae = dt;      // dt dead after k_scan
  k_wout<<<NROWS/16, 256, 0, stream>>>(spa_W_out, spe_W_out, x_spa, x_spe, y, ae);
  k_poolgate<<<BD, 256, 0, stream>>>(ae, fusion_W, fw);
  k_final<<<NROWS*DM/1024, 256, 0, stream>>>(ae, ident, fw, out);
}

// Round 4
// 279.158 us; speedup vs baseline: 1.2966x; 1.2656x over previous
//
#include <hip/hip_runtime.h>
#include <hip/hip_bf16.h>
#include <math.h>

#define BD 8      // B
#define LD 256    // L
#define DM 256    // D_MODEL
#define DS 16     // D_STATE
#define DI 512    // D_INNER
#define RK 16     // DT_RANK

#define NROWS (2*BD*LD)   // 4096 rows (both branches concatenated)
#define HALF_ROWS (BD*LD) // 2048

typedef __attribute__((ext_vector_type(8))) short bhalf8;   // 8 bf16 = 4 VGPR
typedef __attribute__((ext_vector_type(4))) float f32x4;

__device__ __forceinline__ float siluf(float x){ return x / (1.f + __expf(-x)); }
__device__ __forceinline__ float softplusf(float x){
  return fmaxf(x, 0.f) + log1pf(__expf(-fabsf(x)));
}
__device__ __forceinline__ unsigned short f2bf(float f){
  __hip_bfloat16 h = __float2bfloat16(f);   // RNE
  return *reinterpret_cast<unsigned short*>(&h);
}

// ================= weight transpose + bf16 cast =================
// Wt[c][k] = bf16(W[k][c]).  52 blocks, each does a 64k x 256c tile.
__global__ __launch_bounds__(256) void k_transpose(
    const float* __restrict__ Wi_spa, const float* __restrict__ Wi_spe,
    const float* __restrict__ Wo_spa, const float* __restrict__ Wo_spe,
    const float* __restrict__ scW,
    unsigned short* __restrict__ Wt_i_spa, unsigned short* __restrict__ Wt_i_spe,
    unsigned short* __restrict__ Wt_o_spa, unsigned short* __restrict__ Wt_o_spe,
    unsigned short* __restrict__ scWt)
{
  __shared__ unsigned short tile[256][68];
  int b = blockIdx.x;
  const float* W; unsigned short* Wt; int N, K, c0, k0;
  if (b < 32){
    int bb = b & 15;
    W  = (b < 16) ? Wi_spa  : Wi_spe;
    Wt = (b < 16) ? Wt_i_spa: Wt_i_spe;
    N = 1024; K = 256; c0 = (bb >> 2)*256; k0 = (bb & 3)*64;
  } else if (b < 48){
    int bb = b - 32; int h = bb >> 3; bb &= 7;
    W  = h ? Wo_spe  : Wo_spa;
    Wt = h ? Wt_o_spe: Wt_o_spa;
    N = 256; K = 512; c0 = 0; k0 = bb*64;
  } else {
    int bb = b - 48;
    W = scW; Wt = scWt;
    N = 256; K = 256; c0 = 0; k0 = bb*64;
  }
  int tid = threadIdx.x;
  int c = c0 + tid;
  #pragma unroll 8
  for (int kk=0; kk<64; kk++)
    tile[tid][kk] = f2bf(W[(k0+kk)*N + c]);
  __syncthreads();
  for (int p=0; p<16; p++){
    int i = tid + 256*p;
    int cl = i >> 4, kq = (i & 15)*4;
    uint2 v = *(const uint2*)&tile[cl][kq];
    *(uint2*)&Wt[(c0+cl)*K + k0 + kq] = v;
  }
}

// ================= LN + W_in GEMM (MFMA) =================
// grid 256: rg=bi>>2 (64 rows), cg=bi&3 (256 of 1024 cols)
__global__ __launch_bounds__(256) void k_lnwin(
    const float* __restrict__ x_spa, const float* __restrict__ x_spe,
    const float* __restrict__ g_spa, const float* __restrict__ b_spa,
    const float* __restrict__ g_spe, const float* __restrict__ b_spe,
    const unsigned short* __restrict__ Wt_spa, const unsigned short* __restrict__ Wt_spe,
    float* __restrict__ xc_raw, float* __restrict__ szout)
{
  __shared__ unsigned short At[64][264];   // 33.8 KB bf16 A tile
  __shared__ float red[64][4][2];
  __shared__ float mu[64], rs[64];
  int tid = threadIdx.x;
  int bi = blockIdx.x;
  int rg = bi >> 2, cg = bi & 3;
  int r0 = rg * 64;
  int branch = (r0 >= HALF_ROWS);
  const float* xb = branch ? x_spe : x_spa;
  const float* g  = branch ? g_spe : g_spa;
  const float* be = branch ? b_spe : b_spa;
  const unsigned short* Wt = branch ? Wt_spe : Wt_spa;
  int rr0 = branch ? r0 - HALF_ROWS : r0;

  // phase 1: LN stats (thread = row tid>>2, quarter tid&3)
  {
    int row = tid >> 2, q = tid & 3;
    const float* xp = xb + (rr0 + row)*DM + q*64;
    float s = 0.f, s2 = 0.f;
    #pragma unroll
    for (int i=0;i<16;i++){
      float4 v = *(const float4*)(xp + i*4);
      s  += v.x+v.y+v.z+v.w;
      s2 += v.x*v.x + v.y*v.y + v.z*v.z + v.w*v.w;
    }
    red[row][q][0] = s; red[row][q][1] = s2;
  }
  __syncthreads();
  if (tid < 64){
    float s  = red[tid][0][0]+red[tid][1][0]+red[tid][2][0]+red[tid][3][0];
    float s2 = red[tid][0][1]+red[tid][1][1]+red[tid][2][1]+red[tid][3][1];
    float m = s * (1.f/DM);
    float var = s2*(1.f/DM) - m*m;
    mu[tid] = m;
    rs[tid] = rsqrtf(var + 1e-6f);
  }
  __syncthreads();
  // phase 2: normalize + cvt + stage
  for (int p=0;p<16;p++){
    int i4 = tid + 256*p;            // 0..4095 float4s
    int r = i4 >> 6, kq = (i4 & 63)*4;
    float4 v  = *(const float4*)(xb + (rr0+r)*DM + kq);
    float4 gv = *(const float4*)(g + kq);
    float4 bv = *(const float4*)(be + kq);
    float m = mu[r], rv = rs[r];
    unsigned int lo = (unsigned int)f2bf((v.x-m)*rv*gv.x + bv.x)
                    | ((unsigned int)f2bf((v.y-m)*rv*gv.y + bv.y) << 16);
    unsigned int hi = (unsigned int)f2bf((v.z-m)*rv*gv.z + bv.z)
                    | ((unsigned int)f2bf((v.w-m)*rv*gv.w + bv.w) << 16);
    *(uint2*)&At[r][kq] = make_uint2(lo, hi);
  }
  __syncthreads();
  // phase 3: MFMA. wave w: rows w*16..+15, all 256 cols of this col-group
  int w = tid >> 6, lane = tid & 63;
  int m16 = lane & 15, quad = lane >> 4;
  int arow = w*16 + m16;
  bhalf8 af[8];
  #pragma unroll
  for (int ks=0; ks<8; ks++)
    af[ks] = *(const bhalf8*)&At[arow][ks*32 + quad*8];
  f32x4 acc[16];
  #pragma unroll
  for (int ct=0; ct<16; ct++) acc[ct] = (f32x4)(0.f);
  const unsigned short* Wb = Wt + (cg*256)*256;   // row stride K=256
  #pragma unroll
  for (int ks=0; ks<8; ks++){
    #pragma unroll
    for (int ct=0; ct<16; ct++){
      bhalf8 bf = *(const bhalf8*)&Wb[(ct*16 + m16)*256 + ks*32 + quad*8];
      acc[ct] = __builtin_amdgcn_mfma_f32_16x16x32_bf16(af[ks], bf, acc[ct], 0,0,0);
    }
  }
  // epilogue: cg 0,1 -> xc_raw cols cg*256 ; cg 2,3 -> silu -> sz cols (cg-2)*256
  bool isz = (cg >= 2);
  float* outp = isz ? szout : xc_raw;
  int cbase = (cg & 1)*256;
  #pragma unroll
  for (int ct=0; ct<16; ct++){
    #pragma unroll
    for (int e=0;e<4;e++){
      int row = r0 + w*16 + quad*4 + e;
      int col = cbase + ct*16 + m16;
      float v = acc[ct][e];
      if (isz) v = siluf(v);
      outp[row*DI + col] = v;
    }
  }
}

// ================= shortcut GEMM + bias + LN (MFMA) =================
// grid 128: 32 rows/block, full 256 cols
__global__ __launch_bounds__(256) void k_shortcut(
    const float* __restrict__ x_spa, const float* __restrict__ x_spe,
    const unsigned short* __restrict__ scWt, const float* __restrict__ sc_b,
    const float* __restrict__ ln_g, const float* __restrict__ ln_b,
    float* __restrict__ ident)
{
  __shared__ unsigned short At[32][264];   // 16.9 KB
  __shared__ float Dt[32][260];            // 33.3 KB
  __shared__ float red[32][4][2];
  __shared__ float mu[32], rs[32];
  int tid = threadIdx.x;
  int r0 = blockIdx.x * 32;
  int branch = (r0 >= HALF_ROWS);
  const float* xb = branch ? x_spe : x_spa;
  int rr0 = branch ? r0 - HALF_ROWS : r0;
  // stage A = x (bf16)
  for (int p=0;p<8;p++){
    int i4 = tid + 256*p;
    int r = i4 >> 6, kq = (i4 & 63)*4;
    float4 v = *(const float4*)(xb + (rr0+r)*DM + kq);
    unsigned int lo = (unsigned int)f2bf(v.x) | ((unsigned int)f2bf(v.y) << 16);
    unsigned int hi = (unsigned int)f2bf(v.z) | ((unsigned int)f2bf(v.w) << 16);
    *(uint2*)&At[r][kq] = make_uint2(lo, hi);
  }
  __syncthreads();
  int w = tid >> 6, lane = tid & 63;
  int m16 = lane & 15, quad = lane >> 4;
  int rt = w >> 1;        // row tile 0/1
  int ch = w & 1;         // col half: cols ch*128
  bhalf8 af[8];
  #pragma unroll
  for (int ks=0; ks<8; ks++)
    af[ks] = *(const bhalf8*)&At[rt*16 + m16][ks*32 + quad*8];
  f32x4 acc[8];
  #pragma unroll
  for (int ct=0; ct<8; ct++) acc[ct] = (f32x4)(0.f);
  #pragma unroll
  for (int ks=0; ks<8; ks++){
    #pragma unroll
    for (int ct=0; ct<8; ct++){
      bhalf8 bf = *(const bhalf8*)&scWt[(ch*128 + ct*16 + m16)*256 + ks*32 + quad*8];
      acc[ct] = __builtin_amdgcn_mfma_f32_16x16x32_bf16(af[ks], bf, acc[ct], 0,0,0);
    }
  }
  // D + bias -> LDS
  #pragma unroll
  for (int ct=0; ct<8; ct++){
    #pragma unroll
    for (int e=0;e<4;e++){
      int row = rt*16 + quad*4 + e;
      int col = ch*128 + ct*16 + m16;
      Dt[row][col] = acc[ct][e] + sc_b[col];
    }
  }
  __syncthreads();
  // LN stats
  if (tid < 128){
    int row = tid >> 2, q = tid & 3;
    float s = 0.f, s2 = 0.f;
    #pragma unroll
    for (int i=0;i<16;i++){
      float4 v = *(const float4*)&Dt[row][q*64 + i*4];
      s  += v.x+v.y+v.z+v.w;
      s2 += v.x*v.x + v.y*v.y + v.z*v.z + v.w*v.w;
    }
    red[row][q][0] = s; red[row][q][1] = s2;
  }
  __syncthreads();
  if (tid < 32){
    float s  = red[tid][0][0]+red[tid][1][0]+red[tid][2][0]+red[tid][3][0];
    float s2 = red[tid][0][1]+red[tid][1][1]+red[tid][2][1]+red[tid][3][1];
    float m = s * (1.f/DM);
    float var = s2*(1.f/DM) - m*m;
    mu[tid] = m;
    rs[tid] = rsqrtf(var + 1e-5f);
  }
  __syncthreads();
  float gg = ln_g[tid], bb = ln_b[tid];
  #pragma unroll 4
  for (int r=0;r<32;r++)
    ident[(r0+r)*DM + tid] = (Dt[r][tid]-mu[r])*rs[r]*gg + bb;
}

// ================= causal conv + silu -> xc ; x_dbl ; dt (unchanged) =================
__global__ __launch_bounds__(256) void k_convdt(
    const float* __restrict__ cw_spa, const float* __restrict__ cb_spa,
    const float* __restrict__ Wx_spa, const float* __restrict__ Wdt_spa, const float* __restrict__ bdt_spa,
    const float* __restrict__ cw_spe, const float* __restrict__ cb_spe,
    const float* __restrict__ Wx_spe, const float* __restrict__ Wdt_spe, const float* __restrict__ bdt_spe,
    const float* __restrict__ xc_raw,
    float* __restrict__ xc, float* __restrict__ dt,
    float* __restrict__ Bm, float* __restrict__ Cm)
{
  __shared__ float raw[11][DI];
  __shared__ float xcs[8][DI];
  __shared__ float xpart[384][2];
  __shared__ float xdbl[8][48];
  int tid=threadIdx.x;
  int r0 = blockIdx.x*8;
  int branch = r0 >= HALF_ROWS;
  int l0 = r0 & (LD-1);
  const float* cw  = branch ? cw_spe : cw_spa;
  const float* cb  = branch ? cb_spe : cb_spa;
  const float* Wx  = branch ? Wx_spe : Wx_spa;
  const float* Wdt = branch ? Wdt_spe: Wdt_spa;
  const float* bdt = branch ? bdt_spe: bdt_spa;
  for (int idx=tid; idx<1408; idx+=256){
    int j = idx >> 7, c4 = (idx & 127) * 4;
    int lrow = l0 - 3 + j;
    float4 v = make_float4(0.f,0.f,0.f,0.f);
    if (lrow >= 0) v = *(const float4*)(xc_raw + (r0-3+j)*DI + c4);
    *(float4*)&raw[j][c4] = v;
  }
  __syncthreads();
  {
    float4 cw4a = *(const float4*)(cw + 4*tid);
    float4 cw4b = *(const float4*)(cw + 4*(tid+256));
    float cba = cb[tid], cbb = cb[tid+256];
    #pragma unroll
    for (int r=0;r<8;r++){
      float a = cba;
      a = fmaf(raw[r+0][tid], cw4a.x, a);
      a = fmaf(raw[r+1][tid], cw4a.y, a);
      a = fmaf(raw[r+2][tid], cw4a.z, a);
      a = fmaf(raw[r+3][tid], cw4a.w, a);
      xcs[r][tid] = siluf(a);
      float b = cbb;
      b = fmaf(raw[r+0][tid+256], cw4b.x, b);
      b = fmaf(raw[r+1][tid+256], cw4b.y, b);
      b = fmaf(raw[r+2][tid+256], cw4b.z, b);
      b = fmaf(raw[r+3][tid+256], cw4b.w, b);
      xcs[r][tid+256] = siluf(b);
    }
  }
  __syncthreads();
  for (int idx=tid; idx<1024; idx+=256){
    int r = idx >> 7, c4 = (idx & 127) * 4;
    *(float4*)(xc + (r0+r)*DI + c4) = *(float4*)&xcs[r][c4];
  }
  for (int p=0;p<3;p++){
    int id = tid + 256*p;
    int half = id & 1, o = id >> 1;
    int r = o / 48, c = o - r*48;
    const float* wp = Wx + c + half*256*48;
    const float* xp = &xcs[r][half*256];
    float a=0.f;
    for (int k=0;k<256;k+=4){
      float4 xv = *(const float4*)(xp + k);
      a = fmaf(xv.x, wp[(k+0)*48], a);
      a = fmaf(xv.y, wp[(k+1)*48], a);
      a = fmaf(xv.z, wp[(k+2)*48], a);
      a = fmaf(xv.w, wp[(k+3)*48], a);
    }
    xpart[o][half] = a;
  }
  __syncthreads();
  for (int o=tid;o<384;o+=256){
    int r = o / 48, c = o - r*48;
    float a = xpart[o][0] + xpart[o][1];
    xdbl[r][c] = a;
    int gr = r0 + r;
    if (c>=16 && c<32)      Bm[gr*DS + c-16] = a;
    else if (c>=32)         Cm[gr*DS + c-32] = a;
  }
  __syncthreads();
  {
    float wdt0[16], wdt1[16];
    #pragma unroll
    for (int j=0;j<16;j++){ wdt0[j]=Wdt[j*DI+tid]; wdt1[j]=Wdt[j*DI+tid+256]; }
    float b0 = bdt[tid], b1 = bdt[tid+256];
    #pragma unroll
    for (int r=0;r<8;r++){
      float a0=b0, a1=b1;
      #pragma unroll
      for (int j=0;j<16;j++){
        float xv = xdbl[r][j];
        a0 = fmaf(xv, wdt0[j], a0);
        a1 = fmaf(xv, wdt1[j], a1);
      }
      dt[(r0+r)*DI + tid]       = softplusf(a0);
      dt[(r0+r)*DI + tid + 256] = softplusf(a1);
    }
  }
}

// ================= selective scan v3: no shuffles =================
// 512 blocks x 256 thr; thread (dg=tid>>4, s=tid&15); 16-step chunks.
__global__ __launch_bounds__(256) void k_scan(
    const float* __restrict__ Alog_spa, const float* __restrict__ Dp_spa,
    const float* __restrict__ Alog_spe, const float* __restrict__ Dp_spe,
    const float* __restrict__ dt, const float* __restrict__ xc,
    const float* __restrict__ sz, const float* __restrict__ Bm,
    const float* __restrict__ Cm, float* __restrict__ y)
{
  __shared__ float ypbuf[16][260];   // swizzled columns
  __shared__ float Dsh[16];
  int tid = threadIdx.x;
  int bi = blockIdx.x;
  int branch = bi >> 8;
  int rem = bi & 255;
  int b = rem >> 5;
  int d0 = (rem & 31) * 16;
  const float* Alog = branch ? Alog_spe : Alog_spa;
  const float* Dp   = branch ? Dp_spe   : Dp_spa;
  int dg = tid >> 4, s = tid & 15;
  int d = d0 + dg;
  float A_ds = -__expf(Alog[d*DS + s]);
  if (tid < 16) Dsh[tid] = Dp[d0 + tid];
  int row0 = branch*HALF_ROWS + b*LD;
  int rli = tid >> 4, rdd = tid & 15;       // reduction coords
  float h = 0.f;
  for (int c=0; c<16; c++){
    int rbase = row0 + c*16;
    float rdt[16], rxc[16], rB[16], rC[16];
    #pragma unroll
    for (int li=0; li<16; li++){
      rdt[li] = dt[(rbase+li)*DI + d];
      rxc[li] = xc[(rbase+li)*DI + d];
      rB[li]  = Bm[(rbase+li)*DS + s];
      rC[li]  = Cm[(rbase+li)*DS + s];
    }
    __syncthreads();   // prev reduction done; ypbuf free
    #pragma unroll
    for (int li=0; li<16; li++){
      float dA = __expf(rdt[li] * A_ds);
      h = fmaf(dA, h, rdt[li] * rB[li] * rxc[li]);
      ypbuf[li][s*16 + ((dg + s) & 15)] = h * rC[li];
    }
    __syncthreads();
    // reduction: one output per thread (li=tid>>4, dd=tid&15)
    float acc = 0.f;
    #pragma unroll
    for (int ss=0; ss<16; ss++)
      acc += ypbuf[rli][ss*16 + ((rdd + ss) & 15)];
    int grow = rbase + rli;
    float xcv = xc[grow*DI + d0 + rdd];
    float szv = sz[grow*DI + d0 + rdd];
    y[grow*DI + d0 + rdd] = fmaf(xcv, Dsh[rdd], acc) * szv;
  }
}

// ================= W_out GEMM + relu + residual (MFMA) =================
// grid 256: 16 rows/block, 256 cols; wave w -> cols w*64
__global__ __launch_bounds__(256) void k_wout(
    const unsigned short* __restrict__ Wt_spa, const unsigned short* __restrict__ Wt_spe,
    const float* __restrict__ x_spa, const float* __restrict__ x_spe,
    const float* __restrict__ y, float* __restrict__ ae)
{
  __shared__ unsigned short At[16][520];   // 16.6 KB
  int tid = threadIdx.x;
  int r0 = blockIdx.x * 16;
  int branch = (r0 >= HALF_ROWS);
  const unsigned short* Wt = branch ? Wt_spe : Wt_spa;
  const float* xb = branch ? x_spe : x_spa;
  int rr0 = branch ? r0 - HALF_ROWS : r0;
  for (int p=0;p<8;p++){
    int i4 = tid + 256*p;          // 0..2047
    int r = i4 >> 7, kq = (i4 & 127)*4;
    float4 v = *(const float4*)(y + (r0+r)*DI + kq);
    unsigned int lo = (unsigned int)f2bf(v.x) | ((unsigned int)f2bf(v.y) << 16);
    unsigned int hi = (unsigned int)f2bf(v.z) | ((unsigned int)f2bf(v.w) << 16);
    *(uint2*)&At[r][kq] = make_uint2(lo, hi);
  }
  __syncthreads();
  int w = tid >> 6, lane = tid & 63;
  int m16 = lane & 15, quad = lane >> 4;
  bhalf8 af[16];
  #pragma unroll
  for (int ks=0; ks<16; ks++)
    af[ks] = *(const bhalf8*)&At[m16][ks*32 + quad*8];
  f32x4 acc[4];
  #pragma unroll
  for (int ct=0; ct<4; ct++) acc[ct] = (f32x4)(0.f);
  #pragma unroll
  for (int ks=0; ks<16; ks++){
    #pragma unroll
    for (int ct=0; ct<4; ct++){
      bhalf8 bf = *(const bhalf8*)&Wt[(w*64 + ct*16 + m16)*512 + ks*32 + quad*8];
      acc[ct] = __builtin_amdgcn_mfma_f32_16x16x32_bf16(af[ks], bf, acc[ct], 0,0,0);
    }
  }
  #pragma unroll
  for (int ct=0; ct<4; ct++){
    #pragma unroll
    for (int e=0;e<4;e++){
      int row = quad*4 + e;
      int col = w*64 + ct*16 + m16;
      float v = fmaxf(acc[ct][e], 0.f) + xb[(rr0+row)*DM + col];
      ae[(r0+row)*DM + col] = v;
    }
  }
}

// ================= pool + gate fused =================
__global__ __launch_bounds__(256) void k_poolgate(const float* __restrict__ ae,
    const float* __restrict__ fW, float* __restrict__ fw)
{
  __shared__ float p[DM];
  int b=blockIdx.x, c=threadIdx.x;
  const float* a0 = ae + (b*LD)*DM + c;
  const float* a1 = ae + ((BD + b)*LD)*DM + c;
  float s=0.f;
  #pragma unroll 8
  for(int l=0;l<LD;l++) s += a0[l*DM] + a1[l*DM];
  p[c] = s * (0.5f/LD);
  __syncthreads();
  float a=0.f;
  for(int k=0;k<DM;k+=4){
    a = fmaf(p[k+0], fW[(k+0)*DM+c], a);
    a = fmaf(p[k+1], fW[(k+1)*DM+c], a);
    a = fmaf(p[k+2], fW[(k+2)*DM+c], a);
    a = fmaf(p[k+3], fW[(k+3)*DM+c], a);
  }
  fw[b*DM+c]=1.f/(1.f+__expf(-a));
}

// ================= final: out = ae*fw + ident =================
__global__ __launch_bounds__(256) void k_final(const float* __restrict__ ae,
    const float* __restrict__ ident, const float* __restrict__ fw, float* __restrict__ out)
{
  int idx4 = blockIdx.x*256 + threadIdx.x;
  int row = idx4 >> 6;
  int b = (row >> 8) & 7;
  int c4 = (idx4 & 63) * 4;
  float4 av = *(const float4*)(ae + idx4*4);
  float4 iv = *(const float4*)(ident + idx4*4);
  float4 fv = *(const float4*)(fw + b*DM + c4);
  float4 o;
  o.x = fmaf(av.x, fv.x, iv.x);
  o.y = fmaf(av.y, fv.y, iv.y);
  o.z = fmaf(av.z, fv.z, iv.z);
  o.w = fmaf(av.w, fv.w, iv.w);
  *(float4*)(out + idx4*4) = o;
}

extern "C" void kernel_launch(void* const* d_in, const int* in_sizes, int n_in,
                              void* d_out, int out_size, void* d_ws, size_t ws_size,
                              hipStream_t stream) {
  const float* x_spa     = (const float*)d_in[0];
  const float* x_spe     = (const float*)d_in[1];
  const float* spa_ln_g  = (const float*)d_in[2];
  const float* spa_ln_b  = (const float*)d_in[3];
  const float* spa_W_in  = (const float*)d_in[4];
  const float* spa_cw    = (const float*)d_in[5];
  const float* spa_cb    = (const float*)d_in[6];
  const float* spa_W_x   = (const float*)d_in[7];
  const float* spa_W_dt  = (const float*)d_in[8];
  const float* spa_b_dt  = (const float*)d_in[9];
  const float* spa_A_log = (const float*)d_in[10];
  const float* spa_D     = (const float*)d_in[11];
  const float* spa_W_out = (const float*)d_in[12];
  const float* spe_ln_g  = (const float*)d_in[13];
  const float* spe_ln_b  = (const float*)d_in[14];
  const float* spe_W_in  = (const float*)d_in[15];
  const float* spe_cw    = (const float*)d_in[16];
  const float* spe_cb    = (const float*)d_in[17];
  const float* spe_W_x   = (const float*)d_in[18];
  const float* spe_W_dt  = (const float*)d_in[19];
  const float* spe_b_dt  = (const float*)d_in[20];
  const float* spe_A_log = (const float*)d_in[21];
  const float* spe_D     = (const float*)d_in[22];
  const float* spe_W_out = (const float*)d_in[23];
  const float* sc_W      = (const float*)d_in[24];
  const float* sc_b      = (const float*)d_in[25];
  const float* sc_ln_g   = (const float*)d_in[26];
  const float* sc_ln_b   = (const float*)d_in[27];
  const float* fusion_W  = (const float*)d_in[28];

  float* ws = (float*)d_ws;
  float* ident  = ws;                       // 4096*256
  float* xc_raw = ident  + NROWS*DM;        // 4096*512 (reused as y)
  float* sz     = xc_raw + NROWS*DI;        // 4096*512
  float* xc     = sz     + NROWS*DI;        // 4096*512
  float* dt     = xc     + NROWS*DI;        // 4096*512 (reused as ae)
  float* Bm     = dt     + NROWS*DI;        // 4096*16
  float* Cm     = Bm     + NROWS*DS;        // 4096*16
  float* fw     = Cm     + NROWS*DS;        // 8*256
  unsigned short* Wt_i_spa = (unsigned short*)(fw + BD*DM);
  unsigned short* Wt_i_spe = Wt_i_spa + 1024*256;
  unsigned short* Wt_o_spa = Wt_i_spe + 1024*256;
  unsigned short* Wt_o_spe = Wt_o_spa + 256*512;
  unsigned short* scWt     = Wt_o_spe + 256*512;

  float* out = (float*)d_out;

  k_transpose<<<52, 256, 0, stream>>>(spa_W_in, spe_W_in, spa_W_out, spe_W_out, sc_W,
                                      Wt_i_spa, Wt_i_spe, Wt_o_spa, Wt_o_spe, scWt);
  k_lnwin<<<256, 256, 0, stream>>>(x_spa, x_spe, spa_ln_g, spa_ln_b, spe_ln_g, spe_ln_b,
                                   Wt_i_spa, Wt_i_spe, xc_raw, sz);
  k_convdt<<<NROWS/8, 256, 0, stream>>>(spa_cw, spa_cb, spa_W_x, spa_W_dt, spa_b_dt,
                                        spe_cw, spe_cb, spe_W_x, spe_W_dt, spe_b_dt,
                                        xc_raw, xc, dt, Bm, Cm);
  float* y = xc_raw;   // xc_raw dead after k_convdt
  k_scan<<<512, 256, 0, stream>>>(spa_A_log, spa_D, spe_A_log, spe_D, dt, xc, sz, Bm, Cm, y);
  k_shortcut<<<128, 256, 0, stream>>>(x_spa, x_spe, scWt, sc_b, sc_ln_g, sc_ln_b, ident);
  float* ae = dt;      // dt dead after k_scan
  k_wout<<<256, 256, 0, stream>>>(Wt_o_spa, Wt_o_spe, x_spa, x_spe, y, ae);
  k_poolgate<<<BD, 256, 0, stream>>>(ae, fusion_W, fw);
  k_final<<<NROWS*DM/1024, 256, 0, stream>>>(ae, ident, fw, out);
}

// Round 5
// 248.377 us; speedup vs baseline: 1.4573x; 1.1239x over previous
//
#include <hip/hip_runtime.h>
#include <hip/hip_bf16.h>
#include <math.h>

#define BD 8      // B
#define LD 256    // L
#define DM 256    // D_MODEL
#define DS 16     // D_STATE
#define DI 512    // D_INNER
#define RK 16     // DT_RANK

#define NROWS (2*BD*LD)   // 4096 rows (both branches concatenated)
#define HALF_ROWS (BD*LD) // 2048

typedef __attribute__((ext_vector_type(8))) short bhalf8;   // 8 bf16 = 4 VGPR
typedef __attribute__((ext_vector_type(4))) float f32x4;

__device__ __forceinline__ float siluf(float x){ return x / (1.f + __expf(-x)); }
__device__ __forceinline__ float softplusf(float x){
  return fmaxf(x, 0.f) + log1pf(__expf(-fabsf(x)));
}
__device__ __forceinline__ unsigned short f2bf(float f){
  __hip_bfloat16 h = __float2bfloat16(f);   // RNE
  return *reinterpret_cast<unsigned short*>(&h);
}

// ================= weight transpose + bf16 cast =================
// blocks 0..51: Wt[c][k] = bf16(W[k][c]) for W_in/W_out/sc_W (64k x 256c tiles)
// blocks 52..59: Wxt[c][k] = bf16(W_x[k][c]) padded to 64 cols (128k chunks)
__global__ __launch_bounds__(256) void k_transpose(
    const float* __restrict__ Wi_spa, const float* __restrict__ Wi_spe,
    const float* __restrict__ Wo_spa, const float* __restrict__ Wo_spe,
    const float* __restrict__ scW,
    const float* __restrict__ Wx_spa, const float* __restrict__ Wx_spe,
    unsigned short* __restrict__ Wt_i_spa, unsigned short* __restrict__ Wt_i_spe,
    unsigned short* __restrict__ Wt_o_spa, unsigned short* __restrict__ Wt_o_spe,
    unsigned short* __restrict__ scWt,
    unsigned short* __restrict__ Wxt_spa, unsigned short* __restrict__ Wxt_spe)
{
  __shared__ unsigned short tile[256][68];   // 34.8 KB
  __shared__ float tile2[128][49];           // 25.1 KB
  int b = blockIdx.x;
  int tid = threadIdx.x;
  if (b >= 52){
    int bb = b - 52;
    int branch = bb >> 2, chunk = bb & 3;
    int k0 = chunk*128;
    const float* Wx = branch ? Wx_spe : Wx_spa;
    unsigned short* Wxt = branch ? Wxt_spe : Wxt_spa;
    for (int i=tid; i<128*48; i+=256){
      int kk = i/48, c = i - kk*48;
      tile2[kk][c] = Wx[(k0+kk)*48 + c];
    }
    __syncthreads();
    for (int i=tid; i<64*128; i+=256){
      int cc = i >> 7, kk = i & 127;
      float v = (cc < 48) ? tile2[kk][cc] : 0.f;
      Wxt[cc*512 + k0 + kk] = f2bf(v);
    }
    return;
  }
  const float* W; unsigned short* Wt; int N, K, c0, k0;
  if (b < 32){
    int bb = b & 15;
    W  = (b < 16) ? Wi_spa  : Wi_spe;
    Wt = (b < 16) ? Wt_i_spa: Wt_i_spe;
    N = 1024; K = 256; c0 = (bb >> 2)*256; k0 = (bb & 3)*64;
  } else if (b < 48){
    int bb = b - 32; int h = bb >> 3; bb &= 7;
    W  = h ? Wo_spe  : Wo_spa;
    Wt = h ? Wt_o_spe: Wt_o_spa;
    N = 256; K = 512; c0 = 0; k0 = bb*64;
  } else {
    int bb = b - 48;
    W = scW; Wt = scWt;
    N = 256; K = 256; c0 = 0; k0 = bb*64;
  }
  int c = c0 + tid;
  #pragma unroll 8
  for (int kk=0; kk<64; kk++)
    tile[tid][kk] = f2bf(W[(k0+kk)*N + c]);
  __syncthreads();
  for (int p=0; p<16; p++){
    int i = tid + 256*p;
    int cl = i >> 4, kq = (i & 15)*4;
    uint2 v = *(const uint2*)&tile[cl][kq];
    *(uint2*)&Wt[(c0+cl)*K + k0 + kq] = v;
  }
}

// ================= LN + W_in GEMM (MFMA) =================
// grid 256: rg=bi>>2 (64 rows), cg=bi&3 (256 of 1024 cols)
__global__ __launch_bounds__(256) void k_lnwin(
    const float* __restrict__ x_spa, const float* __restrict__ x_spe,
    const float* __restrict__ g_spa, const float* __restrict__ b_spa,
    const float* __restrict__ g_spe, const float* __restrict__ b_spe,
    const unsigned short* __restrict__ Wt_spa, const unsigned short* __restrict__ Wt_spe,
    float* __restrict__ xc_raw, float* __restrict__ szout)
{
  __shared__ unsigned short At[64][264];   // 33.8 KB bf16 A tile
  __shared__ float red[64][4][2];
  __shared__ float mu[64], rs[64];
  int tid = threadIdx.x;
  int bi = blockIdx.x;
  int rg = bi >> 2, cg = bi & 3;
  int r0 = rg * 64;
  int branch = (r0 >= HALF_ROWS);
  const float* xb = branch ? x_spe : x_spa;
  const float* g  = branch ? g_spe : g_spa;
  const float* be = branch ? b_spe : b_spa;
  const unsigned short* Wt = branch ? Wt_spe : Wt_spa;
  int rr0 = branch ? r0 - HALF_ROWS : r0;

  // phase 1: LN stats (thread = row tid>>2, quarter tid&3)
  {
    int row = tid >> 2, q = tid & 3;
    const float* xp = xb + (rr0 + row)*DM + q*64;
    float s = 0.f, s2 = 0.f;
    #pragma unroll
    for (int i=0;i<16;i++){
      float4 v = *(const float4*)(xp + i*4);
      s  += v.x+v.y+v.z+v.w;
      s2 += v.x*v.x + v.y*v.y + v.z*v.z + v.w*v.w;
    }
    red[row][q][0] = s; red[row][q][1] = s2;
  }
  __syncthreads();
  if (tid < 64){
    float s  = red[tid][0][0]+red[tid][1][0]+red[tid][2][0]+red[tid][3][0];
    float s2 = red[tid][0][1]+red[tid][1][1]+red[tid][2][1]+red[tid][3][1];
    float m = s * (1.f/DM);
    float var = s2*(1.f/DM) - m*m;
    mu[tid] = m;
    rs[tid] = rsqrtf(var + 1e-6f);
  }
  __syncthreads();
  // phase 2: normalize + cvt + stage
  for (int p=0;p<16;p++){
    int i4 = tid + 256*p;            // 0..4095 float4s
    int r = i4 >> 6, kq = (i4 & 63)*4;
    float4 v  = *(const float4*)(xb + (rr0+r)*DM + kq);
    float4 gv = *(const float4*)(g + kq);
    float4 bv = *(const float4*)(be + kq);
    float m = mu[r], rv = rs[r];
    unsigned int lo = (unsigned int)f2bf((v.x-m)*rv*gv.x + bv.x)
                    | ((unsigned int)f2bf((v.y-m)*rv*gv.y + bv.y) << 16);
    unsigned int hi = (unsigned int)f2bf((v.z-m)*rv*gv.z + bv.z)
                    | ((unsigned int)f2bf((v.w-m)*rv*gv.w + bv.w) << 16);
    *(uint2*)&At[r][kq] = make_uint2(lo, hi);
  }
  __syncthreads();
  // phase 3: MFMA. wave w: rows w*16..+15, all 256 cols of this col-group
  int w = tid >> 6, lane = tid & 63;
  int m16 = lane & 15, quad = lane >> 4;
  int arow = w*16 + m16;
  bhalf8 af[8];
  #pragma unroll
  for (int ks=0; ks<8; ks++)
    af[ks] = *(const bhalf8*)&At[arow][ks*32 + quad*8];
  f32x4 acc[16];
  #pragma unroll
  for (int ct=0; ct<16; ct++) acc[ct] = (f32x4)(0.f);
  const unsigned short* Wb = Wt + (cg*256)*256;   // row stride K=256
  #pragma unroll
  for (int ks=0; ks<8; ks++){
    #pragma unroll
    for (int ct=0; ct<16; ct++){
      bhalf8 bf = *(const bhalf8*)&Wb[(ct*16 + m16)*256 + ks*32 + quad*8];
      acc[ct] = __builtin_amdgcn_mfma_f32_16x16x32_bf16(af[ks], bf, acc[ct], 0,0,0);
    }
  }
  // epilogue: cg 0,1 -> xc_raw cols cg*256 ; cg 2,3 -> silu -> sz cols (cg-2)*256
  bool isz = (cg >= 2);
  float* outp = isz ? szout : xc_raw;
  int cbase = (cg & 1)*256;
  #pragma unroll
  for (int ct=0; ct<16; ct++){
    #pragma unroll
    for (int e=0;e<4;e++){
      int row = r0 + w*16 + quad*4 + e;
      int col = cbase + ct*16 + m16;
      float v = acc[ct][e];
      if (isz) v = siluf(v);
      outp[row*DI + col] = v;
    }
  }
}

// ================= shortcut GEMM + bias + LN (MFMA) =================
__global__ __launch_bounds__(256) void k_shortcut(
    const float* __restrict__ x_spa, const float* __restrict__ x_spe,
    const unsigned short* __restrict__ scWt, const float* __restrict__ sc_b,
    const float* __restrict__ ln_g, const float* __restrict__ ln_b,
    float* __restrict__ ident)
{
  __shared__ unsigned short At[32][264];   // 16.9 KB
  __shared__ float Dt[32][260];            // 33.3 KB
  __shared__ float red[32][4][2];
  __shared__ float mu[32], rs[32];
  int tid = threadIdx.x;
  int r0 = blockIdx.x * 32;
  int branch = (r0 >= HALF_ROWS);
  const float* xb = branch ? x_spe : x_spa;
  int rr0 = branch ? r0 - HALF_ROWS : r0;
  for (int p=0;p<8;p++){
    int i4 = tid + 256*p;
    int r = i4 >> 6, kq = (i4 & 63)*4;
    float4 v = *(const float4*)(xb + (rr0+r)*DM + kq);
    unsigned int lo = (unsigned int)f2bf(v.x) | ((unsigned int)f2bf(v.y) << 16);
    unsigned int hi = (unsigned int)f2bf(v.z) | ((unsigned int)f2bf(v.w) << 16);
    *(uint2*)&At[r][kq] = make_uint2(lo, hi);
  }
  __syncthreads();
  int w = tid >> 6, lane = tid & 63;
  int m16 = lane & 15, quad = lane >> 4;
  int rt = w >> 1;        // row tile 0/1
  int ch = w & 1;         // col half: cols ch*128
  bhalf8 af[8];
  #pragma unroll
  for (int ks=0; ks<8; ks++)
    af[ks] = *(const bhalf8*)&At[rt*16 + m16][ks*32 + quad*8];
  f32x4 acc[8];
  #pragma unroll
  for (int ct=0; ct<8; ct++) acc[ct] = (f32x4)(0.f);
  #pragma unroll
  for (int ks=0; ks<8; ks++){
    #pragma unroll
    for (int ct=0; ct<8; ct++){
      bhalf8 bf = *(const bhalf8*)&scWt[(ch*128 + ct*16 + m16)*256 + ks*32 + quad*8];
      acc[ct] = __builtin_amdgcn_mfma_f32_16x16x32_bf16(af[ks], bf, acc[ct], 0,0,0);
    }
  }
  #pragma unroll
  for (int ct=0; ct<8; ct++){
    #pragma unroll
    for (int e=0;e<4;e++){
      int row = rt*16 + quad*4 + e;
      int col = ch*128 + ct*16 + m16;
      Dt[row][col] = acc[ct][e] + sc_b[col];
    }
  }
  __syncthreads();
  if (tid < 128){
    int row = tid >> 2, q = tid & 3;
    float s = 0.f, s2 = 0.f;
    #pragma unroll
    for (int i=0;i<16;i++){
      float4 v = *(const float4*)&Dt[row][q*64 + i*4];
      s  += v.x+v.y+v.z+v.w;
      s2 += v.x*v.x + v.y*v.y + v.z*v.z + v.w*v.w;
    }
    red[row][q][0] = s; red[row][q][1] = s2;
  }
  __syncthreads();
  if (tid < 32){
    float s  = red[tid][0][0]+red[tid][1][0]+red[tid][2][0]+red[tid][3][0];
    float s2 = red[tid][0][1]+red[tid][1][1]+red[tid][2][1]+red[tid][3][1];
    float m = s * (1.f/DM);
    float var = s2*(1.f/DM) - m*m;
    mu[tid] = m;
    rs[tid] = rsqrtf(var + 1e-5f);
  }
  __syncthreads();
  float gg = ln_g[tid], bb = ln_b[tid];
  #pragma unroll 4
  for (int r=0;r<32;r++)
    ident[(r0+r)*DM + tid] = (Dt[r][tid]-mu[r])*rs[r]*gg + bb;
}

// ================= causal conv + silu (register history, no LDS) =================
// grid 256: 16 rows/block; thread owns cols 2t, 2t+1
__global__ __launch_bounds__(256) void k_conv(
    const float* __restrict__ cw_spa, const float* __restrict__ cb_spa,
    const float* __restrict__ cw_spe, const float* __restrict__ cb_spe,
    const float* __restrict__ xc_raw,
    float* __restrict__ xc, unsigned short* __restrict__ xcb)
{
  int tid = threadIdx.x;
  int r0 = blockIdx.x * 16;
  int branch = r0 >= HALF_ROWS;
  int l0 = r0 & (LD-1);
  const float* cw = branch ? cw_spe : cw_spa;
  const float* cb = branch ? cb_spe : cb_spa;
  int c = tid*2;
  float4 w0 = *(const float4*)(cw + 4*c);
  float4 w1 = *(const float4*)(cw + 4*(c+1));
  float2 bias = *(const float2*)(cb + c);
  float2 h0, h1, h2;
  if (l0 > 0){
    h0 = *(const float2*)(xc_raw + (r0-3)*DI + c);
    h1 = *(const float2*)(xc_raw + (r0-2)*DI + c);
    h2 = *(const float2*)(xc_raw + (r0-1)*DI + c);
  } else {
    h0 = make_float2(0.f,0.f); h1 = h0; h2 = h0;
  }
  #pragma unroll
  for (int r=0;r<16;r++){
    float2 cur = *(const float2*)(xc_raw + (r0+r)*DI + c);
    float vx = bias.x;
    vx = fmaf(h0.x, w0.x, vx); vx = fmaf(h1.x, w0.y, vx);
    vx = fmaf(h2.x, w0.z, vx); vx = fmaf(cur.x, w0.w, vx);
    float vy = bias.y;
    vy = fmaf(h0.y, w1.x, vy); vy = fmaf(h1.y, w1.y, vy);
    vy = fmaf(h2.y, w1.z, vy); vy = fmaf(cur.y, w1.w, vy);
    vx = siluf(vx); vy = siluf(vy);
    *(float2*)(xc + (r0+r)*DI + c) = make_float2(vx, vy);
    unsigned int pk = (unsigned int)f2bf(vx) | ((unsigned int)f2bf(vy) << 16);
    *(unsigned int*)&xcb[(r0+r)*DI + c] = pk;
    h0 = h1; h1 = h2; h2 = cur;
  }
}

// ================= x_dbl (MFMA) + dt GEMM fused =================
// grid 256: 16 rows/block. Wave w computes padded col-tile w (cols w*16..+15 of 64).
__global__ __launch_bounds__(256) void k_xdbl(
    const unsigned short* __restrict__ xcb,
    const unsigned short* __restrict__ Wxt_spa, const unsigned short* __restrict__ Wxt_spe,
    const float* __restrict__ Wdt_spa, const float* __restrict__ bdt_spa,
    const float* __restrict__ Wdt_spe, const float* __restrict__ bdt_spe,
    float* __restrict__ dt, float* __restrict__ Bm, float* __restrict__ Cm)
{
  __shared__ unsigned short At[16][520];   // 16.6 KB
  __shared__ float xdbl[16][18];
  int tid = threadIdx.x;
  int r0 = blockIdx.x * 16;
  int branch = r0 >= HALF_ROWS;
  const unsigned short* Wxt = branch ? Wxt_spe : Wxt_spa;
  const float* Wdt = branch ? Wdt_spe : Wdt_spa;
  const float* bdt = branch ? bdt_spe : bdt_spa;
  // stage A: 16 x 512 bf16
  for (int p=0;p<4;p++){
    int i = tid + 256*p;               // uint4 index (8 bf16 each)
    int r = i >> 6, q = (i & 63)*8;
    *(uint4*)&At[r][q] = *(const uint4*)&xcb[(r0+r)*DI + q];
  }
  __syncthreads();
  int w = tid >> 6, lane = tid & 63;
  int m16 = lane & 15, quad = lane >> 4;
  f32x4 acc = (f32x4)(0.f);
  #pragma unroll
  for (int ks=0; ks<16; ks++){
    bhalf8 a = *(const bhalf8*)&At[m16][ks*32 + quad*8];
    bhalf8 bf = *(const bhalf8*)&Wxt[(w*16 + m16)*512 + ks*32 + quad*8];
    acc = __builtin_amdgcn_mfma_f32_16x16x32_bf16(a, bf, acc, 0,0,0);
  }
  #pragma unroll
  for (int e=0;e<4;e++){
    int row = quad*4 + e;
    float v = acc[e];
    if (w == 0)      xdbl[row][m16] = v;
    else if (w == 1) Bm[(r0+row)*DS + m16] = v;
    else if (w == 2) Cm[(r0+row)*DS + m16] = v;
    // w == 3: zero padding, discard
  }
  __syncthreads();
  // dt GEMM: thread owns cols tid and tid+256
  float wdt0[16], wdt1[16];
  #pragma unroll
  for (int j=0;j<16;j++){ wdt0[j]=Wdt[j*DI+tid]; wdt1[j]=Wdt[j*DI+tid+256]; }
  float b0 = bdt[tid], b1 = bdt[tid+256];
  #pragma unroll
  for (int r=0;r<16;r++){
    float a0=b0, a1=b1;
    #pragma unroll
    for (int j=0;j<16;j++){
      float xv = xdbl[r][j];
      a0 = fmaf(xv, wdt0[j], a0);
      a1 = fmaf(xv, wdt1[j], a1);
    }
    dt[(r0+r)*DI + tid]       = softplusf(a0);
    dt[(r0+r)*DI + tid + 256] = softplusf(a1);
  }
}

// ================= selective scan v3: no shuffles =================
__global__ __launch_bounds__(256) void k_scan(
    const float* __restrict__ Alog_spa, const float* __restrict__ Dp_spa,
    const float* __restrict__ Alog_spe, const float* __restrict__ Dp_spe,
    const float* __restrict__ dt, const float* __restrict__ xc,
    const float* __restrict__ sz, const float* __restrict__ Bm,
    const float* __restrict__ Cm, float* __restrict__ y)
{
  __shared__ float ypbuf[16][260];
  __shared__ float Dsh[16];
  int tid = threadIdx.x;
  int bi = blockIdx.x;
  int branch = bi >> 8;
  int rem = bi & 255;
  int b = rem >> 5;
  int d0 = (rem & 31) * 16;
  const float* Alog = branch ? Alog_spe : Alog_spa;
  const float* Dp   = branch ? Dp_spe   : Dp_spa;
  int dg = tid >> 4, s = tid & 15;
  int d = d0 + dg;
  float A_ds = -__expf(Alog[d*DS + s]);
  if (tid < 16) Dsh[tid] = Dp[d0 + tid];
  int row0 = branch*HALF_ROWS + b*LD;
  int rli = tid >> 4, rdd = tid & 15;
  float h = 0.f;
  for (int c=0; c<16; c++){
    int rbase = row0 + c*16;
    float rdt[16], rxc[16], rB[16], rC[16];
    #pragma unroll
    for (int li=0; li<16; li++){
      rdt[li] = dt[(rbase+li)*DI + d];
      rxc[li] = xc[(rbase+li)*DI + d];
      rB[li]  = Bm[(rbase+li)*DS + s];
      rC[li]  = Cm[(rbase+li)*DS + s];
    }
    __syncthreads();
    #pragma unroll
    for (int li=0; li<16; li++){
      float dA = __expf(rdt[li] * A_ds);
      h = fmaf(dA, h, rdt[li] * rB[li] * rxc[li]);
      ypbuf[li][s*16 + ((dg + s) & 15)] = h * rC[li];
    }
    __syncthreads();
    float acc = 0.f;
    #pragma unroll
    for (int ss=0; ss<16; ss++)
      acc += ypbuf[rli][ss*16 + ((rdd + ss) & 15)];
    int grow = rbase + rli;
    float xcv = xc[grow*DI + d0 + rdd];
    float szv = sz[grow*DI + d0 + rdd];
    y[grow*DI + d0 + rdd] = fmaf(xcv, Dsh[rdd], acc) * szv;
  }
}

// ================= W_out GEMM + relu + residual (MFMA) =================
__global__ __launch_bounds__(256) void k_wout(
    const unsigned short* __restrict__ Wt_spa, const unsigned short* __restrict__ Wt_spe,
    const float* __restrict__ x_spa, const float* __restrict__ x_spe,
    const float* __restrict__ y, float* __restrict__ ae)
{
  __shared__ unsigned short At[16][520];   // 16.6 KB
  int tid = threadIdx.x;
  int r0 = blockIdx.x * 16;
  int branch = (r0 >= HALF_ROWS);
  const unsigned short* Wt = branch ? Wt_spe : Wt_spa;
  const float* xb = branch ? x_spe : x_spa;
  int rr0 = branch ? r0 - HALF_ROWS : r0;
  for (int p=0;p<8;p++){
    int i4 = tid + 256*p;          // 0..2047
    int r = i4 >> 7, kq = (i4 & 127)*4;
    float4 v = *(const float4*)(y + (r0+r)*DI + kq);
    unsigned int lo = (unsigned int)f2bf(v.x) | ((unsigned int)f2bf(v.y) << 16);
    unsigned int hi = (unsigned int)f2bf(v.z) | ((unsigned int)f2bf(v.w) << 16);
    *(uint2*)&At[r][kq] = make_uint2(lo, hi);
  }
  __syncthreads();
  int w = tid >> 6, lane = tid & 63;
  int m16 = lane & 15, quad = lane >> 4;
  bhalf8 af[16];
  #pragma unroll
  for (int ks=0; ks<16; ks++)
    af[ks] = *(const bhalf8*)&At[m16][ks*32 + quad*8];
  f32x4 acc[4];
  #pragma unroll
  for (int ct=0; ct<4; ct++) acc[ct] = (f32x4)(0.f);
  #pragma unroll
  for (int ks=0; ks<16; ks++){
    #pragma unroll
    for (int ct=0; ct<4; ct++){
      bhalf8 bf = *(const bhalf8*)&Wt[(w*64 + ct*16 + m16)*512 + ks*32 + quad*8];
      acc[ct] = __builtin_amdgcn_mfma_f32_16x16x32_bf16(af[ks], bf, acc[ct], 0,0,0);
    }
  }
  #pragma unroll
  for (int ct=0; ct<4; ct++){
    #pragma unroll
    for (int e=0;e<4;e++){
      int row = quad*4 + e;
      int col = w*64 + ct*16 + m16;
      float v = fmaxf(acc[ct][e], 0.f) + xb[(rr0+row)*DM + col];
      ae[(r0+row)*DM + col] = v;
    }
  }
}

// ================= pool + gate fused =================
__global__ __launch_bounds__(256) void k_poolgate(const float* __restrict__ ae,
    const float* __restrict__ fW, float* __restrict__ fw)
{
  __shared__ float p[DM];
  int b=blockIdx.x, c=threadIdx.x;
  const float* a0 = ae + (b*LD)*DM + c;
  const float* a1 = ae + ((BD + b)*LD)*DM + c;
  float s=0.f;
  #pragma unroll 8
  for(int l=0;l<LD;l++) s += a0[l*DM] + a1[l*DM];
  p[c] = s * (0.5f/LD);
  __syncthreads();
  float a=0.f;
  for(int k=0;k<DM;k+=4){
    a = fmaf(p[k+0], fW[(k+0)*DM+c], a);
    a = fmaf(p[k+1], fW[(k+1)*DM+c], a);
    a = fmaf(p[k+2], fW[(k+2)*DM+c], a);
    a = fmaf(p[k+3], fW[(k+3)*DM+c], a);
  }
  fw[b*DM+c]=1.f/(1.f+__expf(-a));
}

// ================= final: out = ae*fw + ident =================
__global__ __launch_bounds__(256) void k_final(const float* __restrict__ ae,
    const float* __restrict__ ident, const float* __restrict__ fw, float* __restrict__ out)
{
  int idx4 = blockIdx.x*256 + threadIdx.x;
  int row = idx4 >> 6;
  int b = (row >> 8) & 7;
  int c4 = (idx4 & 63) * 4;
  float4 av = *(const float4*)(ae + idx4*4);
  float4 iv = *(const float4*)(ident + idx4*4);
  float4 fv = *(const float4*)(fw + b*DM + c4);
  float4 o;
  o.x = fmaf(av.x, fv.x, iv.x);
  o.y = fmaf(av.y, fv.y, iv.y);
  o.z = fmaf(av.z, fv.z, iv.z);
  o.w = fmaf(av.w, fv.w, iv.w);
  *(float4*)(out + idx4*4) = o;
}

extern "C" void kernel_launch(void* const* d_in, const int* in_sizes, int n_in,
                              void* d_out, int out_size, void* d_ws, size_t ws_size,
                              hipStream_t stream) {
  const float* x_spa     = (const float*)d_in[0];
  const float* x_spe     = (const float*)d_in[1];
  const float* spa_ln_g  = (const float*)d_in[2];
  const float* spa_ln_b  = (const float*)d_in[3];
  const float* spa_W_in  = (const float*)d_in[4];
  const float* spa_cw    = (const float*)d_in[5];
  const float* spa_cb    = (const float*)d_in[6];
  const float* spa_W_x   = (const float*)d_in[7];
  const float* spa_W_dt  = (const float*)d_in[8];
  const float* spa_b_dt  = (const float*)d_in[9];
  const float* spa_A_log = (const float*)d_in[10];
  const float* spa_D     = (const float*)d_in[11];
  const float* spa_W_out = (const float*)d_in[12];
  const float* spe_ln_g  = (const float*)d_in[13];
  const float* spe_ln_b  = (const float*)d_in[14];
  const float* spe_W_in  = (const float*)d_in[15];
  const float* spe_cw    = (const float*)d_in[16];
  const float* spe_cb    = (const float*)d_in[17];
  const float* spe_W_x   = (const float*)d_in[18];
  const float* spe_W_dt  = (const float*)d_in[19];
  const float* spe_b_dt  = (const float*)d_in[20];
  const float* spe_A_log = (const float*)d_in[21];
  const float* spe_D     = (const float*)d_in[22];
  const float* spe_W_out = (const float*)d_in[23];
  const float* sc_W      = (const float*)d_in[24];
  const float* sc_b      = (const float*)d_in[25];
  const float* sc_ln_g   = (const float*)d_in[26];
  const float* sc_ln_b   = (const float*)d_in[27];
  const float* fusion_W  = (const float*)d_in[28];

  float* ws = (float*)d_ws;
  float* ident  = ws;                       // 4096*256
  float* xc_raw = ident  + NROWS*DM;        // 4096*512 (reused as y)
  float* sz     = xc_raw + NROWS*DI;        // 4096*512
  float* xc     = sz     + NROWS*DI;        // 4096*512
  float* dt     = xc     + NROWS*DI;        // 4096*512 (reused as ae)
  float* Bm     = dt     + NROWS*DI;        // 4096*16
  float* Cm     = Bm     + NROWS*DS;        // 4096*16
  float* fw     = Cm     + NROWS*DS;        // 8*256
  unsigned short* Wt_i_spa = (unsigned short*)(fw + BD*DM);
  unsigned short* Wt_i_spe = Wt_i_spa + 1024*256;
  unsigned short* Wt_o_spa = Wt_i_spe + 1024*256;
  unsigned short* Wt_o_spe = Wt_o_spa + 256*512;
  unsigned short* scWt     = Wt_o_spe + 256*512;
  unsigned short* Wxt_spa  = scWt     + 256*256;
  unsigned short* Wxt_spe  = Wxt_spa  + 64*512;
  unsigned short* xcb      = Wxt_spe  + 64*512;   // 4096*512 bf16

  float* out = (float*)d_out;

  k_transpose<<<60, 256, 0, stream>>>(spa_W_in, spe_W_in, spa_W_out, spe_W_out, sc_W,
                                      spa_W_x, spe_W_x,
                                      Wt_i_spa, Wt_i_spe, Wt_o_spa, Wt_o_spe, scWt,
                                      Wxt_spa, Wxt_spe);
  k_lnwin<<<256, 256, 0, stream>>>(x_spa, x_spe, spa_ln_g, spa_ln_b, spe_ln_g, spe_ln_b,
                                   Wt_i_spa, Wt_i_spe, xc_raw, sz);
  k_conv<<<NROWS/16, 256, 0, stream>>>(spa_cw, spa_cb, spe_cw, spe_cb, xc_raw, xc, xcb);
  k_xdbl<<<NROWS/16, 256, 0, stream>>>(xcb, Wxt_spa, Wxt_spe,
                                       spa_W_dt, spa_b_dt, spe_W_dt, spe_b_dt,
                                       dt, Bm, Cm);
  float* y = xc_raw;   // xc_raw dead after k_conv
  k_scan<<<512, 256, 0, stream>>>(spa_A_log, spa_D, spe_A_log, spe_D, dt, xc, sz, Bm, Cm, y);
  k_shortcut<<<128, 256, 0, stream>>>(x_spa, x_spe, scWt, sc_b, sc_ln_g, sc_ln_b, ident);
  float* ae = dt;      // dt dead after k_scan
  k_wout<<<256, 256, 0, stream>>>(Wt_o_spa, Wt_o_spe, x_spa, x_spe, y, ae);
  k_poolgate<<<BD, 256, 0, stream>>>(ae, fusion_W, fw);
  k_final<<<NROWS*DM/1024, 256, 0, stream>>>(ae, ident, fw, out);
}

// Round 6
// 229.151 us; speedup vs baseline: 1.5795x; 1.0839x over previous
//
#include <hip/hip_runtime.h>
#include <hip/hip_bf16.h>
#include <math.h>

#define BD 8      // B
#define LD 256    // L
#define DM 256    // D_MODEL
#define DS 16     // D_STATE
#define DI 512    // D_INNER
#define RK 16     // DT_RANK

#define NROWS (2*BD*LD)   // 4096 rows (both branches concatenated)
#define HALF_ROWS (BD*LD) // 2048

typedef __attribute__((ext_vector_type(8))) short bhalf8;   // 8 bf16 = 4 VGPR
typedef __attribute__((ext_vector_type(4))) float f32x4;

__device__ __forceinline__ float siluf(float x){ return x / (1.f + __expf(-x)); }
__device__ __forceinline__ float softplusf(float x){
  return fmaxf(x, 0.f) + log1pf(__expf(-fabsf(x)));
}
__device__ __forceinline__ unsigned short f2bf(float f){
  __hip_bfloat16 h = __float2bfloat16(f);   // RNE
  return *reinterpret_cast<unsigned short*>(&h);
}

// ================= weight transpose + bf16 cast =================
__global__ __launch_bounds__(256) void k_transpose(
    const float* __restrict__ Wi_spa, const float* __restrict__ Wi_spe,
    const float* __restrict__ Wo_spa, const float* __restrict__ Wo_spe,
    const float* __restrict__ scW,
    const float* __restrict__ Wx_spa, const float* __restrict__ Wx_spe,
    unsigned short* __restrict__ Wt_i_spa, unsigned short* __restrict__ Wt_i_spe,
    unsigned short* __restrict__ Wt_o_spa, unsigned short* __restrict__ Wt_o_spe,
    unsigned short* __restrict__ scWt,
    unsigned short* __restrict__ Wxt_spa, unsigned short* __restrict__ Wxt_spe)
{
  __shared__ unsigned short tile[256][68];   // 34.8 KB
  __shared__ float tile2[128][49];           // 25.1 KB
  int b = blockIdx.x;
  int tid = threadIdx.x;
  if (b >= 52){
    int bb = b - 52;
    int branch = bb >> 2, chunk = bb & 3;
    int k0 = chunk*128;
    const float* Wx = branch ? Wx_spe : Wx_spa;
    unsigned short* Wxt = branch ? Wxt_spe : Wxt_spa;
    for (int i=tid; i<128*48; i+=256){
      int kk = i/48, c = i - kk*48;
      tile2[kk][c] = Wx[(k0+kk)*48 + c];
    }
    __syncthreads();
    for (int i=tid; i<64*128; i+=256){
      int cc = i >> 7, kk = i & 127;
      float v = (cc < 48) ? tile2[kk][cc] : 0.f;
      Wxt[cc*512 + k0 + kk] = f2bf(v);
    }
    return;
  }
  const float* W; unsigned short* Wt; int N, K, c0, k0;
  if (b < 32){
    int bb = b & 15;
    W  = (b < 16) ? Wi_spa  : Wi_spe;
    Wt = (b < 16) ? Wt_i_spa: Wt_i_spe;
    N = 1024; K = 256; c0 = (bb >> 2)*256; k0 = (bb & 3)*64;
  } else if (b < 48){
    int bb = b - 32; int h = bb >> 3; bb &= 7;
    W  = h ? Wo_spe  : Wo_spa;
    Wt = h ? Wt_o_spe: Wt_o_spa;
    N = 256; K = 512; c0 = 0; k0 = bb*64;
  } else {
    int bb = b - 48;
    W = scW; Wt = scWt;
    N = 256; K = 256; c0 = 0; k0 = bb*64;
  }
  int c = c0 + tid;
  #pragma unroll 8
  for (int kk=0; kk<64; kk++)
    tile[tid][kk] = f2bf(W[(k0+kk)*N + c]);
  __syncthreads();
  for (int p=0; p<16; p++){
    int i = tid + 256*p;
    int cl = i >> 4, kq = (i & 15)*4;
    uint2 v = *(const uint2*)&tile[cl][kq];
    *(uint2*)&Wt[(c0+cl)*K + k0 + kq] = v;
  }
}

// ================= LN + W_in GEMM (MFMA) =================
// grid 1024: rg=bi>>2 (16 rows), cg=bi&3 (256 of 1024 cols); wave w -> 64 cols
__global__ __launch_bounds__(256) void k_lnwin(
    const float* __restrict__ x_spa, const float* __restrict__ x_spe,
    const float* __restrict__ g_spa, const float* __restrict__ b_spa,
    const float* __restrict__ g_spe, const float* __restrict__ b_spe,
    const unsigned short* __restrict__ Wt_spa, const unsigned short* __restrict__ Wt_spe,
    float* __restrict__ xc_raw, float* __restrict__ szout)
{
  __shared__ unsigned short At[16][264];   // 8.4 KB
  __shared__ float red[16][16];
  __shared__ float mu[16], rs[16];
  int tid = threadIdx.x;
  int bi = blockIdx.x;
  int rg = bi >> 2, cg = bi & 3;
  int r0 = rg * 16;
  int branch = (r0 >= HALF_ROWS);
  const float* xb = branch ? x_spe : x_spa;
  const float* g  = branch ? g_spe : g_spa;
  const float* be = branch ? b_spe : b_spa;
  const unsigned short* Wt = branch ? Wt_spe : Wt_spa;
  int rr0 = branch ? r0 - HALF_ROWS : r0;

  // phase 1: LN stats (16 threads/row, 16 floats each)
  {
    int row = tid >> 4, seg = tid & 15;
    const float* xp = xb + (rr0 + row)*DM + seg*16;
    float s = 0.f, s2 = 0.f;
    #pragma unroll
    for (int i=0;i<4;i++){
      float4 v = *(const float4*)(xp + i*4);
      s  += v.x+v.y+v.z+v.w;
      s2 += v.x*v.x + v.y*v.y + v.z*v.z + v.w*v.w;
    }
    red[row][seg] = s;
    __syncthreads();
    if (seg == 0){
      float t = 0.f;
      #pragma unroll
      for (int i=0;i<16;i++) t += red[row][i];
      mu[row] = t * (1.f/DM);
    }
    __syncthreads();
    float m = mu[row];
    float v2 = 0.f;
    #pragma unroll
    for (int i=0;i<4;i++){
      float4 v = *(const float4*)(xp + i*4);
      float dx=v.x-m, dy=v.y-m, dz=v.z-m, dw=v.w-m;
      v2 += dx*dx+dy*dy+dz*dz+dw*dw;
    }
    red[row][seg] = v2;
    __syncthreads();
    if (seg == 0){
      float t = 0.f;
      #pragma unroll
      for (int i=0;i<16;i++) t += red[row][i];
      rs[row] = rsqrtf(t*(1.f/DM) + 1e-6f);
    }
  }
  __syncthreads();
  // phase 2: normalize + cvt + stage (16x256 = 1024 float4s)
  for (int p=0;p<4;p++){
    int i4 = tid + 256*p;
    int r = i4 >> 6, kq = (i4 & 63)*4;
    float4 v  = *(const float4*)(xb + (rr0+r)*DM + kq);
    float4 gv = *(const float4*)(g + kq);
    float4 bv = *(const float4*)(be + kq);
    float m = mu[r], rv = rs[r];
    unsigned int lo = (unsigned int)f2bf((v.x-m)*rv*gv.x + bv.x)
                    | ((unsigned int)f2bf((v.y-m)*rv*gv.y + bv.y) << 16);
    unsigned int hi = (unsigned int)f2bf((v.z-m)*rv*gv.z + bv.z)
                    | ((unsigned int)f2bf((v.w-m)*rv*gv.w + bv.w) << 16);
    *(uint2*)&At[r][kq] = make_uint2(lo, hi);
  }
  __syncthreads();
  // phase 3: MFMA. wave w -> cols cg*256 + w*64 .. +63
  int w = tid >> 6, lane = tid & 63;
  int m16 = lane & 15, quad = lane >> 4;
  bhalf8 af[8];
  #pragma unroll
  for (int ks=0; ks<8; ks++)
    af[ks] = *(const bhalf8*)&At[m16][ks*32 + quad*8];
  f32x4 acc[4];
  #pragma unroll
  for (int ct=0; ct<4; ct++) acc[ct] = (f32x4)(0.f);
  const unsigned short* Wbw = Wt + (cg*256 + w*64)*256;
  #pragma unroll
  for (int ks=0; ks<8; ks++){
    #pragma unroll
    for (int ct=0; ct<4; ct++){
      bhalf8 bf = *(const bhalf8*)&Wbw[(ct*16 + m16)*256 + ks*32 + quad*8];
      acc[ct] = __builtin_amdgcn_mfma_f32_16x16x32_bf16(af[ks], bf, acc[ct], 0,0,0);
    }
  }
  bool isz = (cg >= 2);
  float* outp = isz ? szout : xc_raw;
  int cbase = (cg & 1)*256 + w*64;
  #pragma unroll
  for (int ct=0; ct<4; ct++){
    #pragma unroll
    for (int e=0;e<4;e++){
      int row = r0 + quad*4 + e;
      int col = cbase + ct*16 + m16;
      float v = acc[ct][e];
      if (isz) v = siluf(v);
      outp[row*DI + col] = v;
    }
  }
}

// ================= shortcut GEMM + bias + LN (MFMA), 16 rows/block =================
__global__ __launch_bounds__(256) void k_shortcut(
    const float* __restrict__ x_spa, const float* __restrict__ x_spe,
    const unsigned short* __restrict__ scWt, const float* __restrict__ sc_b,
    const float* __restrict__ ln_g, const float* __restrict__ ln_b,
    float* __restrict__ ident)
{
  __shared__ unsigned short At[16][264];   // 8.4 KB
  __shared__ float Dt[16][260];            // 16.6 KB
  __shared__ float red[16][16];
  __shared__ float mu[16], rs[16];
  int tid = threadIdx.x;
  int r0 = blockIdx.x * 16;
  int branch = (r0 >= HALF_ROWS);
  const float* xb = branch ? x_spe : x_spa;
  int rr0 = branch ? r0 - HALF_ROWS : r0;
  for (int p=0;p<4;p++){
    int i4 = tid + 256*p;
    int r = i4 >> 6, kq = (i4 & 63)*4;
    float4 v = *(const float4*)(xb + (rr0+r)*DM + kq);
    unsigned int lo = (unsigned int)f2bf(v.x) | ((unsigned int)f2bf(v.y) << 16);
    unsigned int hi = (unsigned int)f2bf(v.z) | ((unsigned int)f2bf(v.w) << 16);
    *(uint2*)&At[r][kq] = make_uint2(lo, hi);
  }
  __syncthreads();
  int w = tid >> 6, lane = tid & 63;
  int m16 = lane & 15, quad = lane >> 4;
  bhalf8 af[8];
  #pragma unroll
  for (int ks=0; ks<8; ks++)
    af[ks] = *(const bhalf8*)&At[m16][ks*32 + quad*8];
  f32x4 acc[4];
  #pragma unroll
  for (int ct=0; ct<4; ct++) acc[ct] = (f32x4)(0.f);
  const unsigned short* Wbw = scWt + (w*64)*256;
  #pragma unroll
  for (int ks=0; ks<8; ks++){
    #pragma unroll
    for (int ct=0; ct<4; ct++){
      bhalf8 bf = *(const bhalf8*)&Wbw[(ct*16 + m16)*256 + ks*32 + quad*8];
      acc[ct] = __builtin_amdgcn_mfma_f32_16x16x32_bf16(af[ks], bf, acc[ct], 0,0,0);
    }
  }
  #pragma unroll
  for (int ct=0; ct<4; ct++){
    #pragma unroll
    for (int e=0;e<4;e++){
      int row = quad*4 + e;
      int col = w*64 + ct*16 + m16;
      Dt[row][col] = acc[ct][e] + sc_b[col];
    }
  }
  __syncthreads();
  // LN stats (16 threads/row)
  {
    int row = tid >> 4, seg = tid & 15;
    float s = 0.f, s2 = 0.f;
    #pragma unroll
    for (int i=0;i<4;i++){
      float4 v = *(const float4*)&Dt[row][seg*16 + i*4];
      s  += v.x+v.y+v.z+v.w;
      s2 += v.x*v.x + v.y*v.y + v.z*v.z + v.w*v.w;
    }
    red[row][seg] = s;
    __syncthreads();
    if (seg == 0){
      float t=0.f;
      #pragma unroll
      for (int i=0;i<16;i++) t += red[row][i];
      mu[row] = t * (1.f/DM);
    }
    __syncthreads();
    red[row][seg] = s2;
    __syncthreads();
    if (seg == 0){
      float t=0.f;
      #pragma unroll
      for (int i=0;i<16;i++) t += red[row][i];
      float m = mu[row];
      rs[row] = rsqrtf(t*(1.f/DM) - m*m + 1e-5f);
    }
  }
  __syncthreads();
  float gg = ln_g[tid], bb = ln_b[tid];
  #pragma unroll
  for (int r=0;r<16;r++)
    ident[(r0+r)*DM + tid] = (Dt[r][tid]-mu[r])*rs[r]*gg + bb;
}

// ================= causal conv + silu (register history, no LDS) =================
__global__ __launch_bounds__(256) void k_conv(
    const float* __restrict__ cw_spa, const float* __restrict__ cb_spa,
    const float* __restrict__ cw_spe, const float* __restrict__ cb_spe,
    const float* __restrict__ xc_raw,
    float* __restrict__ xc, unsigned short* __restrict__ xcb)
{
  int tid = threadIdx.x;
  int r0 = blockIdx.x * 16;
  int branch = r0 >= HALF_ROWS;
  int l0 = r0 & (LD-1);
  const float* cw = branch ? cw_spe : cw_spa;
  const float* cb = branch ? cb_spe : cb_spa;
  int c = tid*2;
  float4 w0 = *(const float4*)(cw + 4*c);
  float4 w1 = *(const float4*)(cw + 4*(c+1));
  float2 bias = *(const float2*)(cb + c);
  float2 h0, h1, h2;
  if (l0 > 0){
    h0 = *(const float2*)(xc_raw + (r0-3)*DI + c);
    h1 = *(const float2*)(xc_raw + (r0-2)*DI + c);
    h2 = *(const float2*)(xc_raw + (r0-1)*DI + c);
  } else {
    h0 = make_float2(0.f,0.f); h1 = h0; h2 = h0;
  }
  #pragma unroll
  for (int r=0;r<16;r++){
    float2 cur = *(const float2*)(xc_raw + (r0+r)*DI + c);
    float vx = bias.x;
    vx = fmaf(h0.x, w0.x, vx); vx = fmaf(h1.x, w0.y, vx);
    vx = fmaf(h2.x, w0.z, vx); vx = fmaf(cur.x, w0.w, vx);
    float vy = bias.y;
    vy = fmaf(h0.y, w1.x, vy); vy = fmaf(h1.y, w1.y, vy);
    vy = fmaf(h2.y, w1.z, vy); vy = fmaf(cur.y, w1.w, vy);
    vx = siluf(vx); vy = siluf(vy);
    *(float2*)(xc + (r0+r)*DI + c) = make_float2(vx, vy);
    unsigned int pk = (unsigned int)f2bf(vx) | ((unsigned int)f2bf(vy) << 16);
    *(unsigned int*)&xcb[(r0+r)*DI + c] = pk;
    h0 = h1; h1 = h2; h2 = cur;
  }
}

// ================= x_dbl (MFMA) + dt GEMM fused =================
__global__ __launch_bounds__(256) void k_xdbl(
    const unsigned short* __restrict__ xcb,
    const unsigned short* __restrict__ Wxt_spa, const unsigned short* __restrict__ Wxt_spe,
    const float* __restrict__ Wdt_spa, const float* __restrict__ bdt_spa,
    const float* __restrict__ Wdt_spe, const float* __restrict__ bdt_spe,
    float* __restrict__ dt, float* __restrict__ Bm, float* __restrict__ Cm)
{
  __shared__ unsigned short At[16][520];   // 16.6 KB
  __shared__ float xdbl[16][18];
  int tid = threadIdx.x;
  int r0 = blockIdx.x * 16;
  int branch = r0 >= HALF_ROWS;
  const unsigned short* Wxt = branch ? Wxt_spe : Wxt_spa;
  const float* Wdt = branch ? Wdt_spe : Wdt_spa;
  const float* bdt = branch ? bdt_spe : bdt_spa;
  for (int p=0;p<4;p++){
    int i = tid + 256*p;
    int r = i >> 6, q = (i & 63)*8;
    *(uint4*)&At[r][q] = *(const uint4*)&xcb[(r0+r)*DI + q];
  }
  __syncthreads();
  int w = tid >> 6, lane = tid & 63;
  int m16 = lane & 15, quad = lane >> 4;
  f32x4 acc = (f32x4)(0.f);
  #pragma unroll
  for (int ks=0; ks<16; ks++){
    bhalf8 a = *(const bhalf8*)&At[m16][ks*32 + quad*8];
    bhalf8 bf = *(const bhalf8*)&Wxt[(w*16 + m16)*512 + ks*32 + quad*8];
    acc = __builtin_amdgcn_mfma_f32_16x16x32_bf16(a, bf, acc, 0,0,0);
  }
  #pragma unroll
  for (int e=0;e<4;e++){
    int row = quad*4 + e;
    float v = acc[e];
    if (w == 0)      xdbl[row][m16] = v;
    else if (w == 1) Bm[(r0+row)*DS + m16] = v;
    else if (w == 2) Cm[(r0+row)*DS + m16] = v;
  }
  __syncthreads();
  float wdt0[16], wdt1[16];
  #pragma unroll
  for (int j=0;j<16;j++){ wdt0[j]=Wdt[j*DI+tid]; wdt1[j]=Wdt[j*DI+tid+256]; }
  float b0 = bdt[tid], b1 = bdt[tid+256];
  #pragma unroll
  for (int r=0;r<16;r++){
    float a0=b0, a1=b1;
    #pragma unroll
    for (int j=0;j<16;j++){
      float xv = xdbl[r][j];
      a0 = fmaf(xv, wdt0[j], a0);
      a1 = fmaf(xv, wdt1[j], a1);
    }
    dt[(r0+r)*DI + tid]       = softplusf(a0);
    dt[(r0+r)*DI + tid + 256] = softplusf(a1);
  }
}

// ================= selective scan v3: no shuffles =================
__global__ __launch_bounds__(256) void k_scan(
    const float* __restrict__ Alog_spa, const float* __restrict__ Dp_spa,
    const float* __restrict__ Alog_spe, const float* __restrict__ Dp_spe,
    const float* __restrict__ dt, const float* __restrict__ xc,
    const float* __restrict__ sz, const float* __restrict__ Bm,
    const float* __restrict__ Cm, float* __restrict__ y)
{
  __shared__ float ypbuf[16][260];
  __shared__ float Dsh[16];
  int tid = threadIdx.x;
  int bi = blockIdx.x;
  int branch = bi >> 8;
  int rem = bi & 255;
  int b = rem >> 5;
  int d0 = (rem & 31) * 16;
  const float* Alog = branch ? Alog_spe : Alog_spa;
  const float* Dp   = branch ? Dp_spe   : Dp_spa;
  int dg = tid >> 4, s = tid & 15;
  int d = d0 + dg;
  float A_ds = -__expf(Alog[d*DS + s]);
  if (tid < 16) Dsh[tid] = Dp[d0 + tid];
  int row0 = branch*HALF_ROWS + b*LD;
  int rli = tid >> 4, rdd = tid & 15;
  float h = 0.f;
  for (int c=0; c<16; c++){
    int rbase = row0 + c*16;
    float rdt[16], rxc[16], rB[16], rC[16];
    #pragma unroll
    for (int li=0; li<16; li++){
      rdt[li] = dt[(rbase+li)*DI + d];
      rxc[li] = xc[(rbase+li)*DI + d];
      rB[li]  = Bm[(rbase+li)*DS + s];
      rC[li]  = Cm[(rbase+li)*DS + s];
    }
    __syncthreads();
    #pragma unroll
    for (int li=0; li<16; li++){
      float dA = __expf(rdt[li] * A_ds);
      h = fmaf(dA, h, rdt[li] * rB[li] * rxc[li]);
      ypbuf[li][s*16 + ((dg + s) & 15)] = h * rC[li];
    }
    __syncthreads();
    float acc = 0.f;
    #pragma unroll
    for (int ss=0; ss<16; ss++)
      acc += ypbuf[rli][ss*16 + ((rdd + ss) & 15)];
    int grow = rbase + rli;
    float xcv = xc[grow*DI + d0 + rdd];
    float szv = sz[grow*DI + d0 + rdd];
    y[grow*DI + d0 + rdd] = fmaf(xcv, Dsh[rdd], acc) * szv;
  }
}

// ================= W_out GEMM + relu + residual (MFMA) =================
// grid 512: rb=bi>>1 (16 rows), ch=bi&1 (128 cols); wave w -> 32 cols
__global__ __launch_bounds__(256) void k_wout(
    const unsigned short* __restrict__ Wt_spa, const unsigned short* __restrict__ Wt_spe,
    const float* __restrict__ x_spa, const float* __restrict__ x_spe,
    const float* __restrict__ y, float* __restrict__ ae)
{
  __shared__ unsigned short At[16][520];   // 16.6 KB
  int tid = threadIdx.x;
  int bi = blockIdx.x;
  int r0 = (bi >> 1) * 16;
  int ch = bi & 1;
  int branch = (r0 >= HALF_ROWS);
  const unsigned short* Wt = branch ? Wt_spe : Wt_spa;
  const float* xb = branch ? x_spe : x_spa;
  int rr0 = branch ? r0 - HALF_ROWS : r0;
  for (int p=0;p<8;p++){
    int i4 = tid + 256*p;          // 0..2047
    int r = i4 >> 7, kq = (i4 & 127)*4;
    float4 v = *(const float4*)(y + (r0+r)*DI + kq);
    unsigned int lo = (unsigned int)f2bf(v.x) | ((unsigned int)f2bf(v.y) << 16);
    unsigned int hi = (unsigned int)f2bf(v.z) | ((unsigned int)f2bf(v.w) << 16);
    *(uint2*)&At[r][kq] = make_uint2(lo, hi);
  }
  __syncthreads();
  int w = tid >> 6, lane = tid & 63;
  int m16 = lane & 15, quad = lane >> 4;
  bhalf8 af[16];
  #pragma unroll
  for (int ks=0; ks<16; ks++)
    af[ks] = *(const bhalf8*)&At[m16][ks*32 + quad*8];
  f32x4 acc[2];
  #pragma unroll
  for (int ct=0; ct<2; ct++) acc[ct] = (f32x4)(0.f);
  const unsigned short* Wbw = Wt + (ch*128 + w*32)*512;
  #pragma unroll
  for (int ks=0; ks<16; ks++){
    #pragma unroll
    for (int ct=0; ct<2; ct++){
      bhalf8 bf = *(const bhalf8*)&Wbw[(ct*16 + m16)*512 + ks*32 + quad*8];
      acc[ct] = __builtin_amdgcn_mfma_f32_16x16x32_bf16(af[ks], bf, acc[ct], 0,0,0);
    }
  }
  #pragma unroll
  for (int ct=0; ct<2; ct++){
    #pragma unroll
    for (int e=0;e<4;e++){
      int row = quad*4 + e;
      int col = ch*128 + w*32 + ct*16 + m16;
      float v = fmaxf(acc[ct][e], 0.f) + xb[(rr0+row)*DM + col];
      ae[(r0+row)*DM + col] = v;
    }
  }
}

// ================= pool + gate fused =================
__global__ __launch_bounds__(256) void k_poolgate(const float* __restrict__ ae,
    const float* __restrict__ fW, float* __restrict__ fw)
{
  __shared__ float p[DM];
  int b=blockIdx.x, c=threadIdx.x;
  const float* a0 = ae + (b*LD)*DM + c;
  const float* a1 = ae + ((BD + b)*LD)*DM + c;
  float s=0.f;
  #pragma unroll 8
  for(int l=0;l<LD;l++) s += a0[l*DM] + a1[l*DM];
  p[c] = s * (0.5f/LD);
  __syncthreads();
  float a=0.f;
  for(int k=0;k<DM;k+=4){
    a = fmaf(p[k+0], fW[(k+0)*DM+c], a);
    a = fmaf(p[k+1], fW[(k+1)*DM+c], a);
    a = fmaf(p[k+2], fW[(k+2)*DM+c], a);
    a = fmaf(p[k+3], fW[(k+3)*DM+c], a);
  }
  fw[b*DM+c]=1.f/(1.f+__expf(-a));
}

// ================= final: out = ae*fw + ident =================
__global__ __launch_bounds__(256) void k_final(const float* __restrict__ ae,
    const float* __restrict__ ident, const float* __restrict__ fw, float* __restrict__ out)
{
  int idx4 = blockIdx.x*256 + threadIdx.x;
  int row = idx4 >> 6;
  int b = (row >> 8) & 7;
  int c4 = (idx4 & 63) * 4;
  float4 av = *(const float4*)(ae + idx4*4);
  float4 iv = *(const float4*)(ident + idx4*4);
  float4 fv = *(const float4*)(fw + b*DM + c4);
  float4 o;
  o.x = fmaf(av.x, fv.x, iv.x);
  o.y = fmaf(av.y, fv.y, iv.y);
  o.z = fmaf(av.z, fv.z, iv.z);
  o.w = fmaf(av.w, fv.w, iv.w);
  *(float4*)(out + idx4*4) = o;
}

extern "C" void kernel_launch(void* const* d_in, const int* in_sizes, int n_in,
                              void* d_out, int out_size, void* d_ws, size_t ws_size,
                              hipStream_t stream) {
  const float* x_spa     = (const float*)d_in[0];
  const float* x_spe     = (const float*)d_in[1];
  const float* spa_ln_g  = (const float*)d_in[2];
  const float* spa_ln_b  = (const float*)d_in[3];
  const float* spa_W_in  = (const float*)d_in[4];
  const float* spa_cw    = (const float*)d_in[5];
  const float* spa_cb    = (const float*)d_in[6];
  const float* spa_W_x   = (const float*)d_in[7];
  const float* spa_W_dt  = (const float*)d_in[8];
  const float* spa_b_dt  = (const float*)d_in[9];
  const float* spa_A_log = (const float*)d_in[10];
  const float* spa_D     = (const float*)d_in[11];
  const float* spa_W_out = (const float*)d_in[12];
  const float* spe_ln_g  = (const float*)d_in[13];
  const float* spe_ln_b  = (const float*)d_in[14];
  const float* spe_W_in  = (const float*)d_in[15];
  const float* spe_cw    = (const float*)d_in[16];
  const float* spe_cb    = (const float*)d_in[17];
  const float* spe_W_x   = (const float*)d_in[18];
  const float* spe_W_dt  = (const float*)d_in[19];
  const float* spe_b_dt  = (const float*)d_in[20];
  const float* spe_A_log = (const float*)d_in[21];
  const float* spe_D     = (const float*)d_in[22];
  const float* spe_W_out = (const float*)d_in[23];
  const float* sc_W      = (const float*)d_in[24];
  const float* sc_b      = (const float*)d_in[25];
  const float* sc_ln_g   = (const float*)d_in[26];
  const float* sc_ln_b   = (const float*)d_in[27];
  const float* fusion_W  = (const float*)d_in[28];

  float* ws = (float*)d_ws;
  float* ident  = ws;                       // 4096*256
  float* xc_raw = ident  + NROWS*DM;        // 4096*512 (reused as y)
  float* sz     = xc_raw + NROWS*DI;        // 4096*512
  float* xc     = sz     + NROWS*DI;        // 4096*512
  float* dt     = xc     + NROWS*DI;        // 4096*512 (reused as ae)
  float* Bm     = dt     + NROWS*DI;        // 4096*16
  float* Cm     = Bm     + NROWS*DS;        // 4096*16
  float* fw     = Cm     + NROWS*DS;        // 8*256
  unsigned short* Wt_i_spa = (unsigned short*)(fw + BD*DM);
  unsigned short* Wt_i_spe = Wt_i_spa + 1024*256;
  unsigned short* Wt_o_spa = Wt_i_spe + 1024*256;
  unsigned short* Wt_o_spe = Wt_o_spa + 256*512;
  unsigned short* scWt     = Wt_o_spe + 256*512;
  unsigned short* Wxt_spa  = scWt     + 256*256;
  unsigned short* Wxt_spe  = Wxt_spa  + 64*512;
  unsigned short* xcb      = Wxt_spe  + 64*512;   // 4096*512 bf16

  float* out = (float*)d_out;

  k_transpose<<<60, 256, 0, stream>>>(spa_W_in, spe_W_in, spa_W_out, spe_W_out, sc_W,
                                      spa_W_x, spe_W_x,
                                      Wt_i_spa, Wt_i_spe, Wt_o_spa, Wt_o_spe, scWt,
                                      Wxt_spa, Wxt_spe);
  k_lnwin<<<1024, 256, 0, stream>>>(x_spa, x_spe, spa_ln_g, spa_ln_b, spe_ln_g, spe_ln_b,
                                    Wt_i_spa, Wt_i_spe, xc_raw, sz);
  k_conv<<<NROWS/16, 256, 0, stream>>>(spa_cw, spa_cb, spe_cw, spe_cb, xc_raw, xc, xcb);
  k_xdbl<<<NROWS/16, 256, 0, stream>>>(xcb, Wxt_spa, Wxt_spe,
                                       spa_W_dt, spa_b_dt, spe_W_dt, spe_b_dt,
                                       dt, Bm, Cm);
  float* y = xc_raw;   // xc_raw dead after k_conv
  k_scan<<<512, 256, 0, stream>>>(spa_A_log, spa_D, spe_A_log, spe_D, dt, xc, sz, Bm, Cm, y);
  k_shortcut<<<NROWS/16, 256, 0, stream>>>(x_spa, x_spe, scWt, sc_b, sc_ln_g, sc_ln_b, ident);
  float* ae = dt;      // dt dead after k_scan
  k_wout<<<512, 256, 0, stream>>>(Wt_o_spa, Wt_o_spe, x_spa, x_spe, y, ae);
  k_poolgate<<<BD, 256, 0, stream>>>(ae, fusion_W, fw);
  k_final<<<NROWS*DM/1024, 256, 0, stream>>>(ae, ident, fw, out);
}

// Round 7
// 215.345 us; speedup vs baseline: 1.6808x; 1.0641x over previous
//
#include <hip/hip_runtime.h>
#include <hip/hip_bf16.h>
#include <math.h>

#define BD 8      // B
#define LD 256    // L
#define DM 256    // D_MODEL
#define DS 16     // D_STATE
#define DI 512    // D_INNER
#define RK 16     // DT_RANK

#define NROWS (2*BD*LD)   // 4096 rows (both branches concatenated)
#define HALF_ROWS (BD*LD) // 2048

typedef __attribute__((ext_vector_type(8))) short bhalf8;   // 8 bf16 = 4 VGPR
typedef __attribute__((ext_vector_type(4))) float f32x4;

__device__ __forceinline__ float siluf(float x){ return x / (1.f + __expf(-x)); }
__device__ __forceinline__ float softplusf(float x){
  return fmaxf(x, 0.f) + log1pf(__expf(-fabsf(x)));
}
__device__ __forceinline__ unsigned short f2bf(float f){
  __hip_bfloat16 h = __float2bfloat16(f);   // RNE
  return *reinterpret_cast<unsigned short*>(&h);
}

// ================= weight transpose + bf16 cast (+ pooled zero) =================
__global__ __launch_bounds__(256) void k_transpose(
    const float* __restrict__ Wi_spa, const float* __restrict__ Wi_spe,
    const float* __restrict__ Wo_spa, const float* __restrict__ Wo_spe,
    const float* __restrict__ scW,
    const float* __restrict__ Wx_spa, const float* __restrict__ Wx_spe,
    unsigned short* __restrict__ Wt_i_spa, unsigned short* __restrict__ Wt_i_spe,
    unsigned short* __restrict__ Wt_o_spa, unsigned short* __restrict__ Wt_o_spe,
    unsigned short* __restrict__ scWt,
    unsigned short* __restrict__ Wxt_spa, unsigned short* __restrict__ Wxt_spe,
    float* __restrict__ pooled)
{
  __shared__ unsigned short tile[256][68];   // 34.8 KB
  __shared__ float tile2[128][49];           // 25.1 KB
  int b = blockIdx.x;
  int tid = threadIdx.x;
  if (b == 60){
    // zero the pooled accumulator (k_wout atomically adds into it)
    for (int i=tid; i<BD*DM; i+=256) pooled[i] = 0.f;
    return;
  }
  if (b >= 52){
    int bb = b - 52;
    int branch = bb >> 2, chunk = bb & 3;
    int k0 = chunk*128;
    const float* Wx = branch ? Wx_spe : Wx_spa;
    unsigned short* Wxt = branch ? Wxt_spe : Wxt_spa;
    for (int i=tid; i<128*48; i+=256){
      int kk = i/48, c = i - kk*48;
      tile2[kk][c] = Wx[(k0+kk)*48 + c];
    }
    __syncthreads();
    for (int i=tid; i<64*128; i+=256){
      int cc = i >> 7, kk = i & 127;
      float v = (cc < 48) ? tile2[kk][cc] : 0.f;
      Wxt[cc*512 + k0 + kk] = f2bf(v);
    }
    return;
  }
  const float* W; unsigned short* Wt; int N, K, c0, k0;
  if (b < 32){
    int bb = b & 15;
    W  = (b < 16) ? Wi_spa  : Wi_spe;
    Wt = (b < 16) ? Wt_i_spa: Wt_i_spe;
    N = 1024; K = 256; c0 = (bb >> 2)*256; k0 = (bb & 3)*64;
  } else if (b < 48){
    int bb = b - 32; int h = bb >> 3; bb &= 7;
    W  = h ? Wo_spe  : Wo_spa;
    Wt = h ? Wt_o_spe: Wt_o_spa;
    N = 256; K = 512; c0 = 0; k0 = bb*64;
  } else {
    int bb = b - 48;
    W = scW; Wt = scWt;
    N = 256; K = 256; c0 = 0; k0 = bb*64;
  }
  int c = c0 + tid;
  #pragma unroll 8
  for (int kk=0; kk<64; kk++)
    tile[tid][kk] = f2bf(W[(k0+kk)*N + c]);
  __syncthreads();
  for (int p=0; p<16; p++){
    int i = tid + 256*p;
    int cl = i >> 4, kq = (i & 15)*4;
    uint2 v = *(const uint2*)&tile[cl][kq];
    *(uint2*)&Wt[(c0+cl)*K + k0 + kq] = v;
  }
}

// ================= LN + W_in GEMM (MFMA) =================
// grid 1024: rg=bi>>2 (16 rows), cg=bi&3 (256 of 1024 cols); wave w -> 64 cols
__global__ __launch_bounds__(256) void k_lnwin(
    const float* __restrict__ x_spa, const float* __restrict__ x_spe,
    const float* __restrict__ g_spa, const float* __restrict__ b_spa,
    const float* __restrict__ g_spe, const float* __restrict__ b_spe,
    const unsigned short* __restrict__ Wt_spa, const unsigned short* __restrict__ Wt_spe,
    float* __restrict__ xc_raw, float* __restrict__ szout)
{
  __shared__ unsigned short At[16][264];   // 8.4 KB
  __shared__ float red[16][16];
  __shared__ float mu[16], rs[16];
  int tid = threadIdx.x;
  int bi = blockIdx.x;
  int rg = bi >> 2, cg = bi & 3;
  int r0 = rg * 16;
  int branch = (r0 >= HALF_ROWS);
  const float* xb = branch ? x_spe : x_spa;
  const float* g  = branch ? g_spe : g_spa;
  const float* be = branch ? b_spe : b_spa;
  const unsigned short* Wt = branch ? Wt_spe : Wt_spa;
  int rr0 = branch ? r0 - HALF_ROWS : r0;

  {
    int row = tid >> 4, seg = tid & 15;
    const float* xp = xb + (rr0 + row)*DM + seg*16;
    float s = 0.f;
    #pragma unroll
    for (int i=0;i<4;i++){
      float4 v = *(const float4*)(xp + i*4);
      s  += v.x+v.y+v.z+v.w;
    }
    red[row][seg] = s;
    __syncthreads();
    if (seg == 0){
      float t = 0.f;
      #pragma unroll
      for (int i=0;i<16;i++) t += red[row][i];
      mu[row] = t * (1.f/DM);
    }
    __syncthreads();
    float m = mu[row];
    float v2 = 0.f;
    #pragma unroll
    for (int i=0;i<4;i++){
      float4 v = *(const float4*)(xp + i*4);
      float dx=v.x-m, dy=v.y-m, dz=v.z-m, dw=v.w-m;
      v2 += dx*dx+dy*dy+dz*dz+dw*dw;
    }
    red[row][seg] = v2;
    __syncthreads();
    if (seg == 0){
      float t = 0.f;
      #pragma unroll
      for (int i=0;i<16;i++) t += red[row][i];
      rs[row] = rsqrtf(t*(1.f/DM) + 1e-6f);
    }
  }
  __syncthreads();
  for (int p=0;p<4;p++){
    int i4 = tid + 256*p;
    int r = i4 >> 6, kq = (i4 & 63)*4;
    float4 v  = *(const float4*)(xb + (rr0+r)*DM + kq);
    float4 gv = *(const float4*)(g + kq);
    float4 bv = *(const float4*)(be + kq);
    float m = mu[r], rv = rs[r];
    unsigned int lo = (unsigned int)f2bf((v.x-m)*rv*gv.x + bv.x)
                    | ((unsigned int)f2bf((v.y-m)*rv*gv.y + bv.y) << 16);
    unsigned int hi = (unsigned int)f2bf((v.z-m)*rv*gv.z + bv.z)
                    | ((unsigned int)f2bf((v.w-m)*rv*gv.w + bv.w) << 16);
    *(uint2*)&At[r][kq] = make_uint2(lo, hi);
  }
  __syncthreads();
  int w = tid >> 6, lane = tid & 63;
  int m16 = lane & 15, quad = lane >> 4;
  bhalf8 af[8];
  #pragma unroll
  for (int ks=0; ks<8; ks++)
    af[ks] = *(const bhalf8*)&At[m16][ks*32 + quad*8];
  f32x4 acc[4];
  #pragma unroll
  for (int ct=0; ct<4; ct++) acc[ct] = (f32x4)(0.f);
  const unsigned short* Wbw = Wt + (cg*256 + w*64)*256;
  #pragma unroll
  for (int ks=0; ks<8; ks++){
    #pragma unroll
    for (int ct=0; ct<4; ct++){
      bhalf8 bf = *(const bhalf8*)&Wbw[(ct*16 + m16)*256 + ks*32 + quad*8];
      acc[ct] = __builtin_amdgcn_mfma_f32_16x16x32_bf16(af[ks], bf, acc[ct], 0,0,0);
    }
  }
  bool isz = (cg >= 2);
  float* outp = isz ? szout : xc_raw;
  int cbase = (cg & 1)*256 + w*64;
  #pragma unroll
  for (int ct=0; ct<4; ct++){
    #pragma unroll
    for (int e=0;e<4;e++){
      int row = r0 + quad*4 + e;
      int col = cbase + ct*16 + m16;
      float v = acc[ct][e];
      if (isz) v = siluf(v);
      outp[row*DI + col] = v;
    }
  }
}

// ================= shortcut GEMM + bias + LN (MFMA), 16 rows/block =================
__global__ __launch_bounds__(256) void k_shortcut(
    const float* __restrict__ x_spa, const float* __restrict__ x_spe,
    const unsigned short* __restrict__ scWt, const float* __restrict__ sc_b,
    const float* __restrict__ ln_g, const float* __restrict__ ln_b,
    float* __restrict__ ident)
{
  __shared__ unsigned short At[16][264];   // 8.4 KB
  __shared__ float Dt[16][260];            // 16.6 KB
  __shared__ float red[16][16];
  __shared__ float mu[16], rs[16];
  int tid = threadIdx.x;
  int r0 = blockIdx.x * 16;
  int branch = (r0 >= HALF_ROWS);
  const float* xb = branch ? x_spe : x_spa;
  int rr0 = branch ? r0 - HALF_ROWS : r0;
  for (int p=0;p<4;p++){
    int i4 = tid + 256*p;
    int r = i4 >> 6, kq = (i4 & 63)*4;
    float4 v = *(const float4*)(xb + (rr0+r)*DM + kq);
    unsigned int lo = (unsigned int)f2bf(v.x) | ((unsigned int)f2bf(v.y) << 16);
    unsigned int hi = (unsigned int)f2bf(v.z) | ((unsigned int)f2bf(v.w) << 16);
    *(uint2*)&At[r][kq] = make_uint2(lo, hi);
  }
  __syncthreads();
  int w = tid >> 6, lane = tid & 63;
  int m16 = lane & 15, quad = lane >> 4;
  bhalf8 af[8];
  #pragma unroll
  for (int ks=0; ks<8; ks++)
    af[ks] = *(const bhalf8*)&At[m16][ks*32 + quad*8];
  f32x4 acc[4];
  #pragma unroll
  for (int ct=0; ct<4; ct++) acc[ct] = (f32x4)(0.f);
  const unsigned short* Wbw = scWt + (w*64)*256;
  #pragma unroll
  for (int ks=0; ks<8; ks++){
    #pragma unroll
    for (int ct=0; ct<4; ct++){
      bhalf8 bf = *(const bhalf8*)&Wbw[(ct*16 + m16)*256 + ks*32 + quad*8];
      acc[ct] = __builtin_amdgcn_mfma_f32_16x16x32_bf16(af[ks], bf, acc[ct], 0,0,0);
    }
  }
  #pragma unroll
  for (int ct=0; ct<4; ct++){
    #pragma unroll
    for (int e=0;e<4;e++){
      int row = quad*4 + e;
      int col = w*64 + ct*16 + m16;
      Dt[row][col] = acc[ct][e] + sc_b[col];
    }
  }
  __syncthreads();
  {
    int row = tid >> 4, seg = tid & 15;
    float s = 0.f, s2 = 0.f;
    #pragma unroll
    for (int i=0;i<4;i++){
      float4 v = *(const float4*)&Dt[row][seg*16 + i*4];
      s  += v.x+v.y+v.z+v.w;
      s2 += v.x*v.x + v.y*v.y + v.z*v.z + v.w*v.w;
    }
    red[row][seg] = s;
    __syncthreads();
    if (seg == 0){
      float t=0.f;
      #pragma unroll
      for (int i=0;i<16;i++) t += red[row][i];
      mu[row] = t * (1.f/DM);
    }
    __syncthreads();
    red[row][seg] = s2;
    __syncthreads();
    if (seg == 0){
      float t=0.f;
      #pragma unroll
      for (int i=0;i<16;i++) t += red[row][i];
      float m = mu[row];
      rs[row] = rsqrtf(t*(1.f/DM) - m*m + 1e-5f);
    }
  }
  __syncthreads();
  float gg = ln_g[tid], bb = ln_b[tid];
  #pragma unroll
  for (int r=0;r<16;r++)
    ident[(r0+r)*DM + tid] = (Dt[r][tid]-mu[r])*rs[r]*gg + bb;
}

// ================= fused conv + silu + x_dbl(MFMA) + dt =================
// grid 256: 16 rows/block
__global__ __launch_bounds__(256) void k_convdbl(
    const float* __restrict__ cw_spa, const float* __restrict__ cb_spa,
    const float* __restrict__ cw_spe, const float* __restrict__ cb_spe,
    const float* __restrict__ xc_raw,
    const unsigned short* __restrict__ Wxt_spa, const unsigned short* __restrict__ Wxt_spe,
    const float* __restrict__ Wdt_spa, const float* __restrict__ bdt_spa,
    const float* __restrict__ Wdt_spe, const float* __restrict__ bdt_spe,
    float* __restrict__ xc, float* __restrict__ dt,
    float* __restrict__ Bm, float* __restrict__ Cm)
{
  __shared__ unsigned short At[16][520];   // 16.6 KB  bf16 conv output
  __shared__ float xdbl[16][18];
  int tid = threadIdx.x;
  int r0 = blockIdx.x * 16;
  int branch = r0 >= HALF_ROWS;
  int l0 = r0 & (LD-1);
  const float* cw = branch ? cw_spe : cw_spa;
  const float* cb = branch ? cb_spe : cb_spa;
  const unsigned short* Wxt = branch ? Wxt_spe : Wxt_spa;
  const float* Wdt = branch ? Wdt_spe : Wdt_spa;
  const float* bdt = branch ? bdt_spe : bdt_spa;
  // conv phase: thread owns cols 2t, 2t+1
  {
    int c = tid*2;
    float4 w0 = *(const float4*)(cw + 4*c);
    float4 w1 = *(const float4*)(cw + 4*(c+1));
    float2 bias = *(const float2*)(cb + c);
    float2 h0, h1, h2;
    if (l0 > 0){
      h0 = *(const float2*)(xc_raw + (r0-3)*DI + c);
      h1 = *(const float2*)(xc_raw + (r0-2)*DI + c);
      h2 = *(const float2*)(xc_raw + (r0-1)*DI + c);
    } else {
      h0 = make_float2(0.f,0.f); h1 = h0; h2 = h0;
    }
    #pragma unroll
    for (int r=0;r<16;r++){
      float2 cur = *(const float2*)(xc_raw + (r0+r)*DI + c);
      float vx = bias.x;
      vx = fmaf(h0.x, w0.x, vx); vx = fmaf(h1.x, w0.y, vx);
      vx = fmaf(h2.x, w0.z, vx); vx = fmaf(cur.x, w0.w, vx);
      float vy = bias.y;
      vy = fmaf(h0.y, w1.x, vy); vy = fmaf(h1.y, w1.y, vy);
      vy = fmaf(h2.y, w1.z, vy); vy = fmaf(cur.y, w1.w, vy);
      vx = siluf(vx); vy = siluf(vy);
      *(float2*)(xc + (r0+r)*DI + c) = make_float2(vx, vy);
      unsigned int pk = (unsigned int)f2bf(vx) | ((unsigned int)f2bf(vy) << 16);
      *(unsigned int*)&At[r][c] = pk;
      h0 = h1; h1 = h2; h2 = cur;
    }
  }
  __syncthreads();
  // x_dbl MFMA: wave w -> padded cols w*16..+15 (48 real + 16 pad)
  int w = tid >> 6, lane = tid & 63;
  int m16 = lane & 15, quad = lane >> 4;
  f32x4 acc = (f32x4)(0.f);
  #pragma unroll
  for (int ks=0; ks<16; ks++){
    bhalf8 a = *(const bhalf8*)&At[m16][ks*32 + quad*8];
    bhalf8 bf = *(const bhalf8*)&Wxt[(w*16 + m16)*512 + ks*32 + quad*8];
    acc = __builtin_amdgcn_mfma_f32_16x16x32_bf16(a, bf, acc, 0,0,0);
  }
  #pragma unroll
  for (int e=0;e<4;e++){
    int row = quad*4 + e;
    float v = acc[e];
    if (w == 0)      xdbl[row][m16] = v;
    else if (w == 1) Bm[(r0+row)*DS + m16] = v;
    else if (w == 2) Cm[(r0+row)*DS + m16] = v;
  }
  __syncthreads();
  // dt GEMM: thread owns cols tid, tid+256
  float wdt0[16], wdt1[16];
  #pragma unroll
  for (int j=0;j<16;j++){ wdt0[j]=Wdt[j*DI+tid]; wdt1[j]=Wdt[j*DI+tid+256]; }
  float b0 = bdt[tid], b1 = bdt[tid+256];
  #pragma unroll
  for (int r=0;r<16;r++){
    float a0=b0, a1=b1;
    #pragma unroll
    for (int j=0;j<16;j++){
      float xv = xdbl[r][j];
      a0 = fmaf(xv, wdt0[j], a0);
      a1 = fmaf(xv, wdt1[j], a1);
    }
    dt[(r0+r)*DI + tid]       = softplusf(a0);
    dt[(r0+r)*DI + tid + 256] = softplusf(a1);
  }
}

// ================= selective scan v4: LDS-staged inputs, no shuffles =================
__global__ __launch_bounds__(256) void k_scan(
    const float* __restrict__ Alog_spa, const float* __restrict__ Dp_spa,
    const float* __restrict__ Alog_spe, const float* __restrict__ Dp_spe,
    const float* __restrict__ dt, const float* __restrict__ xc,
    const float* __restrict__ sz, const float* __restrict__ Bm,
    const float* __restrict__ Cm, float* __restrict__ y)
{
  __shared__ float dts[16][20], xcs[16][20], szs[16][20], Bs[16][20], Cs[16][20]; // 6.4 KB
  __shared__ float ypbuf[16][260];   // 16.6 KB
  __shared__ float Dsh[16];
  int tid = threadIdx.x;
  int bi = blockIdx.x;
  int branch = bi >> 8;
  int rem = bi & 255;
  int b = rem >> 5;
  int d0 = (rem & 31) * 16;
  const float* Alog = branch ? Alog_spe : Alog_spa;
  const float* Dp   = branch ? Dp_spe   : Dp_spa;
  int dg = tid >> 4, s = tid & 15;
  int d = d0 + dg;
  float A_ds = -__expf(Alog[d*DS + s]);
  if (tid < 16) Dsh[tid] = Dp[d0 + tid];
  int row0 = branch*HALF_ROWS + b*LD;
  int rli = tid >> 4, rdd = tid & 15;
  // staging coords: 320 float4s per chunk: arr 0..4 x (r 0..15, c4 0..3)
  float h = 0.f;
  for (int c=0; c<16; c++){
    int rbase = row0 + c*16;
    // stage
    for (int idx=tid; idx<320; idx+=256){
      int arr = idx >> 6;
      int j = idx & 63;
      int r = j >> 2, c4 = (j & 3)*4;
      float4 v;
      if      (arr == 0) v = *(const float4*)(dt + (rbase+r)*DI + d0 + c4);
      else if (arr == 1) v = *(const float4*)(xc + (rbase+r)*DI + d0 + c4);
      else if (arr == 2) v = *(const float4*)(sz + (rbase+r)*DI + d0 + c4);
      else if (arr == 3) v = *(const float4*)(Bm + (rbase+r)*DS + c4);
      else               v = *(const float4*)(Cm + (rbase+r)*DS + c4);
      if      (arr == 0) *(float4*)&dts[r][c4] = v;
      else if (arr == 1) *(float4*)&xcs[r][c4] = v;
      else if (arr == 2) *(float4*)&szs[r][c4] = v;
      else if (arr == 3) *(float4*)&Bs[r][c4]  = v;
      else               *(float4*)&Cs[r][c4]  = v;
    }
    __syncthreads();
    // serial scan, 16 steps
    #pragma unroll
    for (int li=0; li<16; li++){
      float dtv = dts[li][dg];
      float xcv = xcs[li][dg];
      float dA = __expf(dtv * A_ds);
      h = fmaf(dA, h, dtv * Bs[li][s] * xcv);
      ypbuf[li][s*16 + ((dg + s) & 15)] = h * Cs[li][s];
    }
    __syncthreads();
    // reduction: thread -> (rli, rdd)
    float acc = 0.f;
    #pragma unroll
    for (int ss=0; ss<16; ss++)
      acc += ypbuf[rli][ss*16 + ((rdd + ss) & 15)];
    float xcv = xcs[rli][rdd];
    float szv = szs[rli][rdd];
    y[(rbase+rli)*DI + d0 + rdd] = fmaf(xcv, Dsh[rdd], acc) * szv;
    __syncthreads();   // protect xcs/szs/ypbuf before next chunk's overwrite
  }
}

// ================= W_out GEMM + relu + residual + pool-accumulate (MFMA) =================
// grid 512: rb=bi>>1 (16 rows), ch=bi&1 (128 cols); wave w -> 32 cols
__global__ __launch_bounds__(256) void k_wout(
    const unsigned short* __restrict__ Wt_spa, const unsigned short* __restrict__ Wt_spe,
    const float* __restrict__ x_spa, const float* __restrict__ x_spe,
    const float* __restrict__ y, float* __restrict__ ae,
    float* __restrict__ pooled)
{
  __shared__ unsigned short At[16][520];   // 16.6 KB
  int tid = threadIdx.x;
  int bi = blockIdx.x;
  int r0 = (bi >> 1) * 16;
  int ch = bi & 1;
  int branch = (r0 >= HALF_ROWS);
  const unsigned short* Wt = branch ? Wt_spe : Wt_spa;
  const float* xb = branch ? x_spe : x_spa;
  int rr0 = branch ? r0 - HALF_ROWS : r0;
  for (int p=0;p<8;p++){
    int i4 = tid + 256*p;          // 0..2047
    int r = i4 >> 7, kq = (i4 & 127)*4;
    float4 v = *(const float4*)(y + (r0+r)*DI + kq);
    unsigned int lo = (unsigned int)f2bf(v.x) | ((unsigned int)f2bf(v.y) << 16);
    unsigned int hi = (unsigned int)f2bf(v.z) | ((unsigned int)f2bf(v.w) << 16);
    *(uint2*)&At[r][kq] = make_uint2(lo, hi);
  }
  __syncthreads();
  int w = tid >> 6, lane = tid & 63;
  int m16 = lane & 15, quad = lane >> 4;
  bhalf8 af[16];
  #pragma unroll
  for (int ks=0; ks<16; ks++)
    af[ks] = *(const bhalf8*)&At[m16][ks*32 + quad*8];
  f32x4 acc[2];
  #pragma unroll
  for (int ct=0; ct<2; ct++) acc[ct] = (f32x4)(0.f);
  const unsigned short* Wbw = Wt + (ch*128 + w*32)*512;
  #pragma unroll
  for (int ks=0; ks<16; ks++){
    #pragma unroll
    for (int ct=0; ct<2; ct++){
      bhalf8 bf = *(const bhalf8*)&Wbw[(ct*16 + m16)*512 + ks*32 + quad*8];
      acc[ct] = __builtin_amdgcn_mfma_f32_16x16x32_bf16(af[ks], bf, acc[ct], 0,0,0);
    }
  }
  float ps0 = 0.f, ps1 = 0.f;
  #pragma unroll
  for (int ct=0; ct<2; ct++){
    #pragma unroll
    for (int e=0;e<4;e++){
      int row = quad*4 + e;
      int col = ch*128 + w*32 + ct*16 + m16;
      float v = fmaxf(acc[ct][e], 0.f) + xb[(rr0+row)*DM + col];
      ae[(r0+row)*DM + col] = v;
      if (ct == 0) ps0 += v; else ps1 += v;
    }
  }
  // reduce over quad (rows) and atomically accumulate the mean-pool numerator
  ps0 += __shfl_xor(ps0, 16, 64); ps0 += __shfl_xor(ps0, 32, 64);
  ps1 += __shfl_xor(ps1, 16, 64); ps1 += __shfl_xor(ps1, 32, 64);
  if (quad == 0){
    int bidx = (r0 >> 8) & 7;
    atomicAdd(&pooled[bidx*DM + ch*128 + w*32 + m16],      ps0);
    atomicAdd(&pooled[bidx*DM + ch*128 + w*32 + 16 + m16], ps1);
  }
}

// ================= gate: fw = sigmoid((pooled*0.5/L) @ fusion_W) =================
__global__ __launch_bounds__(256) void k_gate(const float* __restrict__ pooled,
    const float* __restrict__ fW, float* __restrict__ fw)
{
  __shared__ float p[DM];
  int b=blockIdx.x, c=threadIdx.x;
  p[c] = pooled[b*DM+c] * (0.5f/LD);
  __syncthreads();
  float a=0.f;
  for(int k=0;k<DM;k+=4){
    a = fmaf(p[k+0], fW[(k+0)*DM+c], a);
    a = fmaf(p[k+1], fW[(k+1)*DM+c], a);
    a = fmaf(p[k+2], fW[(k+2)*DM+c], a);
    a = fmaf(p[k+3], fW[(k+3)*DM+c], a);
  }
  fw[b*DM+c]=1.f/(1.f+__expf(-a));
}

// ================= final: out = ae*fw + ident =================
__global__ __launch_bounds__(256) void k_final(const float* __restrict__ ae,
    const float* __restrict__ ident, const float* __restrict__ fw, float* __restrict__ out)
{
  int idx4 = blockIdx.x*256 + threadIdx.x;
  int row = idx4 >> 6;
  int b = (row >> 8) & 7;
  int c4 = (idx4 & 63) * 4;
  float4 av = *(const float4*)(ae + idx4*4);
  float4 iv = *(const float4*)(ident + idx4*4);
  float4 fv = *(const float4*)(fw + b*DM + c4);
  float4 o;
  o.x = fmaf(av.x, fv.x, iv.x);
  o.y = fmaf(av.y, fv.y, iv.y);
  o.z = fmaf(av.z, fv.z, iv.z);
  o.w = fmaf(av.w, fv.w, iv.w);
  *(float4*)(out + idx4*4) = o;
}

extern "C" void kernel_launch(void* const* d_in, const int* in_sizes, int n_in,
                              void* d_out, int out_size, void* d_ws, size_t ws_size,
                              hipStream_t stream) {
  const float* x_spa     = (const float*)d_in[0];
  const float* x_spe     = (const float*)d_in[1];
  const float* spa_ln_g  = (const float*)d_in[2];
  const float* spa_ln_b  = (const float*)d_in[3];
  const float* spa_W_in  = (const float*)d_in[4];
  const float* spa_cw    = (const float*)d_in[5];
  const float* spa_cb    = (const float*)d_in[6];
  const float* spa_W_x   = (const float*)d_in[7];
  const float* spa_W_dt  = (const float*)d_in[8];
  const float* spa_b_dt  = (const float*)d_in[9];
  const float* spa_A_log = (const float*)d_in[10];
  const float* spa_D     = (const float*)d_in[11];
  const float* spa_W_out = (const float*)d_in[12];
  const float* spe_ln_g  = (const float*)d_in[13];
  const float* spe_ln_b  = (const float*)d_in[14];
  const float* spe_W_in  = (const float*)d_in[15];
  const float* spe_cw    = (const float*)d_in[16];
  const float* spe_cb    = (const float*)d_in[17];
  const float* spe_W_x   = (const float*)d_in[18];
  const float* spe_W_dt  = (const float*)d_in[19];
  const float* spe_b_dt  = (const float*)d_in[20];
  const float* spe_A_log = (const float*)d_in[21];
  const float* spe_D     = (const float*)d_in[22];
  const float* spe_W_out = (const float*)d_in[23];
  const float* sc_W      = (const float*)d_in[24];
  const float* sc_b      = (const float*)d_in[25];
  const float* sc_ln_g   = (const float*)d_in[26];
  const float* sc_ln_b   = (const float*)d_in[27];
  const float* fusion_W  = (const float*)d_in[28];

  float* ws = (float*)d_ws;
  float* ident  = ws;                       // 4096*256
  float* xc_raw = ident  + NROWS*DM;        // 4096*512 (reused as y)
  float* sz     = xc_raw + NROWS*DI;        // 4096*512
  float* xc     = sz     + NROWS*DI;        // 4096*512
  float* dt     = xc     + NROWS*DI;        // 4096*512 (reused as ae)
  float* Bm     = dt     + NROWS*DI;        // 4096*16
  float* Cm     = Bm     + NROWS*DS;        // 4096*16
  float* pooled = Cm     + NROWS*DS;        // 8*256
  float* fw     = pooled + BD*DM;           // 8*256
  unsigned short* Wt_i_spa = (unsigned short*)(fw + BD*DM);
  unsigned short* Wt_i_spe = Wt_i_spa + 1024*256;
  unsigned short* Wt_o_spa = Wt_i_spe + 1024*256;
  unsigned short* Wt_o_spe = Wt_o_spa + 256*512;
  unsigned short* scWt     = Wt_o_spe + 256*512;
  unsigned short* Wxt_spa  = scWt     + 256*256;
  unsigned short* Wxt_spe  = Wxt_spa  + 64*512;

  float* out = (float*)d_out;

  k_transpose<<<61, 256, 0, stream>>>(spa_W_in, spe_W_in, spa_W_out, spe_W_out, sc_W,
                                      spa_W_x, spe_W_x,
                                      Wt_i_spa, Wt_i_spe, Wt_o_spa, Wt_o_spe, scWt,
                                      Wxt_spa, Wxt_spe, pooled);
  k_lnwin<<<1024, 256, 0, stream>>>(x_spa, x_spe, spa_ln_g, spa_ln_b, spe_ln_g, spe_ln_b,
                                    Wt_i_spa, Wt_i_spe, xc_raw, sz);
  k_convdbl<<<NROWS/16, 256, 0, stream>>>(spa_cw, spa_cb, spe_cw, spe_cb, xc_raw,
                                          Wxt_spa, Wxt_spe,
                                          spa_W_dt, spa_b_dt, spe_W_dt, spe_b_dt,
                                          xc, dt, Bm, Cm);
  float* y = xc_raw;   // xc_raw dead after k_convdbl
  k_scan<<<512, 256, 0, stream>>>(spa_A_log, spa_D, spe_A_log, spe_D, dt, xc, sz, Bm, Cm, y);
  k_shortcut<<<NROWS/16, 256, 0, stream>>>(x_spa, x_spe, scWt, sc_b, sc_ln_g, sc_ln_b, ident);
  float* ae = dt;      // dt dead after k_scan
  k_wout<<<512, 256, 0, stream>>>(Wt_o_spa, Wt_o_spe, x_spa, x_spe, y, ae, pooled);
  k_gate<<<BD, 256, 0, stream>>>(pooled, fusion_W, fw);
  k_final<<<NROWS*DM/1024, 256, 0, stream>>>(ae, ident, fw, out);
}

// Round 8
// 210.395 us; speedup vs baseline: 1.7203x; 1.0235x over previous
//
#include <hip/hip_runtime.h>
#include <hip/hip_bf16.h>
#include <math.h>

#define BD 8      // B
#define LD 256    // L
#define DM 256    // D_MODEL
#define DS 16     // D_STATE
#define DI 512    // D_INNER
#define RK 16     // DT_RANK

#define NROWS (2*BD*LD)   // 4096 rows (both branches concatenated)
#define HALF_ROWS (BD*LD) // 2048

typedef __attribute__((ext_vector_type(8))) short bhalf8;   // 8 bf16 = 4 VGPR
typedef __attribute__((ext_vector_type(4))) float f32x4;

__device__ __forceinline__ float siluf(float x){ return x / (1.f + __expf(-x)); }
__device__ __forceinline__ float softplusf(float x){
  return fmaxf(x, 0.f) + log1pf(__expf(-fabsf(x)));
}
__device__ __forceinline__ unsigned short f2bf(float f){
  __hip_bfloat16 h = __float2bfloat16(f);   // RNE
  return *reinterpret_cast<unsigned short*>(&h);
}

// ================= prep: weight transpose+cast, pooled zero, LN of x =================
// blocks 0..31: W_in tiles; 32..47: W_out; 48..51: sc_W; 52..59: W_x pad; 60: zero pooled
// blocks 61..316: LN of x (16 rows each) -> xnbf (normalized bf16) + xbf (raw bf16)
__global__ __launch_bounds__(256) void k_prep(
    const float* __restrict__ Wi_spa, const float* __restrict__ Wi_spe,
    const float* __restrict__ Wo_spa, const float* __restrict__ Wo_spe,
    const float* __restrict__ scW,
    const float* __restrict__ Wx_spa, const float* __restrict__ Wx_spe,
    const float* __restrict__ x_spa, const float* __restrict__ x_spe,
    const float* __restrict__ g_spa, const float* __restrict__ b_spa,
    const float* __restrict__ g_spe, const float* __restrict__ b_spe,
    unsigned short* __restrict__ Wt_i_spa, unsigned short* __restrict__ Wt_i_spe,
    unsigned short* __restrict__ Wt_o_spa, unsigned short* __restrict__ Wt_o_spe,
    unsigned short* __restrict__ scWt,
    unsigned short* __restrict__ Wxt_spa, unsigned short* __restrict__ Wxt_spe,
    unsigned short* __restrict__ xnbf, unsigned short* __restrict__ xbf,
    float* __restrict__ pooled)
{
  __shared__ __align__(16) unsigned char smem[59904];
  int b = blockIdx.x;
  int tid = threadIdx.x;
  if (b == 60){
    for (int i=tid; i<BD*DM; i+=256) pooled[i] = 0.f;
    return;
  }
  if (b >= 61){
    // LN blocks
    float (*xst)[260] = (float (*)[260])smem;          // 16x260 = 16640 B
    float (*red)[16]  = (float (*)[16])(smem + 16640); // 1024 B
    float *mu = (float*)(smem + 17664);
    float *rs = (float*)(smem + 17728);
    int r0g = (b - 61) * 16;
    int branch = r0g >= HALF_ROWS;
    const float* xb = branch ? x_spe : x_spa;
    const float* g  = branch ? g_spe : g_spa;
    const float* be = branch ? b_spe : b_spa;
    int rr0 = branch ? r0g - HALF_ROWS : r0g;
    for (int p=0;p<4;p++){
      int i4 = tid + 256*p;
      int r = i4 >> 6, c4 = (i4 & 63)*4;
      *(float4*)&xst[r][c4] = *(const float4*)(xb + (rr0+r)*DM + c4);
    }
    __syncthreads();
    {
      int row = tid >> 4, seg = tid & 15;
      float s = 0.f, s2 = 0.f;
      #pragma unroll
      for (int i=0;i<4;i++){
        float4 v = *(float4*)&xst[row][seg*16 + i*4];
        s  += v.x+v.y+v.z+v.w;
        s2 += v.x*v.x + v.y*v.y + v.z*v.z + v.w*v.w;
      }
      red[row][seg] = s;
      __syncthreads();
      if (seg == 0){
        float t=0.f;
        #pragma unroll
        for (int i=0;i<16;i++) t += red[row][i];
        mu[row] = t * (1.f/DM);
      }
      __syncthreads();
      red[row][seg] = s2;
      __syncthreads();
      if (seg == 0){
        float t=0.f;
        #pragma unroll
        for (int i=0;i<16;i++) t += red[row][i];
        float m = mu[row];
        rs[row] = rsqrtf(t*(1.f/DM) - m*m + 1e-6f);
      }
    }
    __syncthreads();
    for (int p=0;p<4;p++){
      int i4 = tid + 256*p;
      int r = i4 >> 6, c4 = (i4 & 63)*4;
      float4 v  = *(float4*)&xst[r][c4];
      float4 gv = *(const float4*)(g + c4);
      float4 bv = *(const float4*)(be + c4);
      float m = mu[r], rv = rs[r];
      // raw bf16
      unsigned int rlo = (unsigned int)f2bf(v.x) | ((unsigned int)f2bf(v.y) << 16);
      unsigned int rhi = (unsigned int)f2bf(v.z) | ((unsigned int)f2bf(v.w) << 16);
      *(uint2*)&xbf[(r0g+r)*DM + c4] = make_uint2(rlo, rhi);
      // normalized bf16
      unsigned int nlo = (unsigned int)f2bf((v.x-m)*rv*gv.x + bv.x)
                       | ((unsigned int)f2bf((v.y-m)*rv*gv.y + bv.y) << 16);
      unsigned int nhi = (unsigned int)f2bf((v.z-m)*rv*gv.z + bv.z)
                       | ((unsigned int)f2bf((v.w-m)*rv*gv.w + bv.w) << 16);
      *(uint2*)&xnbf[(r0g+r)*DM + c4] = make_uint2(nlo, nhi);
    }
    return;
  }
  if (b >= 52){
    int bb = b - 52;
    int branch = bb >> 2, chunk = bb & 3;
    int k0 = chunk*128;
    const float* Wx = branch ? Wx_spe : Wx_spa;
    unsigned short* Wxt = branch ? Wxt_spe : Wxt_spa;
    float (*tile2)[49] = (float (*)[49])(smem + 34816);
    for (int i=tid; i<128*48; i+=256){
      int kk = i/48, c = i - kk*48;
      tile2[kk][c] = Wx[(k0+kk)*48 + c];
    }
    __syncthreads();
    for (int i=tid; i<64*128; i+=256){
      int cc = i >> 7, kk = i & 127;
      float v = (cc < 48) ? tile2[kk][cc] : 0.f;
      Wxt[cc*512 + k0 + kk] = f2bf(v);
    }
    return;
  }
  unsigned short (*tile)[68] = (unsigned short (*)[68])smem;  // 34816 B
  const float* W; unsigned short* Wt; int N, K, c0, k0;
  if (b < 32){
    int bb = b & 15;
    W  = (b < 16) ? Wi_spa  : Wi_spe;
    Wt = (b < 16) ? Wt_i_spa: Wt_i_spe;
    N = 1024; K = 256; c0 = (bb >> 2)*256; k0 = (bb & 3)*64;
  } else if (b < 48){
    int bb = b - 32; int h = bb >> 3; bb &= 7;
    W  = h ? Wo_spe  : Wo_spa;
    Wt = h ? Wt_o_spe: Wt_o_spa;
    N = 256; K = 512; c0 = 0; k0 = bb*64;
  } else {
    int bb = b - 48;
    W = scW; Wt = scWt;
    N = 256; K = 256; c0 = 0; k0 = bb*64;
  }
  int c = c0 + tid;
  #pragma unroll 8
  for (int kk=0; kk<64; kk++)
    tile[tid][kk] = f2bf(W[(k0+kk)*N + c]);
  __syncthreads();
  for (int p=0; p<16; p++){
    int i = tid + 256*p;
    int cl = i >> 4, kq = (i & 15)*4;
    uint2 v = *(const uint2*)&tile[cl][kq];
    *(uint2*)&Wt[(c0+cl)*K + k0 + kq] = v;
  }
}

// ================= W_in GEMM (pure MFMA, inputs pre-normalized bf16) =================
// grid 1024: rg=bi>>2 (16 rows), cg=bi&3 (256 of 1024 cols); wave w -> 64 cols
__global__ __launch_bounds__(256) void k_lnwin(
    const unsigned short* __restrict__ xnbf,
    const unsigned short* __restrict__ Wt_spa, const unsigned short* __restrict__ Wt_spe,
    float* __restrict__ xc_raw, float* __restrict__ szout)
{
  __shared__ unsigned short At[16][264];   // 8.4 KB
  int tid = threadIdx.x;
  int bi = blockIdx.x;
  int rg = bi >> 2, cg = bi & 3;
  int r0 = rg * 16;
  int branch = (r0 >= HALF_ROWS);
  const unsigned short* Wt = branch ? Wt_spe : Wt_spa;
  for (int p=0;p<2;p++){
    int i = tid + 256*p;              // 0..511 octs
    int r = i >> 5, oct = (i & 31)*8;
    *(uint4*)&At[r][oct] = *(const uint4*)&xnbf[(r0+r)*DM + oct];
  }
  __syncthreads();
  int w = tid >> 6, lane = tid & 63;
  int m16 = lane & 15, quad = lane >> 4;
  bhalf8 af[8];
  #pragma unroll
  for (int ks=0; ks<8; ks++)
    af[ks] = *(const bhalf8*)&At[m16][ks*32 + quad*8];
  f32x4 acc[4];
  #pragma unroll
  for (int ct=0; ct<4; ct++) acc[ct] = (f32x4)(0.f);
  const unsigned short* Wbw = Wt + (cg*256 + w*64)*256;
  #pragma unroll
  for (int ks=0; ks<8; ks++){
    #pragma unroll
    for (int ct=0; ct<4; ct++){
      bhalf8 bf = *(const bhalf8*)&Wbw[(ct*16 + m16)*256 + ks*32 + quad*8];
      acc[ct] = __builtin_amdgcn_mfma_f32_16x16x32_bf16(af[ks], bf, acc[ct], 0,0,0);
    }
  }
  bool isz = (cg >= 2);
  float* outp = isz ? szout : xc_raw;
  int cbase = (cg & 1)*256 + w*64;
  #pragma unroll
  for (int ct=0; ct<4; ct++){
    #pragma unroll
    for (int e=0;e<4;e++){
      int row = r0 + quad*4 + e;
      int col = cbase + ct*16 + m16;
      float v = acc[ct][e];
      if (isz) v = siluf(v);
      outp[row*DI + col] = v;
    }
  }
}

// ================= shortcut GEMM + bias + LN (MFMA), 16 rows/block =================
__global__ __launch_bounds__(256) void k_shortcut(
    const unsigned short* __restrict__ xbf,
    const unsigned short* __restrict__ scWt, const float* __restrict__ sc_b,
    const float* __restrict__ ln_g, const float* __restrict__ ln_b,
    float* __restrict__ ident)
{
  __shared__ unsigned short At[16][264];   // 8.4 KB
  __shared__ float Dt[16][260];            // 16.6 KB
  __shared__ float red[16][16];
  __shared__ float mu[16], rs[16];
  int tid = threadIdx.x;
  int r0 = blockIdx.x * 16;
  for (int p=0;p<2;p++){
    int i = tid + 256*p;
    int r = i >> 5, oct = (i & 31)*8;
    *(uint4*)&At[r][oct] = *(const uint4*)&xbf[(r0+r)*DM + oct];
  }
  __syncthreads();
  int w = tid >> 6, lane = tid & 63;
  int m16 = lane & 15, quad = lane >> 4;
  bhalf8 af[8];
  #pragma unroll
  for (int ks=0; ks<8; ks++)
    af[ks] = *(const bhalf8*)&At[m16][ks*32 + quad*8];
  f32x4 acc[4];
  #pragma unroll
  for (int ct=0; ct<4; ct++) acc[ct] = (f32x4)(0.f);
  const unsigned short* Wbw = scWt + (w*64)*256;
  #pragma unroll
  for (int ks=0; ks<8; ks++){
    #pragma unroll
    for (int ct=0; ct<4; ct++){
      bhalf8 bf = *(const bhalf8*)&Wbw[(ct*16 + m16)*256 + ks*32 + quad*8];
      acc[ct] = __builtin_amdgcn_mfma_f32_16x16x32_bf16(af[ks], bf, acc[ct], 0,0,0);
    }
  }
  #pragma unroll
  for (int ct=0; ct<4; ct++){
    #pragma unroll
    for (int e=0;e<4;e++){
      int row = quad*4 + e;
      int col = w*64 + ct*16 + m16;
      Dt[row][col] = acc[ct][e] + sc_b[col];
    }
  }
  __syncthreads();
  {
    int row = tid >> 4, seg = tid & 15;
    float s = 0.f, s2 = 0.f;
    #pragma unroll
    for (int i=0;i<4;i++){
      float4 v = *(const float4*)&Dt[row][seg*16 + i*4];
      s  += v.x+v.y+v.z+v.w;
      s2 += v.x*v.x + v.y*v.y + v.z*v.z + v.w*v.w;
    }
    red[row][seg] = s;
    __syncthreads();
    if (seg == 0){
      float t=0.f;
      #pragma unroll
      for (int i=0;i<16;i++) t += red[row][i];
      mu[row] = t * (1.f/DM);
    }
    __syncthreads();
    red[row][seg] = s2;
    __syncthreads();
    if (seg == 0){
      float t=0.f;
      #pragma unroll
      for (int i=0;i<16;i++) t += red[row][i];
      float m = mu[row];
      rs[row] = rsqrtf(t*(1.f/DM) - m*m + 1e-5f);
    }
  }
  __syncthreads();
  float gg = ln_g[tid], bb = ln_b[tid];
  #pragma unroll
  for (int r=0;r<16;r++)
    ident[(r0+r)*DM + tid] = (Dt[r][tid]-mu[r])*rs[r]*gg + bb;
}

// ================= fused conv + silu + x_dbl(MFMA) + dt =================
// grid 256: 16 rows/block
__global__ __launch_bounds__(256) void k_convdbl(
    const float* __restrict__ cw_spa, const float* __restrict__ cb_spa,
    const float* __restrict__ cw_spe, const float* __restrict__ cb_spe,
    const float* __restrict__ xc_raw,
    const unsigned short* __restrict__ Wxt_spa, const unsigned short* __restrict__ Wxt_spe,
    const float* __restrict__ Wdt_spa, const float* __restrict__ bdt_spa,
    const float* __restrict__ Wdt_spe, const float* __restrict__ bdt_spe,
    float* __restrict__ xc, float* __restrict__ dt,
    float* __restrict__ Bm, float* __restrict__ Cm)
{
  __shared__ unsigned short At[16][520];   // 16.6 KB  bf16 conv output
  __shared__ float xdbl[16][18];
  int tid = threadIdx.x;
  int r0 = blockIdx.x * 16;
  int branch = r0 >= HALF_ROWS;
  int l0 = r0 & (LD-1);
  const float* cw = branch ? cw_spe : cw_spa;
  const float* cb = branch ? cb_spe : cb_spa;
  const unsigned short* Wxt = branch ? Wxt_spe : Wxt_spa;
  const float* Wdt = branch ? Wdt_spe : Wdt_spa;
  const float* bdt = branch ? bdt_spe : bdt_spa;
  {
    int c = tid*2;
    float4 w0 = *(const float4*)(cw + 4*c);
    float4 w1 = *(const float4*)(cw + 4*(c+1));
    float2 bias = *(const float2*)(cb + c);
    float2 h0, h1, h2;
    if (l0 > 0){
      h0 = *(const float2*)(xc_raw + (r0-3)*DI + c);
      h1 = *(const float2*)(xc_raw + (r0-2)*DI + c);
      h2 = *(const float2*)(xc_raw + (r0-1)*DI + c);
    } else {
      h0 = make_float2(0.f,0.f); h1 = h0; h2 = h0;
    }
    #pragma unroll
    for (int r=0;r<16;r++){
      float2 cur = *(const float2*)(xc_raw + (r0+r)*DI + c);
      float vx = bias.x;
      vx = fmaf(h0.x, w0.x, vx); vx = fmaf(h1.x, w0.y, vx);
      vx = fmaf(h2.x, w0.z, vx); vx = fmaf(cur.x, w0.w, vx);
      float vy = bias.y;
      vy = fmaf(h0.y, w1.x, vy); vy = fmaf(h1.y, w1.y, vy);
      vy = fmaf(h2.y, w1.z, vy); vy = fmaf(cur.y, w1.w, vy);
      vx = siluf(vx); vy = siluf(vy);
      *(float2*)(xc + (r0+r)*DI + c) = make_float2(vx, vy);
      unsigned int pk = (unsigned int)f2bf(vx) | ((unsigned int)f2bf(vy) << 16);
      *(unsigned int*)&At[r][c] = pk;
      h0 = h1; h1 = h2; h2 = cur;
    }
  }
  __syncthreads();
  int w = tid >> 6, lane = tid & 63;
  int m16 = lane & 15, quad = lane >> 4;
  f32x4 acc = (f32x4)(0.f);
  #pragma unroll
  for (int ks=0; ks<16; ks++){
    bhalf8 a = *(const bhalf8*)&At[m16][ks*32 + quad*8];
    bhalf8 bf = *(const bhalf8*)&Wxt[(w*16 + m16)*512 + ks*32 + quad*8];
    acc = __builtin_amdgcn_mfma_f32_16x16x32_bf16(a, bf, acc, 0,0,0);
  }
  #pragma unroll
  for (int e=0;e<4;e++){
    int row = quad*4 + e;
    float v = acc[e];
    if (w == 0)      xdbl[row][m16] = v;
    else if (w == 1) Bm[(r0+row)*DS + m16] = v;
    else if (w == 2) Cm[(r0+row)*DS + m16] = v;
  }
  __syncthreads();
  float wdt0[16], wdt1[16];
  #pragma unroll
  for (int j=0;j<16;j++){ wdt0[j]=Wdt[j*DI+tid]; wdt1[j]=Wdt[j*DI+tid+256]; }
  float b0 = bdt[tid], b1 = bdt[tid+256];
  #pragma unroll
  for (int r=0;r<16;r++){
    float a0=b0, a1=b1;
    #pragma unroll
    for (int j=0;j<16;j++){
      float xv = xdbl[r][j];
      a0 = fmaf(xv, wdt0[j], a0);
      a1 = fmaf(xv, wdt1[j], a1);
    }
    dt[(r0+r)*DI + tid]       = softplusf(a0);
    dt[(r0+r)*DI + tid + 256] = softplusf(a1);
  }
}

// ================= selective scan v5: register inputs, bf16 output =================
__global__ __launch_bounds__(256) void k_scan(
    const float* __restrict__ Alog_spa, const float* __restrict__ Dp_spa,
    const float* __restrict__ Alog_spe, const float* __restrict__ Dp_spe,
    const float* __restrict__ dt, const float* __restrict__ xc,
    const float* __restrict__ sz, const float* __restrict__ Bm,
    const float* __restrict__ Cm, unsigned short* __restrict__ ybf)
{
  __shared__ float dts[16][20], xcs[16][20];   // 2.5 KB
  __shared__ float ypbuf[16][260];             // 16.6 KB
  __shared__ float Dsh[16];
  int tid = threadIdx.x;
  int bi = blockIdx.x;
  int branch = bi >> 8;
  int rem = bi & 255;
  int b = rem >> 5;
  int d0 = (rem & 31) * 16;
  const float* Alog = branch ? Alog_spe : Alog_spa;
  const float* Dp   = branch ? Dp_spe   : Dp_spa;
  int dg = tid >> 4, s = tid & 15;
  int d = d0 + dg;
  float A_ds = -__expf(Alog[d*DS + s]);
  if (tid < 16) Dsh[tid] = Dp[d0 + tid];
  int row0 = branch*HALF_ROWS + b*LD;
  float h = 0.f;
  for (int c=0; c<16; c++){
    int rbase = row0 + c*16;
    // direct global loads of B,C (each wave-instruction = 1 cache line)
    float rB[16], rC[16];
    #pragma unroll
    for (int li=0; li<16; li++){
      rB[li] = Bm[(rbase+li)*DS + s];
      rC[li] = Cm[(rbase+li)*DS + s];
    }
    // stage dt/xc tile (threads 0..127, one float4 each)
    if (tid < 128){
      int arr = tid >> 6, j = tid & 63;
      int r = j >> 2, c4 = (j & 3)*4;
      if (arr == 0) *(float4*)&dts[r][c4] = *(const float4*)(dt + (rbase+r)*DI + d0 + c4);
      else          *(float4*)&xcs[r][c4] = *(const float4*)(xc + (rbase+r)*DI + d0 + c4);
    }
    __syncthreads();
    // pre-read own column into registers
    float rdt[16], rxc[16];
    #pragma unroll
    for (int li=0; li<16; li++){ rdt[li] = dts[li][dg]; rxc[li] = xcs[li][dg]; }
    float yp[16];
    #pragma unroll
    for (int li=0; li<16; li++){
      float dA = __expf(rdt[li] * A_ds);
      h = fmaf(dA, h, rdt[li] * rB[li] * rxc[li]);
      yp[li] = h * rC[li];
    }
    #pragma unroll
    for (int li=0; li<16; li++)
      ypbuf[li][s*16 + ((dg + s) & 15)] = yp[li];
    __syncthreads();
    // reduction: thread -> (rli=dg, rdd=s)
    float acc = 0.f;
    #pragma unroll
    for (int ss=0; ss<16; ss++)
      acc += ypbuf[dg][ss*16 + ((s + ss) & 15)];
    float xcv = xc[(rbase+dg)*DI + d0 + s];
    float szv = sz[(rbase+dg)*DI + d0 + s];
    float yv = fmaf(xcv, Dsh[s], acc) * szv;
    ybf[(rbase+dg)*DI + d0 + s] = f2bf(yv);
    __syncthreads();
  }
}

// ================= W_out GEMM + relu + residual + pool-accumulate (MFMA) =================
// grid 512: rb=bi>>1 (16 rows), ch=bi&1 (128 cols); wave w -> 32 cols
__global__ __launch_bounds__(256) void k_wout(
    const unsigned short* __restrict__ Wt_spa, const unsigned short* __restrict__ Wt_spe,
    const float* __restrict__ x_spa, const float* __restrict__ x_spe,
    const unsigned short* __restrict__ ybf, float* __restrict__ ae,
    float* __restrict__ pooled)
{
  __shared__ unsigned short At[16][520];   // 16.6 KB
  int tid = threadIdx.x;
  int bi = blockIdx.x;
  int r0 = (bi >> 1) * 16;
  int ch = bi & 1;
  int branch = (r0 >= HALF_ROWS);
  const unsigned short* Wt = branch ? Wt_spe : Wt_spa;
  const float* xb = branch ? x_spe : x_spa;
  int rr0 = branch ? r0 - HALF_ROWS : r0;
  for (int p=0;p<4;p++){
    int i = tid + 256*p;               // 0..1023 octs
    int r = i >> 6, oct = (i & 63)*8;
    *(uint4*)&At[r][oct] = *(const uint4*)&ybf[(r0+r)*DI + oct];
  }
  __syncthreads();
  int w = tid >> 6, lane = tid & 63;
  int m16 = lane & 15, quad = lane >> 4;
  bhalf8 af[16];
  #pragma unroll
  for (int ks=0; ks<16; ks++)
    af[ks] = *(const bhalf8*)&At[m16][ks*32 + quad*8];
  f32x4 acc[2];
  #pragma unroll
  for (int ct=0; ct<2; ct++) acc[ct] = (f32x4)(0.f);
  const unsigned short* Wbw = Wt + (ch*128 + w*32)*512;
  #pragma unroll
  for (int ks=0; ks<16; ks++){
    #pragma unroll
    for (int ct=0; ct<2; ct++){
      bhalf8 bf = *(const bhalf8*)&Wbw[(ct*16 + m16)*512 + ks*32 + quad*8];
      acc[ct] = __builtin_amdgcn_mfma_f32_16x16x32_bf16(af[ks], bf, acc[ct], 0,0,0);
    }
  }
  float ps0 = 0.f, ps1 = 0.f;
  #pragma unroll
  for (int ct=0; ct<2; ct++){
    #pragma unroll
    for (int e=0;e<4;e++){
      int row = quad*4 + e;
      int col = ch*128 + w*32 + ct*16 + m16;
      float v = fmaxf(acc[ct][e], 0.f) + xb[(rr0+row)*DM + col];
      ae[(r0+row)*DM + col] = v;
      if (ct == 0) ps0 += v; else ps1 += v;
    }
  }
  ps0 += __shfl_xor(ps0, 16, 64); ps0 += __shfl_xor(ps0, 32, 64);
  ps1 += __shfl_xor(ps1, 16, 64); ps1 += __shfl_xor(ps1, 32, 64);
  if (quad == 0){
    int bidx = (r0 >> 8) & 7;
    atomicAdd(&pooled[bidx*DM + ch*128 + w*32 + m16],      ps0);
    atomicAdd(&pooled[bidx*DM + ch*128 + w*32 + 16 + m16], ps1);
  }
}

// ================= gate: fw = sigmoid((pooled*0.5/L) @ fusion_W) =================
__global__ __launch_bounds__(256) void k_gate(const float* __restrict__ pooled,
    const float* __restrict__ fW, float* __restrict__ fw)
{
  __shared__ float p[DM];
  int b=blockIdx.x, c=threadIdx.x;
  p[c] = pooled[b*DM+c] * (0.5f/LD);
  __syncthreads();
  float a=0.f;
  for(int k=0;k<DM;k+=4){
    a = fmaf(p[k+0], fW[(k+0)*DM+c], a);
    a = fmaf(p[k+1], fW[(k+1)*DM+c], a);
    a = fmaf(p[k+2], fW[(k+2)*DM+c], a);
    a = fmaf(p[k+3], fW[(k+3)*DM+c], a);
  }
  fw[b*DM+c]=1.f/(1.f+__expf(-a));
}

// ================= final: out = ae*fw + ident =================
__global__ __launch_bounds__(256) void k_final(const float* __restrict__ ae,
    const float* __restrict__ ident, const float* __restrict__ fw, float* __restrict__ out)
{
  int idx4 = blockIdx.x*256 + threadIdx.x;
  int row = idx4 >> 6;
  int b = (row >> 8) & 7;
  int c4 = (idx4 & 63) * 4;
  float4 av = *(const float4*)(ae + idx4*4);
  float4 iv = *(const float4*)(ident + idx4*4);
  float4 fv = *(const float4*)(fw + b*DM + c4);
  float4 o;
  o.x = fmaf(av.x, fv.x, iv.x);
  o.y = fmaf(av.y, fv.y, iv.y);
  o.z = fmaf(av.z, fv.z, iv.z);
  o.w = fmaf(av.w, fv.w, iv.w);
  *(float4*)(out + idx4*4) = o;
}

extern "C" void kernel_launch(void* const* d_in, const int* in_sizes, int n_in,
                              void* d_out, int out_size, void* d_ws, size_t ws_size,
                              hipStream_t stream) {
  const float* x_spa     = (const float*)d_in[0];
  const float* x_spe     = (const float*)d_in[1];
  const float* spa_ln_g  = (const float*)d_in[2];
  const float* spa_ln_b  = (const float*)d_in[3];
  const float* spa_W_in  = (const float*)d_in[4];
  const float* spa_cw    = (const float*)d_in[5];
  const float* spa_cb    = (const float*)d_in[6];
  const float* spa_W_x   = (const float*)d_in[7];
  const float* spa_W_dt  = (const float*)d_in[8];
  const float* spa_b_dt  = (const float*)d_in[9];
  const float* spa_A_log = (const float*)d_in[10];
  const float* spa_D     = (const float*)d_in[11];
  const float* spa_W_out = (const float*)d_in[12];
  const float* spe_ln_g  = (const float*)d_in[13];
  const float* spe_ln_b  = (const float*)d_in[14];
  const float* spe_W_in  = (const float*)d_in[15];
  const float* spe_cw    = (const float*)d_in[16];
  const float* spe_cb    = (const float*)d_in[17];
  const float* spe_W_x   = (const float*)d_in[18];
  const float* spe_W_dt  = (const float*)d_in[19];
  const float* spe_b_dt  = (const float*)d_in[20];
  const float* spe_A_log = (const float*)d_in[21];
  const float* spe_D     = (const float*)d_in[22];
  const float* spe_W_out = (const float*)d_in[23];
  const float* sc_W      = (const float*)d_in[24];
  const float* sc_b      = (const float*)d_in[25];
  const float* sc_ln_g   = (const float*)d_in[26];
  const float* sc_ln_b   = (const float*)d_in[27];
  const float* fusion_W  = (const float*)d_in[28];

  float* ws = (float*)d_ws;
  float* ident  = ws;                       // 4096*256
  float* xc_raw = ident  + NROWS*DM;        // 4096*512 (reused as ybf)
  float* sz     = xc_raw + NROWS*DI;        // 4096*512
  float* xc     = sz     + NROWS*DI;        // 4096*512
  float* dt     = xc     + NROWS*DI;        // 4096*512 (reused as ae)
  float* Bm     = dt     + NROWS*DI;        // 4096*16
  float* Cm     = Bm     + NROWS*DS;        // 4096*16
  float* pooled = Cm     + NROWS*DS;        // 8*256
  float* fw     = pooled + BD*DM;           // 8*256
  unsigned short* Wt_i_spa = (unsigned short*)(fw + BD*DM);
  unsigned short* Wt_i_spe = Wt_i_spa + 1024*256;
  unsigned short* Wt_o_spa = Wt_i_spe + 1024*256;
  unsigned short* Wt_o_spe = Wt_o_spa + 256*512;
  unsigned short* scWt     = Wt_o_spe + 256*512;
  unsigned short* Wxt_spa  = scWt     + 256*256;
  unsigned short* Wxt_spe  = Wxt_spa  + 64*512;
  unsigned short* xnbf     = Wxt_spe  + 64*512;   // 4096*256 bf16
  unsigned short* xbf      = xnbf     + NROWS*DM; // 4096*256 bf16

  float* out = (float*)d_out;

  k_prep<<<317, 256, 0, stream>>>(spa_W_in, spe_W_in, spa_W_out, spe_W_out, sc_W,
                                  spa_W_x, spe_W_x, x_spa, x_spe,
                                  spa_ln_g, spa_ln_b, spe_ln_g, spe_ln_b,
                                  Wt_i_spa, Wt_i_spe, Wt_o_spa, Wt_o_spe, scWt,
                                  Wxt_spa, Wxt_spe, xnbf, xbf, pooled);
  k_lnwin<<<1024, 256, 0, stream>>>(xnbf, Wt_i_spa, Wt_i_spe, xc_raw, sz);
  k_convdbl<<<NROWS/16, 256, 0, stream>>>(spa_cw, spa_cb, spe_cw, spe_cb, xc_raw,
                                          Wxt_spa, Wxt_spe,
                                          spa_W_dt, spa_b_dt, spe_W_dt, spe_b_dt,
                                          xc, dt, Bm, Cm);
  unsigned short* ybf = (unsigned short*)xc_raw;   // xc_raw dead after k_convdbl
  k_scan<<<512, 256, 0, stream>>>(spa_A_log, spa_D, spe_A_log, spe_D, dt, xc, sz, Bm, Cm, ybf);
  k_shortcut<<<NROWS/16, 256, 0, stream>>>(xbf, scWt, sc_b, sc_ln_g, sc_ln_b, ident);
  float* ae = dt;      // dt dead after k_scan
  k_wout<<<512, 256, 0, stream>>>(Wt_o_spa, Wt_o_spe, x_spa, x_spe, ybf, ae, pooled);
  k_gate<<<BD, 256, 0, stream>>>(pooled, fusion_W, fw);
  k_final<<<NROWS*DM/1024, 256, 0, stream>>>(ae, ident, fw, out);
}

// Round 9
// 208.922 us; speedup vs baseline: 1.7325x; 1.0070x over previous
//
#include <hip/hip_runtime.h>
#include <hip/hip_bf16.h>
#include <math.h>

#define BD 8      // B
#define LD 256    // L
#define DM 256    // D_MODEL
#define DS 16     // D_STATE
#define DI 512    // D_INNER
#define RK 16     // DT_RANK

#define NROWS (2*BD*LD)   // 4096 rows (both branches concatenated)
#define HALF_ROWS (BD*LD) // 2048

typedef __attribute__((ext_vector_type(8))) short bhalf8;   // 8 bf16 = 4 VGPR
typedef __attribute__((ext_vector_type(4))) float f32x4;

__device__ __forceinline__ float siluf(float x){ return x / (1.f + __expf(-x)); }
__device__ __forceinline__ float softplusf(float x){
  return fmaxf(x, 0.f) + log1pf(__expf(-fabsf(x)));
}
__device__ __forceinline__ unsigned short f2bf(float f){
  __hip_bfloat16 h = __float2bfloat16(f);   // RNE
  return *reinterpret_cast<unsigned short*>(&h);
}

// Fragment-ordered weight layout: flat = ((ct*(K/32)+ks)*64 + quad*16 + m16)*8 + j
// so a wave B-load is W + f*512 + lane*8  (fully coalesced 1KB).

// ================= prep: weights -> fragment-order bf16, LN of x, zero pooled =================
// blocks 0..31: W_in; 32..47: W_out; 48..51: sc_W; 52..59: W_x pad; 60: zero pooled
// blocks 61..316: LN of x (16 rows each) -> xnbf + xbf
__global__ __launch_bounds__(256) void k_prep(
    const float* __restrict__ Wi_spa, const float* __restrict__ Wi_spe,
    const float* __restrict__ Wo_spa, const float* __restrict__ Wo_spe,
    const float* __restrict__ scW,
    const float* __restrict__ Wx_spa, const float* __restrict__ Wx_spe,
    const float* __restrict__ x_spa, const float* __restrict__ x_spe,
    const float* __restrict__ g_spa, const float* __restrict__ b_spa,
    const float* __restrict__ g_spe, const float* __restrict__ b_spe,
    unsigned short* __restrict__ Wt_i_spa, unsigned short* __restrict__ Wt_i_spe,
    unsigned short* __restrict__ Wt_o_spa, unsigned short* __restrict__ Wt_o_spe,
    unsigned short* __restrict__ scWt,
    unsigned short* __restrict__ Wxt_spa, unsigned short* __restrict__ Wxt_spe,
    unsigned short* __restrict__ xnbf, unsigned short* __restrict__ xbf,
    float* __restrict__ pooled)
{
  __shared__ __align__(16) unsigned char smem[59904];
  int b = blockIdx.x;
  int tid = threadIdx.x;
  if (b == 60){
    for (int i=tid; i<BD*DM; i+=256) pooled[i] = 0.f;
    return;
  }
  if (b >= 61){
    float (*xst)[260] = (float (*)[260])smem;
    float (*red)[16]  = (float (*)[16])(smem + 16640);
    float *mu = (float*)(smem + 17664);
    float *rs = (float*)(smem + 17728);
    int r0g = (b - 61) * 16;
    int branch = r0g >= HALF_ROWS;
    const float* xb = branch ? x_spe : x_spa;
    const float* g  = branch ? g_spe : g_spa;
    const float* be = branch ? b_spe : b_spa;
    int rr0 = branch ? r0g - HALF_ROWS : r0g;
    for (int p=0;p<4;p++){
      int i4 = tid + 256*p;
      int r = i4 >> 6, c4 = (i4 & 63)*4;
      *(float4*)&xst[r][c4] = *(const float4*)(xb + (rr0+r)*DM + c4);
    }
    __syncthreads();
    {
      int row = tid >> 4, seg = tid & 15;
      float s = 0.f, s2 = 0.f;
      #pragma unroll
      for (int i=0;i<4;i++){
        float4 v = *(float4*)&xst[row][seg*16 + i*4];
        s  += v.x+v.y+v.z+v.w;
        s2 += v.x*v.x + v.y*v.y + v.z*v.z + v.w*v.w;
      }
      red[row][seg] = s;
      __syncthreads();
      if (seg == 0){
        float t=0.f;
        #pragma unroll
        for (int i=0;i<16;i++) t += red[row][i];
        mu[row] = t * (1.f/DM);
      }
      __syncthreads();
      red[row][seg] = s2;
      __syncthreads();
      if (seg == 0){
        float t=0.f;
        #pragma unroll
        for (int i=0;i<16;i++) t += red[row][i];
        float m = mu[row];
        rs[row] = rsqrtf(t*(1.f/DM) - m*m + 1e-6f);
      }
    }
    __syncthreads();
    for (int p=0;p<4;p++){
      int i4 = tid + 256*p;
      int r = i4 >> 6, c4 = (i4 & 63)*4;
      float4 v  = *(float4*)&xst[r][c4];
      float4 gv = *(const float4*)(g + c4);
      float4 bv = *(const float4*)(be + c4);
      float m = mu[r], rv = rs[r];
      unsigned int rlo = (unsigned int)f2bf(v.x) | ((unsigned int)f2bf(v.y) << 16);
      unsigned int rhi = (unsigned int)f2bf(v.z) | ((unsigned int)f2bf(v.w) << 16);
      *(uint2*)&xbf[(r0g+r)*DM + c4] = make_uint2(rlo, rhi);
      unsigned int nlo = (unsigned int)f2bf((v.x-m)*rv*gv.x + bv.x)
                       | ((unsigned int)f2bf((v.y-m)*rv*gv.y + bv.y) << 16);
      unsigned int nhi = (unsigned int)f2bf((v.z-m)*rv*gv.z + bv.z)
                       | ((unsigned int)f2bf((v.w-m)*rv*gv.w + bv.w) << 16);
      *(uint2*)&xnbf[(r0g+r)*DM + c4] = make_uint2(nlo, nhi);
    }
    return;
  }
  if (b >= 52){
    // W_x (512x48) -> frag order, padded to 64 cols; K=512 -> 16 segs
    int bb = b - 52;
    int branch = bb >> 2, chunk = bb & 3;
    int k0 = chunk*128;
    const float* Wx = branch ? Wx_spe : Wx_spa;
    unsigned short* Wxt = branch ? Wxt_spe : Wxt_spa;
    float (*tile2)[49] = (float (*)[49])(smem + 34816);
    for (int i=tid; i<128*48; i+=256){
      int kk = i/48, c = i - kk*48;
      tile2[kk][c] = Wx[(k0+kk)*48 + c];
    }
    __syncthreads();
    for (int i=tid; i<64*128; i+=256){
      int cc = i >> 7, kk = i & 127;
      float v = (cc < 48) ? tile2[kk][cc] : 0.f;
      int kg = k0 + kk;
      int ct = cc >> 4, m16 = cc & 15;
      int ks = kg >> 5, quad = (kg >> 3) & 3, j = kg & 7;
      Wxt[((ct*16 + ks)*64 + quad*16 + m16)*8 + j] = f2bf(v);
    }
    return;
  }
  unsigned short (*tile)[68] = (unsigned short (*)[68])smem;
  const float* W; unsigned short* Wt; int N, K, c0, k0;
  if (b < 32){
    int bb = b & 15;
    W  = (b < 16) ? Wi_spa  : Wi_spe;
    Wt = (b < 16) ? Wt_i_spa: Wt_i_spe;
    N = 1024; K = 256; c0 = (bb >> 2)*256; k0 = (bb & 3)*64;
  } else if (b < 48){
    int bb = b - 32; int h = bb >> 3; bb &= 7;
    W  = h ? Wo_spe  : Wo_spa;
    Wt = h ? Wt_o_spe: Wt_o_spa;
    N = 256; K = 512; c0 = 0; k0 = bb*64;
  } else {
    int bb = b - 48;
    W = scW; Wt = scWt;
    N = 256; K = 256; c0 = 0; k0 = bb*64;
  }
  int c = c0 + tid;
  #pragma unroll 8
  for (int kk=0; kk<64; kk++)
    tile[tid][kk] = f2bf(W[(k0+kk)*N + c]);
  __syncthreads();
  int ksegs = K >> 5;
  for (int p=0; p<16; p++){
    int i = tid + 256*p;
    int cl = i >> 4, kq = (i & 15)*4;
    int cg = c0 + cl;
    int ct = cg >> 4, m16 = cg & 15;
    int kg = k0 + kq;
    int ks = kg >> 5, quad = (kg >> 3) & 3, j = kg & 7;
    uint2 v = *(const uint2*)&tile[cl][kq];
    *(uint2*)&Wt[((ct*ksegs + ks)*64 + quad*16 + m16)*8 + j] = v;
  }
}

// ================= merged W_in GEMM (bi<1024) + shortcut GEMM+LN (bi>=1024) =================
__global__ __launch_bounds__(256) void k_gemm1(
    const unsigned short* __restrict__ xnbf, const unsigned short* __restrict__ xbf,
    const unsigned short* __restrict__ Wt_spa, const unsigned short* __restrict__ Wt_spe,
    const unsigned short* __restrict__ scWt, const float* __restrict__ sc_b,
    const float* __restrict__ ln_g, const float* __restrict__ ln_b,
    float* __restrict__ xc_raw, float* __restrict__ szout, float* __restrict__ ident)
{
  __shared__ unsigned short At[16][264];   // 8.4 KB
  __shared__ float Dt[16][260];            // 16.6 KB (shortcut only)
  __shared__ float red[16][16];
  __shared__ float mu[16], rs[16];
  int tid = threadIdx.x;
  int bi = blockIdx.x;
  int w = tid >> 6, lane = tid & 63;
  int m16 = lane & 15, quad = lane >> 4;
  if (bi < 1024){
    int rg = bi >> 2, cg = bi & 3;
    int r0 = rg * 16;
    int branch = (r0 >= HALF_ROWS);
    const unsigned short* Wt = branch ? Wt_spe : Wt_spa;
    for (int p=0;p<2;p++){
      int i = tid + 256*p;
      int r = i >> 5, oct = (i & 31)*8;
      *(uint4*)&At[r][oct] = *(const uint4*)&xnbf[(r0+r)*DM + oct];
    }
    __syncthreads();
    bhalf8 af[8];
    #pragma unroll
    for (int ks=0; ks<8; ks++)
      af[ks] = *(const bhalf8*)&At[m16][ks*32 + quad*8];
    f32x4 acc[4];
    #pragma unroll
    for (int ct=0; ct<4; ct++) acc[ct] = (f32x4)(0.f);
    #pragma unroll
    for (int ks=0; ks<8; ks++){
      #pragma unroll
      for (int ct=0; ct<4; ct++){
        int f = (cg*16 + w*4 + ct)*8 + ks;
        bhalf8 bf = *(const bhalf8*)&Wt[f*512 + lane*8];
        acc[ct] = __builtin_amdgcn_mfma_f32_16x16x32_bf16(af[ks], bf, acc[ct], 0,0,0);
      }
    }
    bool isz = (cg >= 2);
    float* outp = isz ? szout : xc_raw;
    int cbase = (cg & 1)*256 + w*64;
    #pragma unroll
    for (int ct=0; ct<4; ct++){
      #pragma unroll
      for (int e=0;e<4;e++){
        int row = r0 + quad*4 + e;
        int col = cbase + ct*16 + m16;
        float v = acc[ct][e];
        if (isz) v = siluf(v);
        outp[row*DI + col] = v;
      }
    }
  } else {
    int r0 = (bi - 1024) * 16;
    for (int p=0;p<2;p++){
      int i = tid + 256*p;
      int r = i >> 5, oct = (i & 31)*8;
      *(uint4*)&At[r][oct] = *(const uint4*)&xbf[(r0+r)*DM + oct];
    }
    __syncthreads();
    bhalf8 af[8];
    #pragma unroll
    for (int ks=0; ks<8; ks++)
      af[ks] = *(const bhalf8*)&At[m16][ks*32 + quad*8];
    f32x4 acc[4];
    #pragma unroll
    for (int ct=0; ct<4; ct++) acc[ct] = (f32x4)(0.f);
    #pragma unroll
    for (int ks=0; ks<8; ks++){
      #pragma unroll
      for (int ct=0; ct<4; ct++){
        int f = (w*4 + ct)*8 + ks;
        bhalf8 bf = *(const bhalf8*)&scWt[f*512 + lane*8];
        acc[ct] = __builtin_amdgcn_mfma_f32_16x16x32_bf16(af[ks], bf, acc[ct], 0,0,0);
      }
    }
    #pragma unroll
    for (int ct=0; ct<4; ct++){
      #pragma unroll
      for (int e=0;e<4;e++){
        int row = quad*4 + e;
        int col = w*64 + ct*16 + m16;
        Dt[row][col] = acc[ct][e] + sc_b[col];
      }
    }
    __syncthreads();
    {
      int row = tid >> 4, seg = tid & 15;
      float s = 0.f, s2 = 0.f;
      #pragma unroll
      for (int i=0;i<4;i++){
        float4 v = *(const float4*)&Dt[row][seg*16 + i*4];
        s  += v.x+v.y+v.z+v.w;
        s2 += v.x*v.x + v.y*v.y + v.z*v.z + v.w*v.w;
      }
      red[row][seg] = s;
      __syncthreads();
      if (seg == 0){
        float t=0.f;
        #pragma unroll
        for (int i=0;i<16;i++) t += red[row][i];
        mu[row] = t * (1.f/DM);
      }
      __syncthreads();
      red[row][seg] = s2;
      __syncthreads();
      if (seg == 0){
        float t=0.f;
        #pragma unroll
        for (int i=0;i<16;i++) t += red[row][i];
        float m = mu[row];
        rs[row] = rsqrtf(t*(1.f/DM) - m*m + 1e-5f);
      }
    }
    __syncthreads();
    float gg = ln_g[tid], bb = ln_b[tid];
    #pragma unroll
    for (int r=0;r<16;r++)
      ident[(r0+r)*DM + tid] = (Dt[r][tid]-mu[r])*rs[r]*gg + bb;
  }
}

// ================= fused conv + silu + x_dbl(MFMA) + dt =================
__global__ __launch_bounds__(256) void k_convdbl(
    const float* __restrict__ cw_spa, const float* __restrict__ cb_spa,
    const float* __restrict__ cw_spe, const float* __restrict__ cb_spe,
    const float* __restrict__ xc_raw,
    const unsigned short* __restrict__ Wxt_spa, const unsigned short* __restrict__ Wxt_spe,
    const float* __restrict__ Wdt_spa, const float* __restrict__ bdt_spa,
    const float* __restrict__ Wdt_spe, const float* __restrict__ bdt_spe,
    float* __restrict__ xc, float* __restrict__ dt,
    float* __restrict__ Bm, float* __restrict__ Cm)
{
  __shared__ unsigned short At[16][520];   // 16.6 KB
  __shared__ float xdbl[16][18];
  int tid = threadIdx.x;
  int r0 = blockIdx.x * 16;
  int branch = r0 >= HALF_ROWS;
  int l0 = r0 & (LD-1);
  const float* cw = branch ? cw_spe : cw_spa;
  const float* cb = branch ? cb_spe : cb_spa;
  const unsigned short* Wxt = branch ? Wxt_spe : Wxt_spa;
  const float* Wdt = branch ? Wdt_spe : Wdt_spa;
  const float* bdt = branch ? bdt_spe : bdt_spa;
  {
    int c = tid*2;
    float4 w0 = *(const float4*)(cw + 4*c);
    float4 w1 = *(const float4*)(cw + 4*(c+1));
    float2 bias = *(const float2*)(cb + c);
    float2 h0, h1, h2;
    if (l0 > 0){
      h0 = *(const float2*)(xc_raw + (r0-3)*DI + c);
      h1 = *(const float2*)(xc_raw + (r0-2)*DI + c);
      h2 = *(const float2*)(xc_raw + (r0-1)*DI + c);
    } else {
      h0 = make_float2(0.f,0.f); h1 = h0; h2 = h0;
    }
    #pragma unroll
    for (int r=0;r<16;r++){
      float2 cur = *(const float2*)(xc_raw + (r0+r)*DI + c);
      float vx = bias.x;
      vx = fmaf(h0.x, w0.x, vx); vx = fmaf(h1.x, w0.y, vx);
      vx = fmaf(h2.x, w0.z, vx); vx = fmaf(cur.x, w0.w, vx);
      float vy = bias.y;
      vy = fmaf(h0.y, w1.x, vy); vy = fmaf(h1.y, w1.y, vy);
      vy = fmaf(h2.y, w1.z, vy); vy = fmaf(cur.y, w1.w, vy);
      vx = siluf(vx); vy = siluf(vy);
      *(float2*)(xc + (r0+r)*DI + c) = make_float2(vx, vy);
      unsigned int pk = (unsigned int)f2bf(vx) | ((unsigned int)f2bf(vy) << 16);
      *(unsigned int*)&At[r][c] = pk;
      h0 = h1; h1 = h2; h2 = cur;
    }
  }
  __syncthreads();
  int w = tid >> 6, lane = tid & 63;
  int m16 = lane & 15, quad = lane >> 4;
  f32x4 acc = (f32x4)(0.f);
  #pragma unroll
  for (int ks=0; ks<16; ks++){
    bhalf8 a = *(const bhalf8*)&At[m16][ks*32 + quad*8];
    int f = w*16 + ks;
    bhalf8 bf = *(const bhalf8*)&Wxt[f*512 + lane*8];
    acc = __builtin_amdgcn_mfma_f32_16x16x32_bf16(a, bf, acc, 0,0,0);
  }
  #pragma unroll
  for (int e=0;e<4;e++){
    int row = quad*4 + e;
    float v = acc[e];
    if (w == 0)      xdbl[row][m16] = v;
    else if (w == 1) Bm[(r0+row)*DS + m16] = v;
    else if (w == 2) Cm[(r0+row)*DS + m16] = v;
  }
  __syncthreads();
  float wdt0[16], wdt1[16];
  #pragma unroll
  for (int j=0;j<16;j++){ wdt0[j]=Wdt[j*DI+tid]; wdt1[j]=Wdt[j*DI+tid+256]; }
  float b0 = bdt[tid], b1 = bdt[tid+256];
  #pragma unroll
  for (int r=0;r<16;r++){
    float a0=b0, a1=b1;
    #pragma unroll
    for (int j=0;j<16;j++){
      float xv = xdbl[r][j];
      a0 = fmaf(xv, wdt0[j], a0);
      a1 = fmaf(xv, wdt1[j], a1);
    }
    dt[(r0+r)*DI + tid]       = softplusf(a0);
    dt[(r0+r)*DI + tid + 256] = softplusf(a1);
  }
}

// ================= selective scan v6: 32-row chunks, shuffle reduction =================
__global__ __launch_bounds__(256) void k_scan(
    const float* __restrict__ Alog_spa, const float* __restrict__ Dp_spa,
    const float* __restrict__ Alog_spe, const float* __restrict__ Dp_spe,
    const float* __restrict__ dt, const float* __restrict__ xc,
    const float* __restrict__ sz, const float* __restrict__ Bm,
    const float* __restrict__ Cm, unsigned short* __restrict__ ybf)
{
  __shared__ float dts[32][20], xcs[32][20], szs[32][20], Bs[32][20], Cs[32][20]; // 12.8 KB
  __shared__ float Dsh[16];
  int tid = threadIdx.x;
  int bi = blockIdx.x;
  int branch = bi >> 8;
  int rem = bi & 255;
  int b = rem >> 5;
  int d0 = (rem & 31) * 16;
  const float* Alog = branch ? Alog_spe : Alog_spa;
  const float* Dp   = branch ? Dp_spe   : Dp_spa;
  int dg = tid >> 4, s = tid & 15;
  int d = d0 + dg;
  float A_ds = -__expf(Alog[d*DS + s]);
  if (tid < 16) Dsh[tid] = Dp[d0 + tid];
  int row0 = branch*HALF_ROWS + b*LD;
  float h = 0.f;
  for (int c=0; c<8; c++){
    int rbase = row0 + c*32;
    // stage: 5 arrays x 32 rows x 4 float4 = 640
    for (int idx=tid; idx<640; idx+=256){
      int arr = idx >> 7;
      int j = idx & 127;
      int r = j >> 2, c4 = (j & 3)*4;
      float4 v;
      if      (arr == 0) v = *(const float4*)(dt + (rbase+r)*DI + d0 + c4);
      else if (arr == 1) v = *(const float4*)(xc + (rbase+r)*DI + d0 + c4);
      else if (arr == 2) v = *(const float4*)(sz + (rbase+r)*DI + d0 + c4);
      else if (arr == 3) v = *(const float4*)(Bm + (rbase+r)*DS + c4);
      else               v = *(const float4*)(Cm + (rbase+r)*DS + c4);
      if      (arr == 0) *(float4*)&dts[r][c4] = v;
      else if (arr == 1) *(float4*)&xcs[r][c4] = v;
      else if (arr == 2) *(float4*)&szs[r][c4] = v;
      else if (arr == 3) *(float4*)&Bs[r][c4]  = v;
      else               *(float4*)&Cs[r][c4]  = v;
    }
    __syncthreads();
    float yp[32];
    #pragma unroll
    for (int li=0; li<32; li++){
      float dtv = dts[li][dg];
      float xcv = xcs[li][dg];
      float dA = __expf(dtv * A_ds);
      h = fmaf(dA, h, dtv * Bs[li][s] * xcv);
      yp[li] = h * Cs[li][s];
    }
    // butterfly allreduce over s (lanes within 16-group)
    #pragma unroll
    for (int li=0; li<32; li++){
      yp[li] += __shfl_xor(yp[li], 1, 64);
      yp[li] += __shfl_xor(yp[li], 2, 64);
      yp[li] += __shfl_xor(yp[li], 4, 64);
      yp[li] += __shfl_xor(yp[li], 8, 64);
    }
    // thread (dg,s) stores rows li=s and li=s+16 for column d0+dg
    {
      float Dv = Dsh[dg];
      float v0 = fmaf(xcs[s][dg],    Dv, yp[s])    * szs[s][dg];
      float v1 = fmaf(xcs[s+16][dg], Dv, yp[s+16]) * szs[s+16][dg];
      ybf[(rbase+s)*DI    + d0 + dg] = f2bf(v0);
      ybf[(rbase+s+16)*DI + d0 + dg] = f2bf(v1);
    }
    __syncthreads();
  }
}

// ================= W_out GEMM + relu + residual + pool-accumulate (MFMA) =================
__global__ __launch_bounds__(256) void k_wout(
    const unsigned short* __restrict__ Wt_spa, const unsigned short* __restrict__ Wt_spe,
    const float* __restrict__ x_spa, const float* __restrict__ x_spe,
    const unsigned short* __restrict__ ybf, float* __restrict__ ae,
    float* __restrict__ pooled)
{
  __shared__ unsigned short At[16][520];   // 16.6 KB
  int tid = threadIdx.x;
  int bi = blockIdx.x;
  int r0 = (bi >> 1) * 16;
  int ch = bi & 1;
  int branch = (r0 >= HALF_ROWS);
  const unsigned short* Wt = branch ? Wt_spe : Wt_spa;
  const float* xb = branch ? x_spe : x_spa;
  int rr0 = branch ? r0 - HALF_ROWS : r0;
  for (int p=0;p<4;p++){
    int i = tid + 256*p;
    int r = i >> 6, oct = (i & 63)*8;
    *(uint4*)&At[r][oct] = *(const uint4*)&ybf[(r0+r)*DI + oct];
  }
  __syncthreads();
  int w = tid >> 6, lane = tid & 63;
  int m16 = lane & 15, quad = lane >> 4;
  bhalf8 af[16];
  #pragma unroll
  for (int ks=0; ks<16; ks++)
    af[ks] = *(const bhalf8*)&At[m16][ks*32 + quad*8];
  f32x4 acc[2];
  #pragma unroll
  for (int ct=0; ct<2; ct++) acc[ct] = (f32x4)(0.f);
  #pragma unroll
  for (int ks=0; ks<16; ks++){
    #pragma unroll
    for (int ct=0; ct<2; ct++){
      int f = (ch*8 + w*2 + ct)*16 + ks;
      bhalf8 bf = *(const bhalf8*)&Wt[f*512 + lane*8];
      acc[ct] = __builtin_amdgcn_mfma_f32_16x16x32_bf16(af[ks], bf, acc[ct], 0,0,0);
    }
  }
  float ps0 = 0.f, ps1 = 0.f;
  #pragma unroll
  for (int ct=0; ct<2; ct++){
    #pragma unroll
    for (int e=0;e<4;e++){
      int row = quad*4 + e;
      int col = ch*128 + w*32 + ct*16 + m16;
      float v = fmaxf(acc[ct][e], 0.f) + xb[(rr0+row)*DM + col];
      ae[(r0+row)*DM + col] = v;
      if (ct == 0) ps0 += v; else ps1 += v;
    }
  }
  ps0 += __shfl_xor(ps0, 16, 64); ps0 += __shfl_xor(ps0, 32, 64);
  ps1 += __shfl_xor(ps1, 16, 64); ps1 += __shfl_xor(ps1, 32, 64);
  if (quad == 0){
    int bidx = (r0 >> 8) & 7;
    atomicAdd(&pooled[bidx*DM + ch*128 + w*32 + m16],      ps0);
    atomicAdd(&pooled[bidx*DM + ch*128 + w*32 + 16 + m16], ps1);
  }
}

// ================= gate: fw = sigmoid((pooled*0.5/L) @ fusion_W) =================
__global__ __launch_bounds__(256) void k_gate(const float* __restrict__ pooled,
    const float* __restrict__ fW, float* __restrict__ fw)
{
  __shared__ float p[DM];
  int b=blockIdx.x, c=threadIdx.x;
  p[c] = pooled[b*DM+c] * (0.5f/LD);
  __syncthreads();
  float a=0.f;
  for(int k=0;k<DM;k+=4){
    a = fmaf(p[k+0], fW[(k+0)*DM+c], a);
    a = fmaf(p[k+1], fW[(k+1)*DM+c], a);
    a = fmaf(p[k+2], fW[(k+2)*DM+c], a);
    a = fmaf(p[k+3], fW[(k+3)*DM+c], a);
  }
  fw[b*DM+c]=1.f/(1.f+__expf(-a));
}

// ================= final: out = ae*fw + ident =================
__global__ __launch_bounds__(256) void k_final(const float* __restrict__ ae,
    const float* __restrict__ ident, const float* __restrict__ fw, float* __restrict__ out)
{
  int idx4 = blockIdx.x*256 + threadIdx.x;
  int row = idx4 >> 6;
  int b = (row >> 8) & 7;
  int c4 = (idx4 & 63) * 4;
  float4 av = *(const float4*)(ae + idx4*4);
  float4 iv = *(const float4*)(ident + idx4*4);
  float4 fv = *(const float4*)(fw + b*DM + c4);
  float4 o;
  o.x = fmaf(av.x, fv.x, iv.x);
  o.y = fmaf(av.y, fv.y, iv.y);
  o.z = fmaf(av.z, fv.z, iv.z);
  o.w = fmaf(av.w, fv.w, iv.w);
  *(float4*)(out + idx4*4) = o;
}

extern "C" void kernel_launch(void* const* d_in, const int* in_sizes, int n_in,
                              void* d_out, int out_size, void* d_ws, size_t ws_size,
                              hipStream_t stream) {
  const float* x_spa     = (const float*)d_in[0];
  const float* x_spe     = (const float*)d_in[1];
  const float* spa_ln_g  = (const float*)d_in[2];
  const float* spa_ln_b  = (const float*)d_in[3];
  const float* spa_W_in  = (const float*)d_in[4];
  const float* spa_cw    = (const float*)d_in[5];
  const float* spa_cb    = (const float*)d_in[6];
  const float* spa_W_x   = (const float*)d_in[7];
  const float* spa_W_dt  = (const float*)d_in[8];
  const float* spa_b_dt  = (const float*)d_in[9];
  const float* spa_A_log = (const float*)d_in[10];
  const float* spa_D     = (const float*)d_in[11];
  const float* spa_W_out = (const float*)d_in[12];
  const float* spe_ln_g  = (const float*)d_in[13];
  const float* spe_ln_b  = (const float*)d_in[14];
  const float* spe_W_in  = (const float*)d_in[15];
  const float* spe_cw    = (const float*)d_in[16];
  const float* spe_cb    = (const float*)d_in[17];
  const float* spe_W_x   = (const float*)d_in[18];
  const float* spe_W_dt  = (const float*)d_in[19];
  const float* spe_b_dt  = (const float*)d_in[20];
  const float* spe_A_log = (const float*)d_in[21];
  const float* spe_D     = (const float*)d_in[22];
  const float* spe_W_out = (const float*)d_in[23];
  const float* sc_W      = (const float*)d_in[24];
  const float* sc_b      = (const float*)d_in[25];
  const float* sc_ln_g   = (const float*)d_in[26];
  const float* sc_ln_b   = (const float*)d_in[27];
  const float* fusion_W  = (const float*)d_in[28];

  float* ws = (float*)d_ws;
  float* ident  = ws;                       // 4096*256
  float* xc_raw = ident  + NROWS*DM;        // 4096*512 (reused as ybf)
  float* sz     = xc_raw + NROWS*DI;        // 4096*512
  float* xc     = sz     + NROWS*DI;        // 4096*512
  float* dt     = xc     + NROWS*DI;        // 4096*512 (reused as ae)
  float* Bm     = dt     + NROWS*DI;        // 4096*16
  float* Cm     = Bm     + NROWS*DS;        // 4096*16
  float* pooled = Cm     + NROWS*DS;        // 8*256
  float* fw     = pooled + BD*DM;           // 8*256
  unsigned short* Wt_i_spa = (unsigned short*)(fw + BD*DM);
  unsigned short* Wt_i_spe = Wt_i_spa + 1024*256;
  unsigned short* Wt_o_spa = Wt_i_spe + 1024*256;
  unsigned short* Wt_o_spe = Wt_o_spa + 256*512;
  unsigned short* scWt     = Wt_o_spe + 256*512;
  unsigned short* Wxt_spa  = scWt     + 256*256;
  unsigned short* Wxt_spe  = Wxt_spa  + 64*512;
  unsigned short* xnbf     = Wxt_spe  + 64*512;   // 4096*256 bf16
  unsigned short* xbf      = xnbf     + NROWS*DM; // 4096*256 bf16

  float* out = (float*)d_out;

  k_prep<<<317, 256, 0, stream>>>(spa_W_in, spe_W_in, spa_W_out, spe_W_out, sc_W,
                                  spa_W_x, spe_W_x, x_spa, x_spe,
                                  spa_ln_g, spa_ln_b, spe_ln_g, spe_ln_b,
                                  Wt_i_spa, Wt_i_spe, Wt_o_spa, Wt_o_spe, scWt,
                                  Wxt_spa, Wxt_spe, xnbf, xbf, pooled);
  k_gemm1<<<1280, 256, 0, stream>>>(xnbf, xbf, Wt_i_spa, Wt_i_spe, scWt, sc_b,
                                    sc_ln_g, sc_ln_b, xc_raw, sz, ident);
  k_convdbl<<<NROWS/16, 256, 0, stream>>>(spa_cw, spa_cb, spe_cw, spe_cb, xc_raw,
                                          Wxt_spa, Wxt_spe,
                                          spa_W_dt, spa_b_dt, spe_W_dt, spe_b_dt,
                                          xc, dt, Bm, Cm);
  unsigned short* ybf = (unsigned short*)xc_raw;   // xc_raw dead after k_convdbl
  k_scan<<<512, 256, 0, stream>>>(spa_A_log, spa_D, spe_A_log, spe_D, dt, xc, sz, Bm, Cm, ybf);
  float* ae = dt;      // dt dead after k_scan
  k_wout<<<512, 256, 0, stream>>>(Wt_o_spa, Wt_o_spe, x_spa, x_spe, ybf, ae, pooled);
  k_gate<<<BD, 256, 0, stream>>>(pooled, fusion_W, fw);
  k_final<<<NROWS*DM/1024, 256, 0, stream>>>(ae, ident, fw, out);
}

// Round 10
// 197.115 us; speedup vs baseline: 1.8363x; 1.0599x over previous
//
#include <hip/hip_runtime.h>
#include <hip/hip_bf16.h>
#include <math.h>

#define BD 8      // B
#define LD 256    // L
#define DM 256    // D_MODEL
#define DS 16     // D_STATE
#define DI 512    // D_INNER
#define RK 16     // DT_RANK

#define NROWS (2*BD*LD)   // 4096 rows (both branches concatenated)
#define HALF_ROWS (BD*LD) // 2048

typedef __attribute__((ext_vector_type(8))) short bhalf8;   // 8 bf16 = 4 VGPR
typedef __attribute__((ext_vector_type(4))) float f32x4;

__device__ __forceinline__ float siluf(float x){ return x / (1.f + __expf(-x)); }
__device__ __forceinline__ float softplusf(float x){
  return fmaxf(x, 0.f) + log1pf(__expf(-fabsf(x)));
}
__device__ __forceinline__ unsigned short f2bf(float f){
  __hip_bfloat16 h = __float2bfloat16(f);   // RNE
  return *reinterpret_cast<unsigned short*>(&h);
}

// Fragment-ordered weight layout: flat = ((ct*(K/32)+ks)*64 + quad*16 + m16)*8 + j
// so a wave B-load is W + f*512 + lane*8  (fully coalesced 1KB).

// ================= prep: weights -> fragment-order bf16, LN of x, zero pooled =================
// blocks 0..31: W_in; 32..47: W_out; 48..51: sc_W; 52..59: W_x pad; 60: zero pooled
// blocks 61..316: LN of x (16 rows each) -> xnbf + xbf
__global__ __launch_bounds__(256) void k_prep(
    const float* __restrict__ Wi_spa, const float* __restrict__ Wi_spe,
    const float* __restrict__ Wo_spa, const float* __restrict__ Wo_spe,
    const float* __restrict__ scW,
    const float* __restrict__ Wx_spa, const float* __restrict__ Wx_spe,
    const float* __restrict__ x_spa, const float* __restrict__ x_spe,
    const float* __restrict__ g_spa, const float* __restrict__ b_spa,
    const float* __restrict__ g_spe, const float* __restrict__ b_spe,
    unsigned short* __restrict__ Wt_i_spa, unsigned short* __restrict__ Wt_i_spe,
    unsigned short* __restrict__ Wt_o_spa, unsigned short* __restrict__ Wt_o_spe,
    unsigned short* __restrict__ scWt,
    unsigned short* __restrict__ Wxt_spa, unsigned short* __restrict__ Wxt_spe,
    unsigned short* __restrict__ xnbf, unsigned short* __restrict__ xbf,
    float* __restrict__ pooled)
{
  __shared__ __align__(16) unsigned char smem[59904];
  int b = blockIdx.x;
  int tid = threadIdx.x;
  if (b == 60){
    for (int i=tid; i<BD*DM; i+=256) pooled[i] = 0.f;
    return;
  }
  if (b >= 61){
    float (*xst)[260] = (float (*)[260])smem;
    float (*red)[16]  = (float (*)[16])(smem + 16640);
    float *mu = (float*)(smem + 17664);
    float *rs = (float*)(smem + 17728);
    int r0g = (b - 61) * 16;
    int branch = r0g >= HALF_ROWS;
    const float* xb = branch ? x_spe : x_spa;
    const float* g  = branch ? g_spe : g_spa;
    const float* be = branch ? b_spe : b_spa;
    int rr0 = branch ? r0g - HALF_ROWS : r0g;
    for (int p=0;p<4;p++){
      int i4 = tid + 256*p;
      int r = i4 >> 6, c4 = (i4 & 63)*4;
      *(float4*)&xst[r][c4] = *(const float4*)(xb + (rr0+r)*DM + c4);
    }
    __syncthreads();
    {
      int row = tid >> 4, seg = tid & 15;
      float s = 0.f, s2 = 0.f;
      #pragma unroll
      for (int i=0;i<4;i++){
        float4 v = *(float4*)&xst[row][seg*16 + i*4];
        s  += v.x+v.y+v.z+v.w;
        s2 += v.x*v.x + v.y*v.y + v.z*v.z + v.w*v.w;
      }
      red[row][seg] = s;
      __syncthreads();
      if (seg == 0){
        float t=0.f;
        #pragma unroll
        for (int i=0;i<16;i++) t += red[row][i];
        mu[row] = t * (1.f/DM);
      }
      __syncthreads();
      red[row][seg] = s2;
      __syncthreads();
      if (seg == 0){
        float t=0.f;
        #pragma unroll
        for (int i=0;i<16;i++) t += red[row][i];
        float m = mu[row];
        rs[row] = rsqrtf(t*(1.f/DM) - m*m + 1e-6f);
      }
    }
    __syncthreads();
    for (int p=0;p<4;p++){
      int i4 = tid + 256*p;
      int r = i4 >> 6, c4 = (i4 & 63)*4;
      float4 v  = *(float4*)&xst[r][c4];
      float4 gv = *(const float4*)(g + c4);
      float4 bv = *(const float4*)(be + c4);
      float m = mu[r], rv = rs[r];
      unsigned int rlo = (unsigned int)f2bf(v.x) | ((unsigned int)f2bf(v.y) << 16);
      unsigned int rhi = (unsigned int)f2bf(v.z) | ((unsigned int)f2bf(v.w) << 16);
      *(uint2*)&xbf[(r0g+r)*DM + c4] = make_uint2(rlo, rhi);
      unsigned int nlo = (unsigned int)f2bf((v.x-m)*rv*gv.x + bv.x)
                       | ((unsigned int)f2bf((v.y-m)*rv*gv.y + bv.y) << 16);
      unsigned int nhi = (unsigned int)f2bf((v.z-m)*rv*gv.z + bv.z)
                       | ((unsigned int)f2bf((v.w-m)*rv*gv.w + bv.w) << 16);
      *(uint2*)&xnbf[(r0g+r)*DM + c4] = make_uint2(nlo, nhi);
    }
    return;
  }
  if (b >= 52){
    // W_x (512x48) -> frag order, padded to 64 cols; K=512 -> 16 segs
    int bb = b - 52;
    int branch = bb >> 2, chunk = bb & 3;
    int k0 = chunk*128;
    const float* Wx = branch ? Wx_spe : Wx_spa;
    unsigned short* Wxt = branch ? Wxt_spe : Wxt_spa;
    float (*tile2)[49] = (float (*)[49])(smem + 34816);
    for (int i=tid; i<128*48; i+=256){
      int kk = i/48, c = i - kk*48;
      tile2[kk][c] = Wx[(k0+kk)*48 + c];
    }
    __syncthreads();
    for (int i=tid; i<64*128; i+=256){
      int cc = i >> 7, kk = i & 127;
      float v = (cc < 48) ? tile2[kk][cc] : 0.f;
      int kg = k0 + kk;
      int ct = cc >> 4, m16 = cc & 15;
      int ks = kg >> 5, quad = (kg >> 3) & 3, j = kg & 7;
      Wxt[((ct*16 + ks)*64 + quad*16 + m16)*8 + j] = f2bf(v);
    }
    return;
  }
  unsigned short (*tile)[68] = (unsigned short (*)[68])smem;
  const float* W; unsigned short* Wt; int N, K, c0, k0;
  if (b < 32){
    int bb = b & 15;
    W  = (b < 16) ? Wi_spa  : Wi_spe;
    Wt = (b < 16) ? Wt_i_spa: Wt_i_spe;
    N = 1024; K = 256; c0 = (bb >> 2)*256; k0 = (bb & 3)*64;
  } else if (b < 48){
    int bb = b - 32; int h = bb >> 3; bb &= 7;
    W  = h ? Wo_spe  : Wo_spa;
    Wt = h ? Wt_o_spe: Wt_o_spa;
    N = 256; K = 512; c0 = 0; k0 = bb*64;
  } else {
    int bb = b - 48;
    W = scW; Wt = scWt;
    N = 256; K = 256; c0 = 0; k0 = bb*64;
  }
  int c = c0 + tid;
  #pragma unroll 8
  for (int kk=0; kk<64; kk++)
    tile[tid][kk] = f2bf(W[(k0+kk)*N + c]);
  __syncthreads();
  int ksegs = K >> 5;
  for (int p=0; p<16; p++){
    int i = tid + 256*p;
    int cl = i >> 4, kq = (i & 15)*4;
    int cg = c0 + cl;
    int ct = cg >> 4, m16 = cg & 15;
    int kg = k0 + kq;
    int ks = kg >> 5, quad = (kg >> 3) & 3, j = kg & 7;
    uint2 v = *(const uint2*)&tile[cl][kq];
    *(uint2*)&Wt[((ct*ksegs + ks)*64 + quad*16 + m16)*8 + j] = v;
  }
}

// ================= merged W_in GEMM (bi<1024) + shortcut GEMM+LN (bi>=1024) =================
__global__ __launch_bounds__(256) void k_gemm1(
    const unsigned short* __restrict__ xnbf, const unsigned short* __restrict__ xbf,
    const unsigned short* __restrict__ Wt_spa, const unsigned short* __restrict__ Wt_spe,
    const unsigned short* __restrict__ scWt, const float* __restrict__ sc_b,
    const float* __restrict__ ln_g, const float* __restrict__ ln_b,
    float* __restrict__ xc_raw, float* __restrict__ szout, float* __restrict__ ident)
{
  __shared__ unsigned short At[16][264];   // 8.4 KB
  __shared__ float Dt[16][260];            // 16.6 KB (shortcut only)
  __shared__ float red[16][16];
  __shared__ float mu[16], rs[16];
  int tid = threadIdx.x;
  int bi = blockIdx.x;
  int w = tid >> 6, lane = tid & 63;
  int m16 = lane & 15, quad = lane >> 4;
  if (bi < 1024){
    int rg = bi >> 2, cg = bi & 3;
    int r0 = rg * 16;
    int branch = (r0 >= HALF_ROWS);
    const unsigned short* Wt = branch ? Wt_spe : Wt_spa;
    for (int p=0;p<2;p++){
      int i = tid + 256*p;
      int r = i >> 5, oct = (i & 31)*8;
      *(uint4*)&At[r][oct] = *(const uint4*)&xnbf[(r0+r)*DM + oct];
    }
    __syncthreads();
    bhalf8 af[8];
    #pragma unroll
    for (int ks=0; ks<8; ks++)
      af[ks] = *(const bhalf8*)&At[m16][ks*32 + quad*8];
    f32x4 acc[4];
    #pragma unroll
    for (int ct=0; ct<4; ct++) acc[ct] = (f32x4)(0.f);
    #pragma unroll
    for (int ks=0; ks<8; ks++){
      #pragma unroll
      for (int ct=0; ct<4; ct++){
        int f = (cg*16 + w*4 + ct)*8 + ks;
        bhalf8 bf = *(const bhalf8*)&Wt[f*512 + lane*8];
        acc[ct] = __builtin_amdgcn_mfma_f32_16x16x32_bf16(af[ks], bf, acc[ct], 0,0,0);
      }
    }
    bool isz = (cg >= 2);
    float* outp = isz ? szout : xc_raw;
    int cbase = (cg & 1)*256 + w*64;
    #pragma unroll
    for (int ct=0; ct<4; ct++){
      #pragma unroll
      for (int e=0;e<4;e++){
        int row = r0 + quad*4 + e;
        int col = cbase + ct*16 + m16;
        float v = acc[ct][e];
        if (isz) v = siluf(v);
        outp[row*DI + col] = v;
      }
    }
  } else {
    int r0 = (bi - 1024) * 16;
    for (int p=0;p<2;p++){
      int i = tid + 256*p;
      int r = i >> 5, oct = (i & 31)*8;
      *(uint4*)&At[r][oct] = *(const uint4*)&xbf[(r0+r)*DM + oct];
    }
    __syncthreads();
    bhalf8 af[8];
    #pragma unroll
    for (int ks=0; ks<8; ks++)
      af[ks] = *(const bhalf8*)&At[m16][ks*32 + quad*8];
    f32x4 acc[4];
    #pragma unroll
    for (int ct=0; ct<4; ct++) acc[ct] = (f32x4)(0.f);
    #pragma unroll
    for (int ks=0; ks<8; ks++){
      #pragma unroll
      for (int ct=0; ct<4; ct++){
        int f = (w*4 + ct)*8 + ks;
        bhalf8 bf = *(const bhalf8*)&scWt[f*512 + lane*8];
        acc[ct] = __builtin_amdgcn_mfma_f32_16x16x32_bf16(af[ks], bf, acc[ct], 0,0,0);
      }
    }
    #pragma unroll
    for (int ct=0; ct<4; ct++){
      #pragma unroll
      for (int e=0;e<4;e++){
        int row = quad*4 + e;
        int col = w*64 + ct*16 + m16;
        Dt[row][col] = acc[ct][e] + sc_b[col];
      }
    }
    __syncthreads();
    {
      int row = tid >> 4, seg = tid & 15;
      float s = 0.f, s2 = 0.f;
      #pragma unroll
      for (int i=0;i<4;i++){
        float4 v = *(const float4*)&Dt[row][seg*16 + i*4];
        s  += v.x+v.y+v.z+v.w;
        s2 += v.x*v.x + v.y*v.y + v.z*v.z + v.w*v.w;
      }
      red[row][seg] = s;
      __syncthreads();
      if (seg == 0){
        float t=0.f;
        #pragma unroll
        for (int i=0;i<16;i++) t += red[row][i];
        mu[row] = t * (1.f/DM);
      }
      __syncthreads();
      red[row][seg] = s2;
      __syncthreads();
      if (seg == 0){
        float t=0.f;
        #pragma unroll
        for (int i=0;i<16;i++) t += red[row][i];
        float m = mu[row];
        rs[row] = rsqrtf(t*(1.f/DM) - m*m + 1e-5f);
      }
    }
    __syncthreads();
    float gg = ln_g[tid], bb = ln_b[tid];
    #pragma unroll
    for (int r=0;r<16;r++)
      ident[(r0+r)*DM + tid] = (Dt[r][tid]-mu[r])*rs[r]*gg + bb;
  }
}

// ================= fused conv + silu + x_dbl(MFMA) + dt =================
__global__ __launch_bounds__(256) void k_convdbl(
    const float* __restrict__ cw_spa, const float* __restrict__ cb_spa,
    const float* __restrict__ cw_spe, const float* __restrict__ cb_spe,
    const float* __restrict__ xc_raw,
    const unsigned short* __restrict__ Wxt_spa, const unsigned short* __restrict__ Wxt_spe,
    const float* __restrict__ Wdt_spa, const float* __restrict__ bdt_spa,
    const float* __restrict__ Wdt_spe, const float* __restrict__ bdt_spe,
    float* __restrict__ xc, float* __restrict__ dt,
    float* __restrict__ Bm, float* __restrict__ Cm)
{
  __shared__ unsigned short At[16][520];   // 16.6 KB
  __shared__ float xdbl[16][18];
  int tid = threadIdx.x;
  int r0 = blockIdx.x * 16;
  int branch = r0 >= HALF_ROWS;
  int l0 = r0 & (LD-1);
  const float* cw = branch ? cw_spe : cw_spa;
  const float* cb = branch ? cb_spe : cb_spa;
  const unsigned short* Wxt = branch ? Wxt_spe : Wxt_spa;
  const float* Wdt = branch ? Wdt_spe : Wdt_spa;
  const float* bdt = branch ? bdt_spe : bdt_spa;
  {
    int c = tid*2;
    float4 w0 = *(const float4*)(cw + 4*c);
    float4 w1 = *(const float4*)(cw + 4*(c+1));
    float2 bias = *(const float2*)(cb + c);
    float2 h0, h1, h2;
    if (l0 > 0){
      h0 = *(const float2*)(xc_raw + (r0-3)*DI + c);
      h1 = *(const float2*)(xc_raw + (r0-2)*DI + c);
      h2 = *(const float2*)(xc_raw + (r0-1)*DI + c);
    } else {
      h0 = make_float2(0.f,0.f); h1 = h0; h2 = h0;
    }
    #pragma unroll
    for (int r=0;r<16;r++){
      float2 cur = *(const float2*)(xc_raw + (r0+r)*DI + c);
      float vx = bias.x;
      vx = fmaf(h0.x, w0.x, vx); vx = fmaf(h1.x, w0.y, vx);
      vx = fmaf(h2.x, w0.z, vx); vx = fmaf(cur.x, w0.w, vx);
      float vy = bias.y;
      vy = fmaf(h0.y, w1.x, vy); vy = fmaf(h1.y, w1.y, vy);
      vy = fmaf(h2.y, w1.z, vy); vy = fmaf(cur.y, w1.w, vy);
      vx = siluf(vx); vy = siluf(vy);
      *(float2*)(xc + (r0+r)*DI + c) = make_float2(vx, vy);
      unsigned int pk = (unsigned int)f2bf(vx) | ((unsigned int)f2bf(vy) << 16);
      *(unsigned int*)&At[r][c] = pk;
      h0 = h1; h1 = h2; h2 = cur;
    }
  }
  __syncthreads();
  int w = tid >> 6, lane = tid & 63;
  int m16 = lane & 15, quad = lane >> 4;
  f32x4 acc = (f32x4)(0.f);
  #pragma unroll
  for (int ks=0; ks<16; ks++){
    bhalf8 a = *(const bhalf8*)&At[m16][ks*32 + quad*8];
    int f = w*16 + ks;
    bhalf8 bf = *(const bhalf8*)&Wxt[f*512 + lane*8];
    acc = __builtin_amdgcn_mfma_f32_16x16x32_bf16(a, bf, acc, 0,0,0);
  }
  #pragma unroll
  for (int e=0;e<4;e++){
    int row = quad*4 + e;
    float v = acc[e];
    if (w == 0)      xdbl[row][m16] = v;
    else if (w == 1) Bm[(r0+row)*DS + m16] = v;
    else if (w == 2) Cm[(r0+row)*DS + m16] = v;
  }
  __syncthreads();
  float wdt0[16], wdt1[16];
  #pragma unroll
  for (int j=0;j<16;j++){ wdt0[j]=Wdt[j*DI+tid]; wdt1[j]=Wdt[j*DI+tid+256]; }
  float b0 = bdt[tid], b1 = bdt[tid+256];
  #pragma unroll
  for (int r=0;r<16;r++){
    float a0=b0, a1=b1;
    #pragma unroll
    for (int j=0;j<16;j++){
      float xv = xdbl[r][j];
      a0 = fmaf(xv, wdt0[j], a0);
      a1 = fmaf(xv, wdt1[j], a1);
    }
    dt[(r0+r)*DI + tid]       = softplusf(a0);
    dt[(r0+r)*DI + tid + 256] = softplusf(a1);
  }
}

// ================= selective scan v7: all-register inputs, double-buffered ypbuf =================
// 512 blocks x 256 thr; thread (dg=tid>>4, s=tid&15); 16 chunks of 16 rows.
__global__ __launch_bounds__(256) void k_scan(
    const float* __restrict__ Alog_spa, const float* __restrict__ Dp_spa,
    const float* __restrict__ Alog_spe, const float* __restrict__ Dp_spe,
    const float* __restrict__ dt, const float* __restrict__ xc,
    const float* __restrict__ sz, const float* __restrict__ Bm,
    const float* __restrict__ Cm, unsigned short* __restrict__ ybf)
{
  __shared__ float ypbuf[2][16][257];   // 32.9 KB, double-buffered
  __shared__ float Dsh[16];
  int tid = threadIdx.x;
  int bi = blockIdx.x;
  int branch = bi >> 8;
  int rem = bi & 255;
  int b = rem >> 5;
  int d0 = (rem & 31) * 16;
  const float* Alog = branch ? Alog_spe : Alog_spa;
  const float* Dp   = branch ? Dp_spe   : Dp_spa;
  int dg = tid >> 4, s = tid & 15;
  int d = d0 + dg;
  float A_ds = -__expf(Alog[d*DS + s]);
  if (tid < 16) Dsh[tid] = Dp[d0 + tid];
  int row0 = branch*HALF_ROWS + b*LD;
  int wcol = s*16 + ((dg + s) & 15);    // this thread's ypbuf write column
  float h = 0.f;
  for (int c=0; c<16; c++){
    int rbase = row0 + c*16;
    int buf = c & 1;
    // all inputs straight into registers (VMEM pipe; broadcast/segment loads)
    float rdt[16], rxc[16], rB[16], rC[16];
    #pragma unroll
    for (int li=0; li<16; li++){
      rdt[li] = dt[(rbase+li)*DI + d];
      rxc[li] = xc[(rbase+li)*DI + d];
      rB[li]  = Bm[(rbase+li)*DS + s];
      rC[li]  = Cm[(rbase+li)*DS + s];
    }
    // serial scan (critical path: exp + fma per step)
    float yp[16];
    #pragma unroll
    for (int li=0; li<16; li++){
      float dA = __expf(rdt[li] * A_ds);
      h = fmaf(dA, h, rdt[li] * rB[li] * rxc[li]);
      yp[li] = h * rC[li];
    }
    #pragma unroll
    for (int li=0; li<16; li++)
      ypbuf[buf][li][wcol] = yp[li];
    __syncthreads();
    // reduce over s: thread (dg,s) -> row rbase+s, col d0+dg
    float acc = 0.f;
    #pragma unroll
    for (int ss=0; ss<16; ss++)
      acc += ypbuf[buf][s][ss*16 + ((dg + ss) & 15)];
    float xcv = rxc[s];   // xc[rbase+s][d0+dg] already in this thread's registers
    float szv = sz[(rbase+s)*DI + d0 + dg];
    float yv = fmaf(xcv, Dsh[dg], acc) * szv;
    ybf[(rbase+s)*DI + d0 + dg] = f2bf(yv);
    // no trailing barrier: next chunk writes the other buffer; reads of that
    // buffer (2 chunks ago) are separated by this chunk's barrier.
  }
}

// ================= W_out GEMM + relu + residual + pool-accumulate (MFMA) =================
__global__ __launch_bounds__(256) void k_wout(
    const unsigned short* __restrict__ Wt_spa, const unsigned short* __restrict__ Wt_spe,
    const float* __restrict__ x_spa, const float* __restrict__ x_spe,
    const unsigned short* __restrict__ ybf, float* __restrict__ ae,
    float* __restrict__ pooled)
{
  __shared__ unsigned short At[16][520];   // 16.6 KB
  int tid = threadIdx.x;
  int bi = blockIdx.x;
  int r0 = (bi >> 1) * 16;
  int ch = bi & 1;
  int branch = (r0 >= HALF_ROWS);
  const unsigned short* Wt = branch ? Wt_spe : Wt_spa;
  const float* xb = branch ? x_spe : x_spa;
  int rr0 = branch ? r0 - HALF_ROWS : r0;
  for (int p=0;p<4;p++){
    int i = tid + 256*p;
    int r = i >> 6, oct = (i & 63)*8;
    *(uint4*)&At[r][oct] = *(const uint4*)&ybf[(r0+r)*DI + oct];
  }
  __syncthreads();
  int w = tid >> 6, lane = tid & 63;
  int m16 = lane & 15, quad = lane >> 4;
  bhalf8 af[16];
  #pragma unroll
  for (int ks=0; ks<16; ks++)
    af[ks] = *(const bhalf8*)&At[m16][ks*32 + quad*8];
  f32x4 acc[2];
  #pragma unroll
  for (int ct=0; ct<2; ct++) acc[ct] = (f32x4)(0.f);
  #pragma unroll
  for (int ks=0; ks<16; ks++){
    #pragma unroll
    for (int ct=0; ct<2; ct++){
      int f = (ch*8 + w*2 + ct)*16 + ks;
      bhalf8 bf = *(const bhalf8*)&Wt[f*512 + lane*8];
      acc[ct] = __builtin_amdgcn_mfma_f32_16x16x32_bf16(af[ks], bf, acc[ct], 0,0,0);
    }
  }
  float ps0 = 0.f, ps1 = 0.f;
  #pragma unroll
  for (int ct=0; ct<2; ct++){
    #pragma unroll
    for (int e=0;e<4;e++){
      int row = quad*4 + e;
      int col = ch*128 + w*32 + ct*16 + m16;
      float v = fmaxf(acc[ct][e], 0.f) + xb[(rr0+row)*DM + col];
      ae[(r0+row)*DM + col] = v;
      if (ct == 0) ps0 += v; else ps1 += v;
    }
  }
  ps0 += __shfl_xor(ps0, 16, 64); ps0 += __shfl_xor(ps0, 32, 64);
  ps1 += __shfl_xor(ps1, 16, 64); ps1 += __shfl_xor(ps1, 32, 64);
  if (quad == 0){
    int bidx = (r0 >> 8) & 7;
    atomicAdd(&pooled[bidx*DM + ch*128 + w*32 + m16],      ps0);
    atomicAdd(&pooled[bidx*DM + ch*128 + w*32 + 16 + m16], ps1);
  }
}

// ================= gate: fw = sigmoid((pooled*0.5/L) @ fusion_W) =================
__global__ __launch_bounds__(256) void k_gate(const float* __restrict__ pooled,
    const float* __restrict__ fW, float* __restrict__ fw)
{
  __shared__ float p[DM];
  int b=blockIdx.x, c=threadIdx.x;
  p[c] = pooled[b*DM+c] * (0.5f/LD);
  __syncthreads();
  float a=0.f;
  for(int k=0;k<DM;k+=4){
    a = fmaf(p[k+0], fW[(k+0)*DM+c], a);
    a = fmaf(p[k+1], fW[(k+1)*DM+c], a);
    a = fmaf(p[k+2], fW[(k+2)*DM+c], a);
    a = fmaf(p[k+3], fW[(k+3)*DM+c], a);
  }
  fw[b*DM+c]=1.f/(1.f+__expf(-a));
}

// ================= final: out = ae*fw + ident =================
__global__ __launch_bounds__(256) void k_final(const float* __restrict__ ae,
    const float* __restrict__ ident, const float* __restrict__ fw, float* __restrict__ out)
{
  int idx4 = blockIdx.x*256 + threadIdx.x;
  int row = idx4 >> 6;
  int b = (row >> 8) & 7;
  int c4 = (idx4 & 63) * 4;
  float4 av = *(const float4*)(ae + idx4*4);
  float4 iv = *(const float4*)(ident + idx4*4);
  float4 fv = *(const float4*)(fw + b*DM + c4);
  float4 o;
  o.x = fmaf(av.x, fv.x, iv.x);
  o.y = fmaf(av.y, fv.y, iv.y);
  o.z = fmaf(av.z, fv.z, iv.z);
  o.w = fmaf(av.w, fv.w, iv.w);
  *(float4*)(out + idx4*4) = o;
}

extern "C" void kernel_launch(void* const* d_in, const int* in_sizes, int n_in,
                              void* d_out, int out_size, void* d_ws, size_t ws_size,
                              hipStream_t stream) {
  const float* x_spa     = (const float*)d_in[0];
  const float* x_spe     = (const float*)d_in[1];
  const float* spa_ln_g  = (const float*)d_in[2];
  const float* spa_ln_b  = (const float*)d_in[3];
  const float* spa_W_in  = (const float*)d_in[4];
  const float* spa_cw    = (const float*)d_in[5];
  const float* spa_cb    = (const float*)d_in[6];
  const float* spa_W_x   = (const float*)d_in[7];
  const float* spa_W_dt  = (const float*)d_in[8];
  const float* spa_b_dt  = (const float*)d_in[9];
  const float* spa_A_log = (const float*)d_in[10];
  const float* spa_D     = (const float*)d_in[11];
  const float* spa_W_out = (const float*)d_in[12];
  const float* spe_ln_g  = (const float*)d_in[13];
  const float* spe_ln_b  = (const float*)d_in[14];
  const float* spe_W_in  = (const float*)d_in[15];
  const float* spe_cw    = (const float*)d_in[16];
  const float* spe_cb    = (const float*)d_in[17];
  const float* spe_W_x   = (const float*)d_in[18];
  const float* spe_W_dt  = (const float*)d_in[19];
  const float* spe_b_dt  = (const float*)d_in[20];
  const float* spe_A_log = (const float*)d_in[21];
  const float* spe_D     = (const float*)d_in[22];
  const float* spe_W_out = (const float*)d_in[23];
  const float* sc_W      = (const float*)d_in[24];
  const float* sc_b      = (const float*)d_in[25];
  const float* sc_ln_g   = (const float*)d_in[26];
  const float* sc_ln_b   = (const float*)d_in[27];
  const float* fusion_W  = (const float*)d_in[28];

  float* ws = (float*)d_ws;
  float* ident  = ws;                       // 4096*256
  float* xc_raw = ident  + NROWS*DM;        // 4096*512 (reused as ybf)
  float* sz     = xc_raw + NROWS*DI;        // 4096*512
  float* xc     = sz     + NROWS*DI;        // 4096*512
  float* dt     = xc     + NROWS*DI;        // 4096*512 (reused as ae)
  float* Bm     = dt     + NROWS*DI;        // 4096*16
  float* Cm     = Bm     + NROWS*DS;        // 4096*16
  float* pooled = Cm     + NROWS*DS;        // 8*256
  float* fw     = pooled + BD*DM;           // 8*256
  unsigned short* Wt_i_spa = (unsigned short*)(fw + BD*DM);
  unsigned short* Wt_i_spe = Wt_i_spa + 1024*256;
  unsigned short* Wt_o_spa = Wt_i_spe + 1024*256;
  unsigned short* Wt_o_spe = Wt_o_spa + 256*512;
  unsigned short* scWt     = Wt_o_spe + 256*512;
  unsigned short* Wxt_spa  = scWt     + 256*256;
  unsigned short* Wxt_spe  = Wxt_spa  + 64*512;
  unsigned short* xnbf     = Wxt_spe  + 64*512;   // 4096*256 bf16
  unsigned short* xbf      = xnbf     + NROWS*DM; // 4096*256 bf16

  float* out = (float*)d_out;

  k_prep<<<317, 256, 0, stream>>>(spa_W_in, spe_W_in, spa_W_out, spe_W_out, sc_W,
                                  spa_W_x, spe_W_x, x_spa, x_spe,
                                  spa_ln_g, spa_ln_b, spe_ln_g, spe_ln_b,
                                  Wt_i_spa, Wt_i_spe, Wt_o_spa, Wt_o_spe, scWt,
                                  Wxt_spa, Wxt_spe, xnbf, xbf, pooled);
  k_gemm1<<<1280, 256, 0, stream>>>(xnbf, xbf, Wt_i_spa, Wt_i_spe, scWt, sc_b,
                                    sc_ln_g, sc_ln_b, xc_raw, sz, ident);
  k_convdbl<<<NROWS/16, 256, 0, stream>>>(spa_cw, spa_cb, spe_cw, spe_cb, xc_raw,
                                          Wxt_spa, Wxt_spe,
                                          spa_W_dt, spa_b_dt, spe_W_dt, spe_b_dt,
                                          xc, dt, Bm, Cm);
  unsigned short* ybf = (unsigned short*)xc_raw;   // xc_raw dead after k_convdbl
  k_scan<<<512, 256, 0, stream>>>(spa_A_log, spa_D, spe_A_log, spe_D, dt, xc, sz, Bm, Cm, ybf);
  float* ae = dt;      // dt dead after k_scan
  k_wout<<<512, 256, 0, stream>>>(Wt_o_spa, Wt_o_spe, x_spa, x_spe, ybf, ae, pooled);
  k_gate<<<BD, 256, 0, stream>>>(pooled, fusion_W, fw);
  k_final<<<NROWS*DM/1024, 256, 0, stream>>>(ae, ident, fw, out);
}